// Round 1
// baseline (1235.975 us; speedup 1.0000x reference)
//
#include <hip/hip_runtime.h>
#include <hip/hip_bf16.h>

#define BSZ 2
#define C 256
#define NH 8
#define DIM 32
#define LSEQ 30720
#define ROWS (BSZ*LSEQ)
#define FF 1024
#define NCHUNK 120
#define CHS 256

__device__ __forceinline__ float phi_elu1(float v) { return v > 0.f ? v + 1.f : __expf(v); }

// round-to-nearest-even f32 -> bf16 bits (finite inputs)
__device__ __forceinline__ unsigned short f2bf(float f) {
    unsigned int u = __float_as_uint(f);
    u += 0x7fffu + ((u >> 16) & 1u);
    return (unsigned short)(u >> 16);
}

// ---------------- K1: partial KV (32x32) + Ksum per (b,head,s-chunk) ----------------
__global__ __launch_bounds__(256) void k1_kv_partial(
        const float* __restrict__ x, const float* __restrict__ Wkqv,
        float* __restrict__ part) {
    __shared__ float Wk[DIM][DIM+1];
    __shared__ float Wv[DIM][DIM+1];
    __shared__ float KsT[DIM][CHS+1];   // pad 257: conflict-free transposed access
    __shared__ float VsT[DIM][CHS+1];
    const int t = threadIdx.x;
    const int bh = blockIdx.x;          // 0..15  (b*8+head)
    const int chunk = blockIdx.y;       // 0..119
    const int b = bh >> 3, head = bh & 7;
    for (int idx = t; idx < DIM*DIM; idx += 256) {
        int e = idx >> 5, d = idx & 31;
        Wk[e][d] = Wkqv[idx];               // rows 0..31  = K weights (split order k,q,v)
        Wv[e][d] = Wkqv[2*DIM*DIM + idx];   // rows 64..95 = V weights
    }
    __syncthreads();
    const int s = chunk*CHS + t;
    const float* xr = x + ((size_t)(b*LSEQ + s))*C + head*DIM;
    float xv[DIM];
    #pragma unroll
    for (int i = 0; i < DIM/4; ++i) {
        float4 v4 = reinterpret_cast<const float4*>(xr)[i];
        xv[4*i+0]=v4.x; xv[4*i+1]=v4.y; xv[4*i+2]=v4.z; xv[4*i+3]=v4.w;
    }
    // NOTE: v is NOT divided by L and attn not multiplied by L — they cancel exactly.
    #pragma unroll 4
    for (int e = 0; e < DIM; ++e) {
        float ak = 0.f, av = 0.f;
        #pragma unroll
        for (int d = 0; d < DIM; ++d) { ak += xv[d]*Wk[e][d]; av += xv[d]*Wv[e][d]; }
        KsT[e][t] = phi_elu1(ak);
        VsT[e][t] = av;
    }
    __syncthreads();
    // phase 2: thread (d, g) accumulates KV[d][g*4..g*4+3] over the 256 s of this chunk
    const int d = t & 31, g = t >> 5;
    const int e0 = g*4;
    float acc0=0.f, acc1=0.f, acc2=0.f, acc3=0.f, ks=0.f;
    for (int s2 = 0; s2 < CHS; ++s2) {
        float kd = KsT[d][s2];
        ks += kd;
        acc0 += kd * VsT[e0+0][s2];
        acc1 += kd * VsT[e0+1][s2];
        acc2 += kd * VsT[e0+2][s2];
        acc3 += kd * VsT[e0+3][s2];
    }
    float* pb = part + ((size_t)bh*NCHUNK + chunk)*1056;
    float4 o = make_float4(acc0, acc1, acc2, acc3);
    *reinterpret_cast<float4*>(pb + d*32 + e0) = o;
    if (g == 0) pb[1024 + d] = ks;
}

// ---------------- K2: deterministic reduce of NCHUNK partials ----------------
__global__ __launch_bounds__(256) void k2_kv_reduce(
        const float* __restrict__ part, float* __restrict__ kv) {
    const int bh = blockIdx.x, t = threadIdx.x;
    for (int i = t; i < 1056; i += 256) {
        float s = 0.f;
        for (int c2 = 0; c2 < NCHUNK; ++c2)
            s += part[((size_t)bh*NCHUNK + c2)*1056 + i];
        kv[bh*1056 + i] = s;
    }
}

// ---------------- K3: recompute Q, apply attention, residual + LN1 -> x1 (in d_out) ----------------
__global__ __launch_bounds__(256) void k3_attn_ln1(
        const float* __restrict__ x, const float* __restrict__ Wkqv,
        const float* __restrict__ kv, const float* __restrict__ g1,
        const float* __restrict__ be1, float* __restrict__ x1out) {
    __shared__ float Wq[DIM][DIM+1];
    __shared__ float KVs[NH][DIM][DIM];   // 32 KB, all heads for this b
    __shared__ float Ksm[NH][DIM];
    __shared__ float xs[C];
    __shared__ float Qs[C];
    __shared__ float redA[4], redB[4];
    const int t = threadIdx.x;
    const int hd = t >> 5, e = t & 31;
    const int row0 = blockIdx.x * 4;      // LSEQ % 4 == 0 -> block never straddles b
    const int b = row0 / LSEQ;
    for (int idx = t; idx < DIM*DIM; idx += 256)
        Wq[idx >> 5][idx & 31] = Wkqv[DIM*DIM + idx];     // rows 32..63 = Q weights
    for (int idx = t; idx < NH*DIM*DIM; idx += 256) {
        int h2 = idx >> 10, rem = idx & 1023;
        KVs[h2][rem >> 5][rem & 31] = kv[(size_t)(b*NH + h2)*1056 + rem];
    }
    Ksm[t >> 5][e] = kv[(size_t)(b*NH + (t >> 5))*1056 + 1024 + e];
    __syncthreads();
    const int lane = t & 63, wv = t >> 6;
    for (int rr = 0; rr < 4; ++rr) {
        const int row = row0 + rr;
        xs[t] = x[(size_t)row*C + t];
        __syncthreads();
        float q = 0.f;
        #pragma unroll
        for (int d2 = 0; d2 < DIM; ++d2) q += xs[hd*DIM + d2] * Wq[e][d2];
        float Q = phi_elu1(q);
        float pz = Q * Ksm[hd][e];
        #pragma unroll
        for (int m = 16; m >= 1; m >>= 1) pz += __shfl_xor(pz, m, 32);
        float Z = 1.f / (pz + 1e-6f);
        Qs[t] = Q;
        __syncthreads();
        float at = 0.f;
        #pragma unroll
        for (int d2 = 0; d2 < DIM; ++d2) at += Qs[hd*DIM + d2] * KVs[hd][d2][e];
        float val = xs[t] + at * Z;
        float s1 = val, s2 = val*val;
        #pragma unroll
        for (int m = 32; m >= 1; m >>= 1) {
            s1 += __shfl_xor(s1, m, 64);
            s2 += __shfl_xor(s2, m, 64);
        }
        if (lane == 0) { redA[wv] = s1; redB[wv] = s2; }
        __syncthreads();
        float tot1 = redA[0]+redA[1]+redA[2]+redA[3];
        float tot2 = redB[0]+redB[1]+redB[2]+redB[3];
        float mean = tot1 * (1.f/C);
        float var  = tot2 * (1.f/C) - mean*mean;
        float rs = rsqrtf(var + 1e-5f);
        x1out[(size_t)row*C + t] = (val - mean)*rs*g1[t] + be1[t];
        __syncthreads();   // xs/Qs/red reused next row
    }
}

// ---------------- K4: ff = gelu(x1 @ W1^T + b1) -> bf16 in ws ----------------
__global__ __launch_bounds__(256) void k4_ffn1(
        const float* __restrict__ x1, const float* __restrict__ W1,
        const float* __restrict__ b1, unsigned short* __restrict__ c1) {
    __shared__ float As[64][68];    // [m][k]
    __shared__ float BsT[64][68];   // [k][n]  (transposed -> conflict-free b-reads)
    const int t = threadIdx.x;
    const int m0 = blockIdx.x * 64, n0 = blockIdx.y * 64;
    const int tm = t >> 4, tn = t & 15;
    float acc[4][4] = {};
    for (int kt = 0; kt < 4; ++kt) {
        const int k0 = kt * 64;
        #pragma unroll
        for (int i = 0; i < 4; ++i) {
            int fi = t + i*256;
            int row = fi >> 4, c4 = fi & 15;
            float4 a4 = reinterpret_cast<const float4*>(x1 + (size_t)(m0+row)*C + k0)[c4];
            *reinterpret_cast<float4*>(&As[row][c4*4]) = a4;
            float4 b4 = reinterpret_cast<const float4*>(W1 + (size_t)(n0+row)*C + k0)[c4];
            BsT[c4*4+0][row] = b4.x;
            BsT[c4*4+1][row] = b4.y;
            BsT[c4*4+2][row] = b4.z;
            BsT[c4*4+3][row] = b4.w;
        }
        __syncthreads();
        #pragma unroll
        for (int kk4 = 0; kk4 < 16; ++kk4) {
            float av[4][4], bv[4][4];
            #pragma unroll
            for (int i = 0; i < 4; ++i) {
                float4 tmp = *reinterpret_cast<const float4*>(&As[tm*4+i][kk4*4]);
                av[i][0]=tmp.x; av[i][1]=tmp.y; av[i][2]=tmp.z; av[i][3]=tmp.w;
            }
            #pragma unroll
            for (int q = 0; q < 4; ++q) {
                float4 tmp = *reinterpret_cast<const float4*>(&BsT[kk4*4+q][tn*4]);
                bv[q][0]=tmp.x; bv[q][1]=tmp.y; bv[q][2]=tmp.z; bv[q][3]=tmp.w;
            }
            #pragma unroll
            for (int q = 0; q < 4; ++q)
                #pragma unroll
                for (int i = 0; i < 4; ++i)
                    #pragma unroll
                    for (int j = 0; j < 4; ++j)
                        acc[i][j] += av[i][q] * bv[q][j];
        }
        __syncthreads();
    }
    #pragma unroll
    for (int i = 0; i < 4; ++i) {
        const int row = m0 + tm*4 + i;
        unsigned short us[4];
        #pragma unroll
        for (int j = 0; j < 4; ++j) {
            const int n = n0 + tn*4 + j;
            float f = acc[i][j] + b1[n];
            f = 0.5f * f * (1.f + erff(f * 0.70710678118654752f));  // exact erf gelu
            us[j] = f2bf(f);
        }
        ushort4 u; u.x=us[0]; u.y=us[1]; u.z=us[2]; u.w=us[3];
        *reinterpret_cast<ushort4*>(c1 + (size_t)row*FF + n0 + tn*4) = u;
    }
}

// ---------------- K5: out = LN2(x1 + ff @ W2^T + b2) ----------------
// xo == d_out: holds x1 on entry (residual), final output on exit.
// Each global address is read and written by exactly one thread -> no hazard.
__global__ __launch_bounds__(256) void k5_ffn2(
        const unsigned short* __restrict__ c1, const float* __restrict__ W2,
        const float* __restrict__ b2, const float* __restrict__ g2,
        const float* __restrict__ be2, float* xo) {
    __shared__ float As2[64][36];     // [m][k] (from bf16 ff)
    __shared__ float BsT2[32][260];   // [k][n], 260 mod 32 == 4 -> 2-way max (free)
    const int t = threadIdx.x;
    const int m0 = blockIdx.x * 64;
    const int tm = t >> 4, tn = t & 15;
    float acc[4][16] = {};
    for (int kt = 0; kt < 32; ++kt) {
        const int k0 = kt * 32;
        {
            const int row = t >> 2, c8 = t & 3;
            uint4 u = *reinterpret_cast<const uint4*>(c1 + (size_t)(m0+row)*FF + k0 + c8*8);
            const unsigned int* uw = reinterpret_cast<const unsigned int*>(&u);
            #pragma unroll
            for (int q2 = 0; q2 < 4; ++q2) {
                unsigned int w = uw[q2];
                As2[row][c8*8 + 2*q2    ] = __uint_as_float(w << 16);
                As2[row][c8*8 + 2*q2 + 1] = __uint_as_float(w & 0xffff0000u);
            }
        }
        {
            const float* wsrc = W2 + (size_t)t*FF + k0;   // thread t = output col n
            #pragma unroll
            for (int mq = 0; mq < 8; ++mq) {
                float4 w4 = reinterpret_cast<const float4*>(wsrc)[mq];
                BsT2[mq*4+0][t] = w4.x;
                BsT2[mq*4+1][t] = w4.y;
                BsT2[mq*4+2][t] = w4.z;
                BsT2[mq*4+3][t] = w4.w;
            }
        }
        __syncthreads();
        #pragma unroll 4
        for (int kk = 0; kk < 32; ++kk) {
            float a0 = As2[tm*4+0][kk];
            float a1 = As2[tm*4+1][kk];
            float a2 = As2[tm*4+2][kk];
            float a3 = As2[tm*4+3][kk];
            #pragma unroll
            for (int j2 = 0; j2 < 4; ++j2) {
                float4 b4 = *reinterpret_cast<const float4*>(&BsT2[kk][j2*64 + tn*4]);
                float bb[4] = {b4.x, b4.y, b4.z, b4.w};
                #pragma unroll
                for (int q = 0; q < 4; ++q) {
                    acc[0][j2*4+q] += a0 * bb[q];
                    acc[1][j2*4+q] += a1 * bb[q];
                    acc[2][j2*4+q] += a2 * bb[q];
                    acc[3][j2*4+q] += a3 * bb[q];
                }
            }
        }
        __syncthreads();
    }
    #pragma unroll
    for (int i = 0; i < 4; ++i) {
        const int row = m0 + tm*4 + i;
        float vals[16], s1 = 0.f, s2 = 0.f;
        #pragma unroll
        for (int j2 = 0; j2 < 4; ++j2) {
            const int cb = j2*64 + tn*4;   // strided cols: conflict-free LDS + coalesced global
            float4 xr = *reinterpret_cast<const float4*>(xo + (size_t)row*C + cb);
            float xx[4] = {xr.x, xr.y, xr.z, xr.w};
            #pragma unroll
            for (int q = 0; q < 4; ++q) {
                float v = acc[i][j2*4+q] + b2[cb+q] + xx[q];
                vals[j2*4+q] = v;
                s1 += v; s2 += v*v;
            }
        }
        #pragma unroll
        for (int m = 8; m >= 1; m >>= 1) {    // row lives in 16 consecutive lanes
            s1 += __shfl_xor(s1, m, 16);
            s2 += __shfl_xor(s2, m, 16);
        }
        float mean = s1 * (1.f/C);
        float var  = s2 * (1.f/C) - mean*mean;
        float rs = rsqrtf(var + 1e-5f);
        #pragma unroll
        for (int j2 = 0; j2 < 4; ++j2) {
            const int cb = j2*64 + tn*4;
            float4 o;
            o.x = (vals[j2*4+0]-mean)*rs*g2[cb+0] + be2[cb+0];
            o.y = (vals[j2*4+1]-mean)*rs*g2[cb+1] + be2[cb+1];
            o.z = (vals[j2*4+2]-mean)*rs*g2[cb+2] + be2[cb+2];
            o.w = (vals[j2*4+3]-mean)*rs*g2[cb+3] + be2[cb+3];
            *reinterpret_cast<float4*>(xo + (size_t)row*C + cb) = o;
        }
    }
}

extern "C" void kernel_launch(void* const* d_in, const int* in_sizes, int n_in,
                              void* d_out, int out_size, void* d_ws, size_t ws_size,
                              hipStream_t stream) {
    const float* x    = (const float*)d_in[0];
    const float* Wkqv = (const float*)d_in[1];
    const float* W1   = (const float*)d_in[2];
    const float* b1   = (const float*)d_in[3];
    const float* W2   = (const float*)d_in[4];
    const float* b2   = (const float*)d_in[5];
    const float* g1   = (const float*)d_in[6];
    const float* be1  = (const float*)d_in[7];
    const float* g2   = (const float*)d_in[8];
    const float* be2  = (const float*)d_in[9];
    float* out = (float*)d_out;

    // ws layout: [0..16896) KV+Ksum | [128KB..8.24MB) partials | [16MB..) ff bf16 (126MB)
    float* kv   = (float*)d_ws;
    float* part = (float*)d_ws + 32768;
    unsigned short* c1 = (unsigned short*)((char*)d_ws + ((size_t)16 << 20));

    k1_kv_partial<<<dim3(16, NCHUNK), 256, 0, stream>>>(x, Wkqv, part);
    k2_kv_reduce<<<16, 256, 0, stream>>>(part, kv);
    k3_attn_ln1<<<ROWS/4, 256, 0, stream>>>(x, Wkqv, kv, g1, be1, out);   // d_out <- x1
    k4_ffn1<<<dim3(ROWS/64, FF/64), 256, 0, stream>>>(out, W1, b1, c1);
    k5_ffn2<<<ROWS/64, 256, 0, stream>>>(c1, W2, b2, g2, be2, out);      // d_out <- final
}

// Round 3
// 548.640 us; speedup vs baseline: 2.2528x; 2.2528x over previous
//
#include <hip/hip_runtime.h>
#include <hip/hip_bf16.h>

#define BSZ 2
#define C 256
#define NH 8
#define DIM 32
#define LSEQ 30720
#define ROWS (BSZ*LSEQ)
#define FF 1024
#define NCHUNK 120
#define CHS 256
#define MCHUNK (ROWS/2)

typedef __attribute__((ext_vector_type(8))) short bf16x8;
typedef __attribute__((ext_vector_type(4))) float f32x4;

__device__ __forceinline__ float phi_elu1(float v) { return v > 0.f ? v + 1.f : __expf(v); }

// round-to-nearest-even f32 -> bf16 bits (finite inputs)
__device__ __forceinline__ unsigned short f2bf(float f) {
    unsigned int u = __float_as_uint(f);
    u += 0x7fffu + ((u >> 16) & 1u);
    return (unsigned short)(u >> 16);
}
__device__ __forceinline__ float bf2f(unsigned short u) {
    return __uint_as_float(((unsigned int)u) << 16);
}

// async global->LDS, 16B per lane. LDS dest is wave-uniform base + lane*16.
__device__ __forceinline__ void gload_lds16(const unsigned short* g, unsigned short* l) {
    __builtin_amdgcn_global_load_lds(
        (const __attribute__((address_space(1))) unsigned int*)g,
        (__attribute__((address_space(3))) unsigned int*)l, 16, 0, 0);
}

// ---------------- K0: weights fp32 -> bf16 ----------------
__global__ __launch_bounds__(256) void k0_cvt(
        const float* __restrict__ W1, const float* __restrict__ W2,
        unsigned short* __restrict__ W1b, unsigned short* __restrict__ W2b) {
    const int i = blockIdx.x * 256 + threadIdx.x;   // 262144 total
    W1b[i] = f2bf(W1[i]);
    W2b[i] = f2bf(W2[i]);
}

// ---------------- K1: partial KV (32x32) + Ksum per (b,head,s-chunk) ----------------
__global__ __launch_bounds__(256) void k1_kv_partial(
        const float* __restrict__ x, const float* __restrict__ Wkqv,
        float* __restrict__ part) {
    __shared__ float Wk[DIM][DIM+1];
    __shared__ float Wv[DIM][DIM+1];
    __shared__ float KsT[DIM][CHS+1];
    __shared__ float VsT[DIM][CHS+1];
    const int t = threadIdx.x;
    const int bh = blockIdx.x;
    const int chunk = blockIdx.y;
    const int b = bh >> 3, head = bh & 7;
    for (int idx = t; idx < DIM*DIM; idx += 256) {
        int e = idx >> 5, d = idx & 31;
        Wk[e][d] = Wkqv[idx];
        Wv[e][d] = Wkqv[2*DIM*DIM + idx];
    }
    __syncthreads();
    const int s = chunk*CHS + t;
    const float* xr = x + ((size_t)(b*LSEQ + s))*C + head*DIM;
    float xv[DIM];
    #pragma unroll
    for (int i = 0; i < DIM/4; ++i) {
        float4 v4 = reinterpret_cast<const float4*>(xr)[i];
        xv[4*i+0]=v4.x; xv[4*i+1]=v4.y; xv[4*i+2]=v4.z; xv[4*i+3]=v4.w;
    }
    // v NOT divided by L, attn not multiplied by L — cancels exactly.
    #pragma unroll 4
    for (int e = 0; e < DIM; ++e) {
        float ak = 0.f, av = 0.f;
        #pragma unroll
        for (int d = 0; d < DIM; ++d) { ak += xv[d]*Wk[e][d]; av += xv[d]*Wv[e][d]; }
        KsT[e][t] = phi_elu1(ak);
        VsT[e][t] = av;
    }
    __syncthreads();
    const int d = t & 31, g = t >> 5;
    const int e0 = g*4;
    float acc0=0.f, acc1=0.f, acc2=0.f, acc3=0.f, ks=0.f;
    for (int s2 = 0; s2 < CHS; ++s2) {
        float kd = KsT[d][s2];
        ks += kd;
        acc0 += kd * VsT[e0+0][s2];
        acc1 += kd * VsT[e0+1][s2];
        acc2 += kd * VsT[e0+2][s2];
        acc3 += kd * VsT[e0+3][s2];
    }
    float* pb = part + ((size_t)bh*NCHUNK + chunk)*1056;
    float4 o = make_float4(acc0, acc1, acc2, acc3);
    *reinterpret_cast<float4*>(pb + d*32 + e0) = o;
    if (g == 0) pb[1024 + d] = ks;
}

// ---------------- K2: deterministic reduce ----------------
__global__ __launch_bounds__(256) void k2_kv_reduce(
        const float* __restrict__ part, float* __restrict__ kv) {
    const int bh = blockIdx.x, t = threadIdx.x;
    for (int i = t; i < 1056; i += 256) {
        float s = 0.f;
        for (int c2 = 0; c2 < NCHUNK; ++c2)
            s += part[((size_t)bh*NCHUNK + c2)*1056 + i];
        kv[bh*1056 + i] = s;
    }
}

// ---------------- K3: Q recompute, attention, residual + LN1 -> xb (bf16) ----------------
__global__ __launch_bounds__(256) void k3_attn_ln1(
        const float* __restrict__ x, const float* __restrict__ Wkqv,
        const float* __restrict__ kv, const float* __restrict__ g1,
        const float* __restrict__ be1, unsigned short* __restrict__ xb) {
    __shared__ float Wq[DIM][DIM+1];
    __shared__ float KVs[NH][DIM][DIM];
    __shared__ float Ksm[NH][DIM];
    __shared__ float xs[C];
    __shared__ float Qs[C];
    __shared__ float redA[4], redB[4];
    const int t = threadIdx.x;
    const int hd = t >> 5, e = t & 31;
    const int row0 = blockIdx.x * 4;
    const int b = row0 / LSEQ;
    for (int idx = t; idx < DIM*DIM; idx += 256)
        Wq[idx >> 5][idx & 31] = Wkqv[DIM*DIM + idx];
    for (int idx = t; idx < NH*DIM*DIM; idx += 256) {
        int h2 = idx >> 10, rem = idx & 1023;
        KVs[h2][rem >> 5][rem & 31] = kv[(size_t)(b*NH + h2)*1056 + rem];
    }
    Ksm[t >> 5][e] = kv[(size_t)(b*NH + (t >> 5))*1056 + 1024 + e];
    __syncthreads();
    const int lane = t & 63, wv = t >> 6;
    for (int rr = 0; rr < 4; ++rr) {
        const int row = row0 + rr;
        xs[t] = x[(size_t)row*C + t];
        __syncthreads();
        float q = 0.f;
        #pragma unroll
        for (int d2 = 0; d2 < DIM; ++d2) q += xs[hd*DIM + d2] * Wq[e][d2];
        float Q = phi_elu1(q);
        float pz = Q * Ksm[hd][e];
        #pragma unroll
        for (int m = 16; m >= 1; m >>= 1) pz += __shfl_xor(pz, m, 32);
        float Z = 1.f / (pz + 1e-6f);
        Qs[t] = Q;
        __syncthreads();
        float at = 0.f;
        #pragma unroll
        for (int d2 = 0; d2 < DIM; ++d2) at += Qs[hd*DIM + d2] * KVs[hd][d2][e];
        float val = xs[t] + at * Z;
        float s1 = val, s2 = val*val;
        #pragma unroll
        for (int m = 32; m >= 1; m >>= 1) {
            s1 += __shfl_xor(s1, m, 64);
            s2 += __shfl_xor(s2, m, 64);
        }
        if (lane == 0) { redA[wv] = s1; redB[wv] = s2; }
        __syncthreads();
        float tot1 = redA[0]+redA[1]+redA[2]+redA[3];
        float tot2 = redB[0]+redB[1]+redB[2]+redB[3];
        float mean = tot1 * (1.f/C);
        float var  = tot2 * (1.f/C) - mean*mean;
        float rs = rsqrtf(var + 1e-5f);
        xb[(size_t)row*C + t] = f2bf((val - mean)*rs*g1[t] + be1[t]);
        __syncthreads();
    }
}

// ---------------- K4: MFMA GEMM1  c1 = gelu(xb @ W1^T + b1), bf16 out ----------------
// A: xb [ROWS][256] bf16 (rows mbase..mbase+MCHUNK), B: W1b [1024][256] bf16.
// 128x128 tile, BK=64, 4 waves (2x2), 16x16x32 MFMA, XOR-swizzled LDS.
// Tile = 128 rows x 64 cols x 2B = 16 KB = 1024 segs of 16B -> FOUR issues of
// 256 lanes x 16B per tile (round-2 bug: only two -> half the tile staged).
__global__ __launch_bounds__(256) void k4_ffn1_mfma(
        const unsigned short* __restrict__ A, const unsigned short* __restrict__ B,
        const float* __restrict__ b1, unsigned short* __restrict__ c1, int mbase) {
    __shared__ unsigned short As[128*64];
    __shared__ unsigned short Bs[128*64];
    const int t = threadIdx.x;
    const int wid = t >> 6, lane = t & 63;
    const int wr = wid >> 1, wc = wid & 1;
    const int m0 = mbase + blockIdx.x*128;
    const int n0 = blockIdx.y*128;
    f32x4 acc[4][4] = {};
    for (int kt = 0; kt < C/64; ++kt) {
        const int k0 = kt*64;
        #pragma unroll
        for (int i = 0; i < 4; ++i) {
            const int seg = i*256 + t;              // 0..1023
            const int row = seg >> 3, jd = seg & 7;
            const int js = jd ^ (row & 7);          // pre-swizzled global source (rule #21)
            gload_lds16(A + (size_t)(m0+row)*C + k0 + js*8, &As[(i*256 + wid*64)*8]);
            gload_lds16(B + (size_t)(n0+row)*C + k0 + js*8, &Bs[(i*256 + wid*64)*8]);
        }
        __syncthreads();   // compiler drains vmcnt before barrier
        #pragma unroll
        for (int kk = 0; kk < 2; ++kk) {
            bf16x8 af[4], bfr[4];
            #pragma unroll
            for (int m = 0; m < 4; ++m) {
                const int row = wr*64 + m*16 + (lane & 15);
                const int j = (kk*4 + (lane >> 4)) ^ (row & 7);
                af[m] = *reinterpret_cast<const bf16x8*>(&As[row*64 + j*8]);
            }
            #pragma unroll
            for (int n = 0; n < 4; ++n) {
                const int row = wc*64 + n*16 + (lane & 15);
                const int j = (kk*4 + (lane >> 4)) ^ (row & 7);
                bfr[n] = *reinterpret_cast<const bf16x8*>(&Bs[row*64 + j*8]);
            }
            #pragma unroll
            for (int m = 0; m < 4; ++m)
                #pragma unroll
                for (int n = 0; n < 4; ++n)
                    acc[m][n] = __builtin_amdgcn_mfma_f32_16x16x32_bf16(af[m], bfr[n], acc[m][n], 0, 0, 0);
        }
        __syncthreads();
    }
    const int r4 = lane >> 4, cc = lane & 15;
    #pragma unroll
    for (int m = 0; m < 4; ++m) {
        #pragma unroll
        for (int r = 0; r < 4; ++r) {
            const int lrow = blockIdx.x*128 + wr*64 + m*16 + r4*4 + r;  // chunk-local
            #pragma unroll
            for (int n = 0; n < 4; ++n) {
                const int gcol = n0 + wc*64 + n*16 + cc;
                float f = acc[m][n][r] + b1[gcol];
                f = 0.5f * f * (1.f + erff(f * 0.70710678118654752f));
                c1[(size_t)lrow*FF + gcol] = f2bf(f);
            }
        }
    }
}

// ---------------- K5: MFMA GEMM2  out = xb + c1 @ W2^T + b2 (fp32, pre-LN) ----------------
// A: c1 [MCHUNK][1024] bf16 (chunk-local), B: W2b [256][1024] bf16.
__global__ __launch_bounds__(256) void k5_ffn2_mfma(
        const unsigned short* __restrict__ A, const unsigned short* __restrict__ B,
        const float* __restrict__ b2, const unsigned short* __restrict__ xb,
        float* __restrict__ out, int mbase) {
    __shared__ unsigned short As[128*64];
    __shared__ unsigned short Bs[128*64];
    const int t = threadIdx.x;
    const int wid = t >> 6, lane = t & 63;
    const int wr = wid >> 1, wc = wid & 1;
    const int lm0 = blockIdx.x*128;     // chunk-local A row base
    const int n0 = blockIdx.y*128;
    f32x4 acc[4][4] = {};
    for (int kt = 0; kt < FF/64; ++kt) {
        const int k0 = kt*64;
        #pragma unroll
        for (int i = 0; i < 4; ++i) {
            const int seg = i*256 + t;
            const int row = seg >> 3, jd = seg & 7;
            const int js = jd ^ (row & 7);
            gload_lds16(A + (size_t)(lm0+row)*FF + k0 + js*8, &As[(i*256 + wid*64)*8]);
            gload_lds16(B + (size_t)(n0+row)*FF + k0 + js*8, &Bs[(i*256 + wid*64)*8]);
        }
        __syncthreads();
        #pragma unroll
        for (int kk = 0; kk < 2; ++kk) {
            bf16x8 af[4], bfr[4];
            #pragma unroll
            for (int m = 0; m < 4; ++m) {
                const int row = wr*64 + m*16 + (lane & 15);
                const int j = (kk*4 + (lane >> 4)) ^ (row & 7);
                af[m] = *reinterpret_cast<const bf16x8*>(&As[row*64 + j*8]);
            }
            #pragma unroll
            for (int n = 0; n < 4; ++n) {
                const int row = wc*64 + n*16 + (lane & 15);
                const int j = (kk*4 + (lane >> 4)) ^ (row & 7);
                bfr[n] = *reinterpret_cast<const bf16x8*>(&Bs[row*64 + j*8]);
            }
            #pragma unroll
            for (int m = 0; m < 4; ++m)
                #pragma unroll
                for (int n = 0; n < 4; ++n)
                    acc[m][n] = __builtin_amdgcn_mfma_f32_16x16x32_bf16(af[m], bfr[n], acc[m][n], 0, 0, 0);
        }
        __syncthreads();
    }
    const int r4 = lane >> 4, cc = lane & 15;
    #pragma unroll
    for (int m = 0; m < 4; ++m) {
        #pragma unroll
        for (int r = 0; r < 4; ++r) {
            const int grow = mbase + blockIdx.x*128 + wr*64 + m*16 + r4*4 + r;
            #pragma unroll
            for (int n = 0; n < 4; ++n) {
                const int gcol = n0 + wc*64 + n*16 + cc;
                float f = acc[m][n][r] + b2[gcol] + bf2f(xb[(size_t)grow*C + gcol]);
                out[(size_t)grow*C + gcol] = f;
            }
        }
    }
}

// ---------------- K6: in-place LN2 over d_out rows ----------------
__global__ __launch_bounds__(256) void k6_ln2(
        float* __restrict__ o, const float* __restrict__ g2,
        const float* __restrict__ be2) {
    const int t = threadIdx.x;
    const int wid = t >> 6, lane = t & 63;
    const int row = blockIdx.x*4 + wid;
    float* p = o + (size_t)row*C + lane*4;
    float4 v = *reinterpret_cast<const float4*>(p);
    float s1 = v.x + v.y + v.z + v.w;
    float s2 = v.x*v.x + v.y*v.y + v.z*v.z + v.w*v.w;
    #pragma unroll
    for (int m = 32; m >= 1; m >>= 1) {
        s1 += __shfl_xor(s1, m, 64);
        s2 += __shfl_xor(s2, m, 64);
    }
    const float mean = s1 * (1.f/C);
    const float var  = s2 * (1.f/C) - mean*mean;
    const float rs = rsqrtf(var + 1e-5f);
    const int cb = lane*4;
    float4 w;
    w.x = (v.x - mean)*rs*g2[cb+0] + be2[cb+0];
    w.y = (v.y - mean)*rs*g2[cb+1] + be2[cb+1];
    w.z = (v.z - mean)*rs*g2[cb+2] + be2[cb+2];
    w.w = (v.w - mean)*rs*g2[cb+3] + be2[cb+3];
    *reinterpret_cast<float4*>(p) = w;
}

extern "C" void kernel_launch(void* const* d_in, const int* in_sizes, int n_in,
                              void* d_out, int out_size, void* d_ws, size_t ws_size,
                              hipStream_t stream) {
    const float* x    = (const float*)d_in[0];
    const float* Wkqv = (const float*)d_in[1];
    const float* W1   = (const float*)d_in[2];
    const float* b1   = (const float*)d_in[3];
    const float* W2   = (const float*)d_in[4];
    const float* b2   = (const float*)d_in[5];
    const float* g1   = (const float*)d_in[6];
    const float* be1  = (const float*)d_in[7];
    const float* g2   = (const float*)d_in[8];
    const float* be2  = (const float*)d_in[9];
    float* out = (float*)d_out;

    // ws layout (bytes):
    //   kv @ 0 | W1b @ 128K | W2b @ 640K | part @ 2M | xb @ 12M | c1 @ 48M  (~111 MB)
    char* wsb = (char*)d_ws;
    float* kv            = (float*)(wsb);
    unsigned short* W1b  = (unsigned short*)(wsb + (131072));
    unsigned short* W2b  = (unsigned short*)(wsb + (655360));
    float* part          = (float*)(wsb + ((size_t)2 << 20));
    unsigned short* xb   = (unsigned short*)(wsb + ((size_t)12 << 20));
    unsigned short* c1   = (unsigned short*)(wsb + ((size_t)48 << 20));

    k0_cvt<<<1024, 256, 0, stream>>>(W1, W2, W1b, W2b);
    k1_kv_partial<<<dim3(16, NCHUNK), 256, 0, stream>>>(x, Wkqv, part);
    k2_kv_reduce<<<16, 256, 0, stream>>>(part, kv);
    k3_attn_ln1<<<ROWS/4, 256, 0, stream>>>(x, Wkqv, kv, g1, be1, xb);
    for (int chunk = 0; chunk < 2; ++chunk) {
        const int mbase = chunk * MCHUNK;
        k4_ffn1_mfma<<<dim3(MCHUNK/128, FF/128), 256, 0, stream>>>(xb, W1b, b1, c1, mbase);
        k5_ffn2_mfma<<<dim3(MCHUNK/128, C/128), 256, 0, stream>>>(c1, W2b, b2, xb, out, mbase);
    }
    k6_ln2<<<ROWS/4, 256, 0, stream>>>(out, g2, be2);
}

// Round 4
// 402.343 us; speedup vs baseline: 3.0719x; 1.3636x over previous
//
#include <hip/hip_runtime.h>
#include <hip/hip_bf16.h>

#define BSZ 2
#define C 256
#define NH 8
#define DIM 32
#define LSEQ 30720
#define ROWS (BSZ*LSEQ)
#define FF 1024
#define NCHUNK 120
#define CHS 256
#define MCHUNK (ROWS/2)

typedef __attribute__((ext_vector_type(8))) short bf16x8;
typedef __attribute__((ext_vector_type(4))) float f32x4;

__device__ __forceinline__ float phi_elu1(float v) { return v > 0.f ? v + 1.f : __expf(v); }

// round-to-nearest-even f32 -> bf16 bits (finite inputs)
__device__ __forceinline__ unsigned short f2bf(float f) {
    unsigned int u = __float_as_uint(f);
    u += 0x7fffu + ((u >> 16) & 1u);
    return (unsigned short)(u >> 16);
}
__device__ __forceinline__ float bf2f(unsigned short u) {
    return __uint_as_float(((unsigned int)u) << 16);
}
__device__ __forceinline__ unsigned int pack2bf(float a, float b) {
    return (unsigned int)f2bf(a) | ((unsigned int)f2bf(b) << 16);
}

// async global->LDS, 16B per lane. LDS dest is wave-uniform base + lane*16.
__device__ __forceinline__ void gload_lds16(const unsigned short* g, unsigned short* l) {
    __builtin_amdgcn_global_load_lds(
        (const __attribute__((address_space(1))) unsigned int*)g,
        (__attribute__((address_space(3))) unsigned int*)l, 16, 0, 0);
}

// ---------------- K0: weights fp32 -> bf16 ----------------
__global__ __launch_bounds__(256) void k0_cvt(
        const float* __restrict__ W1, const float* __restrict__ W2,
        unsigned short* __restrict__ W1b, unsigned short* __restrict__ W2b) {
    const int i = blockIdx.x * 256 + threadIdx.x;   // 262144 total
    W1b[i] = f2bf(W1[i]);
    W2b[i] = f2bf(W2[i]);
}

// ---------------- K1: partial KV (32x32) + Ksum per (b,head,s-chunk) ----------------
__global__ __launch_bounds__(256) void k1_kv_partial(
        const float* __restrict__ x, const float* __restrict__ Wkqv,
        float* __restrict__ part) {
    __shared__ float Wk[DIM][DIM+1];
    __shared__ float Wv[DIM][DIM+1];
    __shared__ float KsT[DIM][CHS+1];
    __shared__ float VsT[DIM][CHS+1];
    const int t = threadIdx.x;
    const int bh = blockIdx.x;
    const int chunk = blockIdx.y;
    const int b = bh >> 3, head = bh & 7;
    for (int idx = t; idx < DIM*DIM; idx += 256) {
        int e = idx >> 5, d = idx & 31;
        Wk[e][d] = Wkqv[idx];
        Wv[e][d] = Wkqv[2*DIM*DIM + idx];
    }
    __syncthreads();
    const int s = chunk*CHS + t;
    const float* xr = x + ((size_t)(b*LSEQ + s))*C + head*DIM;
    float xv[DIM];
    #pragma unroll
    for (int i = 0; i < DIM/4; ++i) {
        float4 v4 = reinterpret_cast<const float4*>(xr)[i];
        xv[4*i+0]=v4.x; xv[4*i+1]=v4.y; xv[4*i+2]=v4.z; xv[4*i+3]=v4.w;
    }
    // v NOT divided by L, attn not multiplied by L — cancels exactly.
    #pragma unroll 4
    for (int e = 0; e < DIM; ++e) {
        float ak = 0.f, av = 0.f;
        #pragma unroll
        for (int d = 0; d < DIM; ++d) { ak += xv[d]*Wk[e][d]; av += xv[d]*Wv[e][d]; }
        KsT[e][t] = phi_elu1(ak);
        VsT[e][t] = av;
    }
    __syncthreads();
    const int d = t & 31, g = t >> 5;
    const int e0 = g*4;
    float acc0=0.f, acc1=0.f, acc2=0.f, acc3=0.f, ks=0.f;
    for (int s2 = 0; s2 < CHS; ++s2) {
        float kd = KsT[d][s2];
        ks += kd;
        acc0 += kd * VsT[e0+0][s2];
        acc1 += kd * VsT[e0+1][s2];
        acc2 += kd * VsT[e0+2][s2];
        acc3 += kd * VsT[e0+3][s2];
    }
    float* pb = part + ((size_t)bh*NCHUNK + chunk)*1056;
    float4 o = make_float4(acc0, acc1, acc2, acc3);
    *reinterpret_cast<float4*>(pb + d*32 + e0) = o;
    if (g == 0) pb[1024 + d] = ks;
}

// ---------------- K2: deterministic reduce ----------------
__global__ __launch_bounds__(256) void k2_kv_reduce(
        const float* __restrict__ part, float* __restrict__ kv) {
    const int bh = blockIdx.x, t = threadIdx.x;
    for (int i = t; i < 1056; i += 256) {
        float s = 0.f;
        for (int c2 = 0; c2 < NCHUNK; ++c2)
            s += part[((size_t)bh*NCHUNK + c2)*1056 + i];
        kv[bh*1056 + i] = s;
    }
}

// ---------------- K3 (MFMA): Q-proj + attn via 16x16x32, residual + LN1 -> xb ----------------
// One wave per 16 rows, 4 waves/block = 64 rows. No block barriers after staging.
// q-proj swapped operands: qT[e][m] = mfma(Wq_frag, X_frag) -> lane holds col m = lane&15.
// attnT[e][m] = mfma(KVT_frag, Qrow_frag). Q transposed D->A layout via per-wave LDS slot.
__global__ __launch_bounds__(256) void k3_attn_ln1_mfma(
        const float* __restrict__ x, const float* __restrict__ Wkqv,
        const float* __restrict__ kv, const float* __restrict__ g1,
        const float* __restrict__ be1, unsigned short* __restrict__ xb) {
    __shared__ __align__(16) unsigned short wq[32*40];        // Wq[e][d] bf16, pad 40
    __shared__ __align__(16) unsigned short kvt[NH*32*40];    // KV^T[h][e][d] bf16, pad 40
    __shared__ __align__(16) float ksm[NH*32];                // Ksum[h][d] f32
    __shared__ __align__(16) float gl[C], bl[C];
    __shared__ __align__(16) unsigned short qld[4][2][16*40]; // per-wave Q slot, dbuf by head parity
    const int t = threadIdx.x;
    const int wid = t >> 6, lane = t & 63;
    const int g = lane >> 4, m = lane & 15;
    const int row0 = blockIdx.x * 64;
    const int b = row0 / LSEQ;      // 64 | 30720 -> no straddle
    // ---- stage (once per block) ----
    for (int idx = t; idx < 1024; idx += 256) {
        int e = idx >> 5, d = idx & 31;
        wq[e*40 + d] = f2bf(Wkqv[1024 + idx]);        // q rows 32..63 of Wkqv
    }
    for (int idx = t; idx < NH*1024; idx += 256) {
        int h = idx >> 10, rem = idx & 1023;
        int d = rem >> 5, eo = rem & 31;
        kvt[h*1280 + eo*40 + d] = f2bf(kv[(size_t)(b*NH + h)*1056 + rem]);
    }
    {
        int h = t >> 5, d = t & 31;
        ksm[t] = kv[(size_t)(b*NH + h)*1056 + 1024 + d];
        gl[t] = g1[t];
        bl[t] = be1[t];
    }
    __syncthreads();

    const int row = row0 + wid*16 + m;
    f32x4 att[NH][2];
    const f32x4 zacc = {0.f, 0.f, 0.f, 0.f};
    #pragma unroll
    for (int h = 0; h < NH; ++h) {
        // X fragment (Q-operand): lane holds x[row][h*32 + g*8 .. +8] as bf16x8
        const float* xp = x + (size_t)row*C + h*32 + g*8;
        float4 xa = *reinterpret_cast<const float4*>(xp);
        float4 xc = *reinterpret_cast<const float4*>(xp + 4);
        bf16x8 xfrag;
        xfrag[0] = (short)f2bf(xa.x); xfrag[1] = (short)f2bf(xa.y);
        xfrag[2] = (short)f2bf(xa.z); xfrag[3] = (short)f2bf(xa.w);
        xfrag[4] = (short)f2bf(xc.x); xfrag[5] = (short)f2bf(xc.y);
        xfrag[6] = (short)f2bf(xc.z); xfrag[7] = (short)f2bf(xc.w);
        // Wq fragments (P-operand): lane holds Wq[e = m (+16)][g*8 .. +8]
        bf16x8 wf0 = *reinterpret_cast<const bf16x8*>(&wq[m*40 + g*8]);
        bf16x8 wf1 = *reinterpret_cast<const bf16x8*>(&wq[(16+m)*40 + g*8]);
        f32x4 q0 = __builtin_amdgcn_mfma_f32_16x16x32_bf16(wf0, xfrag, zacc, 0, 0, 0);
        f32x4 q1 = __builtin_amdgcn_mfma_f32_16x16x32_bf16(wf1, xfrag, zacc, 0, 0, 0);
        // phi = elu+1; lane holds Q[d = 4g+r][m] (q0) and Q[16+4g+r][m] (q1)
        #pragma unroll
        for (int r = 0; r < 4; ++r) { q0[r] = phi_elu1(q0[r]); q1[r] = phi_elu1(q1[r]); }
        // per-head Z: z[m] = sum_d Q[d][m]*Ksum[h][d]
        f32x4 ks0 = *reinterpret_cast<const f32x4*>(&ksm[h*32 + g*4]);
        f32x4 ks1 = *reinterpret_cast<const f32x4*>(&ksm[h*32 + 16 + g*4]);
        float zp = q0[0]*ks0[0] + q0[1]*ks0[1] + q0[2]*ks0[2] + q0[3]*ks0[3]
                 + q1[0]*ks1[0] + q1[1]*ks1[1] + q1[2]*ks1[2] + q1[3]*ks1[3];
        zp += __shfl_xor(zp, 16, 64);
        zp += __shfl_xor(zp, 32, 64);
        const float Z = 1.f / (zp + 1e-6f);
        // transpose Q (D-layout) -> Qrow (A-layout) via per-wave LDS slot
        unsigned short* slot = &qld[wid][h & 1][0];
        *reinterpret_cast<uint2*>(&slot[m*40 + g*4]) =
            make_uint2(pack2bf(q0[0], q0[1]), pack2bf(q0[2], q0[3]));
        *reinterpret_cast<uint2*>(&slot[m*40 + 16 + g*4]) =
            make_uint2(pack2bf(q1[0], q1[1]), pack2bf(q1[2], q1[3]));
        __builtin_amdgcn_wave_barrier();
        bf16x8 qrow = *reinterpret_cast<const bf16x8*>(&slot[m*40 + g*8]);
        __builtin_amdgcn_wave_barrier();
        // attnT[e][m] = sum_d KVT[e][d] * Qrow[m][d]
        bf16x8 kf0 = *reinterpret_cast<const bf16x8*>(&kvt[h*1280 + m*40 + g*8]);
        bf16x8 kf1 = *reinterpret_cast<const bf16x8*>(&kvt[h*1280 + (16+m)*40 + g*8]);
        f32x4 a0 = __builtin_amdgcn_mfma_f32_16x16x32_bf16(kf0, qrow, zacc, 0, 0, 0);
        f32x4 a1 = __builtin_amdgcn_mfma_f32_16x16x32_bf16(kf1, qrow, zacc, 0, 0, 0);
        #pragma unroll
        for (int r = 0; r < 4; ++r) { a0[r] *= Z; a1[r] *= Z; }
        att[h][0] = a0;   // cols h*32 + 4g + r
        att[h][1] = a1;   // cols h*32 + 16 + 4g + r
    }
    // ---- residual + LN1 ----
    float s1 = 0.f, s2 = 0.f;
    #pragma unroll
    for (int h = 0; h < NH; ++h) {
        #pragma unroll
        for (int n = 0; n < 2; ++n) {
            const int c0 = h*32 + n*16 + g*4;
            float4 xr = *reinterpret_cast<const float4*>(x + (size_t)row*C + c0);
            f32x4 v = att[h][n];
            v[0] += xr.x; v[1] += xr.y; v[2] += xr.z; v[3] += xr.w;
            att[h][n] = v;
            s1 += v[0] + v[1] + v[2] + v[3];
            s2 += v[0]*v[0] + v[1]*v[1] + v[2]*v[2] + v[3]*v[3];
        }
    }
    s1 += __shfl_xor(s1, 16, 64); s1 += __shfl_xor(s1, 32, 64);
    s2 += __shfl_xor(s2, 16, 64); s2 += __shfl_xor(s2, 32, 64);
    const float mean = s1 * (1.f/C);
    const float var  = s2 * (1.f/C) - mean*mean;
    const float rs = rsqrtf(var + 1e-5f);
    #pragma unroll
    for (int h = 0; h < NH; ++h) {
        #pragma unroll
        for (int n = 0; n < 2; ++n) {
            const int c0 = h*32 + n*16 + g*4;
            f32x4 gv = *reinterpret_cast<const f32x4*>(&gl[c0]);
            f32x4 bv = *reinterpret_cast<const f32x4*>(&bl[c0]);
            f32x4 v = att[h][n];
            float o0 = (v[0]-mean)*rs*gv[0] + bv[0];
            float o1 = (v[1]-mean)*rs*gv[1] + bv[1];
            float o2 = (v[2]-mean)*rs*gv[2] + bv[2];
            float o3 = (v[3]-mean)*rs*gv[3] + bv[3];
            *reinterpret_cast<uint2*>(xb + (size_t)row*C + c0) =
                make_uint2(pack2bf(o0, o1), pack2bf(o2, o3));
        }
    }
}

// ---------------- K4: MFMA GEMM1  c1 = gelu(xb @ W1^T + b1), bf16 out ----------------
__global__ __launch_bounds__(256) void k4_ffn1_mfma(
        const unsigned short* __restrict__ A, const unsigned short* __restrict__ B,
        const float* __restrict__ b1, unsigned short* __restrict__ c1, int mbase) {
    __shared__ unsigned short As[128*64];
    __shared__ unsigned short Bs[128*64];
    const int t = threadIdx.x;
    const int wid = t >> 6, lane = t & 63;
    const int wr = wid >> 1, wc = wid & 1;
    const int m0 = mbase + blockIdx.x*128;
    const int n0 = blockIdx.y*128;
    f32x4 acc[4][4] = {};
    for (int kt = 0; kt < C/64; ++kt) {
        const int k0 = kt*64;
        #pragma unroll
        for (int i = 0; i < 4; ++i) {
            const int seg = i*256 + t;              // 0..1023
            const int row = seg >> 3, jd = seg & 7;
            const int js = jd ^ (row & 7);          // pre-swizzled global source
            gload_lds16(A + (size_t)(m0+row)*C + k0 + js*8, &As[(i*256 + wid*64)*8]);
            gload_lds16(B + (size_t)(n0+row)*C + k0 + js*8, &Bs[(i*256 + wid*64)*8]);
        }
        __syncthreads();
        #pragma unroll
        for (int kk = 0; kk < 2; ++kk) {
            bf16x8 af[4], bfr[4];
            #pragma unroll
            for (int m = 0; m < 4; ++m) {
                const int row = wr*64 + m*16 + (lane & 15);
                const int j = (kk*4 + (lane >> 4)) ^ (row & 7);
                af[m] = *reinterpret_cast<const bf16x8*>(&As[row*64 + j*8]);
            }
            #pragma unroll
            for (int n = 0; n < 4; ++n) {
                const int row = wc*64 + n*16 + (lane & 15);
                const int j = (kk*4 + (lane >> 4)) ^ (row & 7);
                bfr[n] = *reinterpret_cast<const bf16x8*>(&Bs[row*64 + j*8]);
            }
            #pragma unroll
            for (int m = 0; m < 4; ++m)
                #pragma unroll
                for (int n = 0; n < 4; ++n)
                    acc[m][n] = __builtin_amdgcn_mfma_f32_16x16x32_bf16(af[m], bfr[n], acc[m][n], 0, 0, 0);
        }
        __syncthreads();
    }
    const int r4 = lane >> 4, cc = lane & 15;
    #pragma unroll
    for (int m = 0; m < 4; ++m) {
        #pragma unroll
        for (int r = 0; r < 4; ++r) {
            const int lrow = blockIdx.x*128 + wr*64 + m*16 + r4*4 + r;  // chunk-local
            #pragma unroll
            for (int n = 0; n < 4; ++n) {
                const int gcol = n0 + wc*64 + n*16 + cc;
                float f = acc[m][n][r] + b1[gcol];
                f = 0.5f * f * (1.f + erff(f * 0.70710678118654752f));
                c1[(size_t)lrow*FF + gcol] = f2bf(f);
            }
        }
    }
}

// ---------------- K5: MFMA GEMM2  out = xb + c1 @ W2^T + b2 (fp32, pre-LN) ----------------
__global__ __launch_bounds__(256) void k5_ffn2_mfma(
        const unsigned short* __restrict__ A, const unsigned short* __restrict__ B,
        const float* __restrict__ b2, const unsigned short* __restrict__ xb,
        float* __restrict__ out, int mbase) {
    __shared__ unsigned short As[128*64];
    __shared__ unsigned short Bs[128*64];
    const int t = threadIdx.x;
    const int wid = t >> 6, lane = t & 63;
    const int wr = wid >> 1, wc = wid & 1;
    const int lm0 = blockIdx.x*128;
    const int n0 = blockIdx.y*128;
    f32x4 acc[4][4] = {};
    for (int kt = 0; kt < FF/64; ++kt) {
        const int k0 = kt*64;
        #pragma unroll
        for (int i = 0; i < 4; ++i) {
            const int seg = i*256 + t;
            const int row = seg >> 3, jd = seg & 7;
            const int js = jd ^ (row & 7);
            gload_lds16(A + (size_t)(lm0+row)*FF + k0 + js*8, &As[(i*256 + wid*64)*8]);
            gload_lds16(B + (size_t)(n0+row)*FF + k0 + js*8, &Bs[(i*256 + wid*64)*8]);
        }
        __syncthreads();
        #pragma unroll
        for (int kk = 0; kk < 2; ++kk) {
            bf16x8 af[4], bfr[4];
            #pragma unroll
            for (int m = 0; m < 4; ++m) {
                const int row = wr*64 + m*16 + (lane & 15);
                const int j = (kk*4 + (lane >> 4)) ^ (row & 7);
                af[m] = *reinterpret_cast<const bf16x8*>(&As[row*64 + j*8]);
            }
            #pragma unroll
            for (int n = 0; n < 4; ++n) {
                const int row = wc*64 + n*16 + (lane & 15);
                const int j = (kk*4 + (lane >> 4)) ^ (row & 7);
                bfr[n] = *reinterpret_cast<const bf16x8*>(&Bs[row*64 + j*8]);
            }
            #pragma unroll
            for (int m = 0; m < 4; ++m)
                #pragma unroll
                for (int n = 0; n < 4; ++n)
                    acc[m][n] = __builtin_amdgcn_mfma_f32_16x16x32_bf16(af[m], bfr[n], acc[m][n], 0, 0, 0);
        }
        __syncthreads();
    }
    const int r4 = lane >> 4, cc = lane & 15;
    #pragma unroll
    for (int m = 0; m < 4; ++m) {
        #pragma unroll
        for (int r = 0; r < 4; ++r) {
            const int grow = mbase + blockIdx.x*128 + wr*64 + m*16 + r4*4 + r;
            #pragma unroll
            for (int n = 0; n < 4; ++n) {
                const int gcol = n0 + wc*64 + n*16 + cc;
                float f = acc[m][n][r] + b2[gcol] + bf2f(xb[(size_t)grow*C + gcol]);
                out[(size_t)grow*C + gcol] = f;
            }
        }
    }
}

// ---------------- K6: in-place LN2 over d_out rows ----------------
__global__ __launch_bounds__(256) void k6_ln2(
        float* __restrict__ o, const float* __restrict__ g2,
        const float* __restrict__ be2) {
    const int t = threadIdx.x;
    const int wid = t >> 6, lane = t & 63;
    const int row = blockIdx.x*4 + wid;
    float* p = o + (size_t)row*C + lane*4;
    float4 v = *reinterpret_cast<const float4*>(p);
    float s1 = v.x + v.y + v.z + v.w;
    float s2 = v.x*v.x + v.y*v.y + v.z*v.z + v.w*v.w;
    #pragma unroll
    for (int m = 32; m >= 1; m >>= 1) {
        s1 += __shfl_xor(s1, m, 64);
        s2 += __shfl_xor(s2, m, 64);
    }
    const float mean = s1 * (1.f/C);
    const float var  = s2 * (1.f/C) - mean*mean;
    const float rs = rsqrtf(var + 1e-5f);
    const int cb = lane*4;
    float4 w;
    w.x = (v.x - mean)*rs*g2[cb+0] + be2[cb+0];
    w.y = (v.y - mean)*rs*g2[cb+1] + be2[cb+1];
    w.z = (v.z - mean)*rs*g2[cb+2] + be2[cb+2];
    w.w = (v.w - mean)*rs*g2[cb+3] + be2[cb+3];
    *reinterpret_cast<float4*>(p) = w;
}

extern "C" void kernel_launch(void* const* d_in, const int* in_sizes, int n_in,
                              void* d_out, int out_size, void* d_ws, size_t ws_size,
                              hipStream_t stream) {
    const float* x    = (const float*)d_in[0];
    const float* Wkqv = (const float*)d_in[1];
    const float* W1   = (const float*)d_in[2];
    const float* b1   = (const float*)d_in[3];
    const float* W2   = (const float*)d_in[4];
    const float* b2   = (const float*)d_in[5];
    const float* g1   = (const float*)d_in[6];
    const float* be1  = (const float*)d_in[7];
    const float* g2   = (const float*)d_in[8];
    const float* be2  = (const float*)d_in[9];
    float* out = (float*)d_out;

    // ws layout (bytes):
    //   kv @ 0 | W1b @ 128K | W2b @ 640K | part @ 2M | xb @ 12M | c1 @ 48M  (~111 MB)
    char* wsb = (char*)d_ws;
    float* kv            = (float*)(wsb);
    unsigned short* W1b  = (unsigned short*)(wsb + (131072));
    unsigned short* W2b  = (unsigned short*)(wsb + (655360));
    float* part          = (float*)(wsb + ((size_t)2 << 20));
    unsigned short* xb   = (unsigned short*)(wsb + ((size_t)12 << 20));
    unsigned short* c1   = (unsigned short*)(wsb + ((size_t)48 << 20));

    k0_cvt<<<1024, 256, 0, stream>>>(W1, W2, W1b, W2b);
    k1_kv_partial<<<dim3(16, NCHUNK), 256, 0, stream>>>(x, Wkqv, part);
    k2_kv_reduce<<<16, 256, 0, stream>>>(part, kv);
    k3_attn_ln1_mfma<<<ROWS/64, 256, 0, stream>>>(x, Wkqv, kv, g1, be1, xb);
    for (int chunk = 0; chunk < 2; ++chunk) {
        const int mbase = chunk * MCHUNK;
        k4_ffn1_mfma<<<dim3(MCHUNK/128, FF/128), 256, 0, stream>>>(xb, W1b, b1, c1, mbase);
        k5_ffn2_mfma<<<dim3(MCHUNK/128, C/128), 256, 0, stream>>>(c1, W2b, b2, xb, out, mbase);
    }
    k6_ln2<<<ROWS/4, 256, 0, stream>>>(out, g2, be2);
}

// Round 5
// 279.988 us; speedup vs baseline: 4.4144x; 1.4370x over previous
//
#include <hip/hip_runtime.h>
#include <hip/hip_bf16.h>

#define BSZ 2
#define C 256
#define NH 8
#define DIM 32
#define LSEQ 30720
#define ROWS (BSZ*LSEQ)
#define FF 1024
#define NCHUNK 120
#define CHS 256
#define MCHUNK (ROWS/2)

typedef __attribute__((ext_vector_type(8))) short bf16x8;
typedef __attribute__((ext_vector_type(4))) float f32x4;

__device__ __forceinline__ float phi_elu1(float v) { return v > 0.f ? v + 1.f : __expf(v); }

// round-to-nearest-even f32 -> bf16 bits (finite inputs)
__device__ __forceinline__ unsigned short f2bf(float f) {
    unsigned int u = __float_as_uint(f);
    u += 0x7fffu + ((u >> 16) & 1u);
    return (unsigned short)(u >> 16);
}
__device__ __forceinline__ float bf2f(unsigned short u) {
    return __uint_as_float(((unsigned int)u) << 16);
}
__device__ __forceinline__ unsigned int pack2bf(float a, float b) {
    return (unsigned int)f2bf(a) | ((unsigned int)f2bf(b) << 16);
}

// async global->LDS, 16B per lane. LDS dest is wave-uniform base + lane*16.
__device__ __forceinline__ void gload_lds16(const unsigned short* g, unsigned short* l) {
    __builtin_amdgcn_global_load_lds(
        (const __attribute__((address_space(1))) unsigned int*)g,
        (__attribute__((address_space(3))) unsigned int*)l, 16, 0, 0);
}

// ---------------- K0: weights fp32 -> bf16 ----------------
__global__ __launch_bounds__(256) void k0_cvt(
        const float* __restrict__ W1, const float* __restrict__ W2,
        unsigned short* __restrict__ W1b, unsigned short* __restrict__ W2b) {
    const int i = blockIdx.x * 256 + threadIdx.x;   // 262144 total
    W1b[i] = f2bf(W1[i]);
    W2b[i] = f2bf(W2[i]);
}

// ---------------- K1 (MFMA): projection + partial KV(32x32) + Ksum per (b,h,chunk) ----------------
// Phase 1: KT[e][s16] = mfma(Wk_frag, X_frag) (swapped operands, k3-verified layout),
//          phi applied in-register, stored bf16 transposed: KsT[e][s], VsT[e][s].
// Phase 2: KV_partial = mfma(A=K^T, B=V): A-frag = KsT row (lane&15), B-frag = VsT row
//          (lane&15), k = s. Row stride 264 ushorts -> b128 reads 8 words/bank (balanced).
__global__ __launch_bounds__(256) void k1_kv_partial_mfma(
        const float* __restrict__ x, const float* __restrict__ Wkqv,
        float* __restrict__ part) {
    __shared__ __align__(16) unsigned short KsT[32*264];
    __shared__ __align__(16) unsigned short VsT[32*264];
    __shared__ __align__(16) float red[4][32][33];
    __shared__ __align__(16) float ksr[8][32];
    const int t = threadIdx.x;
    const int w = t >> 6, lane = t & 63;
    const int g = lane >> 4, m = lane & 15;
    const int bh = blockIdx.x, chunk = blockIdx.y;
    const int b = bh >> 3, head = bh & 7;
    const size_t rowbase = (size_t)b*LSEQ + (size_t)chunk*CHS;

    // weight A-fragments: lane holds W[e = half*16 + m][d = g*8 .. +8)
    bf16x8 wk[2], wv[2];
    #pragma unroll
    for (int half = 0; half < 2; ++half) {
        const float* kp = Wkqv + (half*16 + m)*DIM + g*8;   // K rows 0..31
        const float* vp = kp + 2*DIM*DIM;                   // V rows 64..95
        float4 ka = *reinterpret_cast<const float4*>(kp);
        float4 kb = *reinterpret_cast<const float4*>(kp + 4);
        float4 va = *reinterpret_cast<const float4*>(vp);
        float4 vb = *reinterpret_cast<const float4*>(vp + 4);
        wk[half][0]=(short)f2bf(ka.x); wk[half][1]=(short)f2bf(ka.y);
        wk[half][2]=(short)f2bf(ka.z); wk[half][3]=(short)f2bf(ka.w);
        wk[half][4]=(short)f2bf(kb.x); wk[half][5]=(short)f2bf(kb.y);
        wk[half][6]=(short)f2bf(kb.z); wk[half][7]=(short)f2bf(kb.w);
        wv[half][0]=(short)f2bf(va.x); wv[half][1]=(short)f2bf(va.y);
        wv[half][2]=(short)f2bf(va.z); wv[half][3]=(short)f2bf(va.w);
        wv[half][4]=(short)f2bf(vb.x); wv[half][5]=(short)f2bf(vb.y);
        wv[half][6]=(short)f2bf(vb.z); wv[half][7]=(short)f2bf(vb.w);
    }
    const f32x4 zac = {0.f, 0.f, 0.f, 0.f};
    // ---- phase 1: each wave projects 64 s-values ----
    #pragma unroll
    for (int sg = 0; sg < 4; ++sg) {
        const int sl = w*64 + sg*16 + m;        // s-local, also this lane's D col
        const float* xp = x + (rowbase + sl)*C + head*DIM + g*8;
        float4 xa = *reinterpret_cast<const float4*>(xp);
        float4 xc = *reinterpret_cast<const float4*>(xp + 4);
        bf16x8 xf;
        xf[0]=(short)f2bf(xa.x); xf[1]=(short)f2bf(xa.y);
        xf[2]=(short)f2bf(xa.z); xf[3]=(short)f2bf(xa.w);
        xf[4]=(short)f2bf(xc.x); xf[5]=(short)f2bf(xc.y);
        xf[6]=(short)f2bf(xc.z); xf[7]=(short)f2bf(xc.w);
        f32x4 kt0 = __builtin_amdgcn_mfma_f32_16x16x32_bf16(wk[0], xf, zac, 0, 0, 0);
        f32x4 kt1 = __builtin_amdgcn_mfma_f32_16x16x32_bf16(wk[1], xf, zac, 0, 0, 0);
        f32x4 vt0 = __builtin_amdgcn_mfma_f32_16x16x32_bf16(wv[0], xf, zac, 0, 0, 0);
        f32x4 vt1 = __builtin_amdgcn_mfma_f32_16x16x32_bf16(wv[1], xf, zac, 0, 0, 0);
        #pragma unroll
        for (int r = 0; r < 4; ++r) {          // lane holds rows e = 4g+r (+16)
            KsT[(4*g+r)*264 + sl]    = f2bf(phi_elu1(kt0[r]));
            KsT[(16+4*g+r)*264 + sl] = f2bf(phi_elu1(kt1[r]));
            VsT[(4*g+r)*264 + sl]    = f2bf(vt0[r]);
            VsT[(16+4*g+r)*264 + sl] = f2bf(vt1[r]);
        }
    }
    __syncthreads();
    // ---- phase 2: KV partial over this wave's 64 s ----
    f32x4 acc[2][2] = {};
    #pragma unroll
    for (int ss = 0; ss < 2; ++ss) {
        const int s0 = w*64 + ss*32 + g*8;      // k-slice this lane reads
        bf16x8 aK0 = *reinterpret_cast<const bf16x8*>(&KsT[m*264 + s0]);
        bf16x8 aK1 = *reinterpret_cast<const bf16x8*>(&KsT[(16+m)*264 + s0]);
        bf16x8 bV0 = *reinterpret_cast<const bf16x8*>(&VsT[m*264 + s0]);
        bf16x8 bV1 = *reinterpret_cast<const bf16x8*>(&VsT[(16+m)*264 + s0]);
        acc[0][0] = __builtin_amdgcn_mfma_f32_16x16x32_bf16(aK0, bV0, acc[0][0], 0, 0, 0);
        acc[0][1] = __builtin_amdgcn_mfma_f32_16x16x32_bf16(aK0, bV1, acc[0][1], 0, 0, 0);
        acc[1][0] = __builtin_amdgcn_mfma_f32_16x16x32_bf16(aK1, bV0, acc[1][0], 0, 0, 0);
        acc[1][1] = __builtin_amdgcn_mfma_f32_16x16x32_bf16(aK1, bV1, acc[1][1], 0, 0, 0);
    }
    // Ksum partials: thread t sums KsT[d = t&31][s in oct window]
    {
        const int d = t & 31, oct = t >> 5;
        float s = 0.f;
        #pragma unroll
        for (int q = 0; q < 4; ++q) {
            bf16x8 kb = *reinterpret_cast<const bf16x8*>(&KsT[d*264 + oct*32 + q*8]);
            #pragma unroll
            for (int j = 0; j < 8; ++j) s += bf2f((unsigned short)kb[j]);
        }
        ksr[oct][d] = s;
    }
    // spill per-wave KV partials (D layout: row d = 16i+4g+r, col e = 16j+m)
    #pragma unroll
    for (int i = 0; i < 2; ++i)
        #pragma unroll
        for (int j = 0; j < 2; ++j)
            #pragma unroll
            for (int r = 0; r < 4; ++r)
                red[w][i*16 + 4*g + r][j*16 + m] = acc[i][j][r];
    __syncthreads();
    // ---- final cross-wave reduce + store ----
    float* pb = part + ((size_t)bh*NCHUNK + chunk)*1056;
    {
        const int d = t >> 3, e0 = (t & 7)*4;
        float4 sum;
        sum.x = red[0][d][e0+0]+red[1][d][e0+0]+red[2][d][e0+0]+red[3][d][e0+0];
        sum.y = red[0][d][e0+1]+red[1][d][e0+1]+red[2][d][e0+1]+red[3][d][e0+1];
        sum.z = red[0][d][e0+2]+red[1][d][e0+2]+red[2][d][e0+2]+red[3][d][e0+2];
        sum.w = red[0][d][e0+3]+red[1][d][e0+3]+red[2][d][e0+3]+red[3][d][e0+3];
        *reinterpret_cast<float4*>(pb + d*32 + e0) = sum;
    }
    if (t < 32) {
        float ks = 0.f;
        #pragma unroll
        for (int o = 0; o < 8; ++o) ks += ksr[o][t];
        pb[1024 + t] = ks;
    }
}

// ---------------- K2: deterministic reduce ----------------
__global__ __launch_bounds__(256) void k2_kv_reduce(
        const float* __restrict__ part, float* __restrict__ kv) {
    const int bh = blockIdx.x, t = threadIdx.x;
    for (int i = t; i < 1056; i += 256) {
        float s = 0.f;
        for (int c2 = 0; c2 < NCHUNK; ++c2)
            s += part[((size_t)bh*NCHUNK + c2)*1056 + i];
        kv[bh*1056 + i] = s;
    }
}

// ---------------- K3 (MFMA): Q-proj + attn via 16x16x32, residual + LN1 -> xb ----------------
__global__ __launch_bounds__(256) void k3_attn_ln1_mfma(
        const float* __restrict__ x, const float* __restrict__ Wkqv,
        const float* __restrict__ kv, const float* __restrict__ g1,
        const float* __restrict__ be1, unsigned short* __restrict__ xb) {
    __shared__ __align__(16) unsigned short wq[32*40];        // Wq[e][d] bf16, pad 40
    __shared__ __align__(16) unsigned short kvt[NH*32*40];    // KV^T[h][e][d] bf16, pad 40
    __shared__ __align__(16) float ksm[NH*32];                // Ksum[h][d] f32
    __shared__ __align__(16) float gl[C], bl[C];
    __shared__ __align__(16) unsigned short qld[4][2][16*40]; // per-wave Q slot, dbuf by head parity
    const int t = threadIdx.x;
    const int wid = t >> 6, lane = t & 63;
    const int g = lane >> 4, m = lane & 15;
    const int row0 = blockIdx.x * 64;
    const int b = row0 / LSEQ;      // 64 | 30720 -> no straddle
    for (int idx = t; idx < 1024; idx += 256) {
        int e = idx >> 5, d = idx & 31;
        wq[e*40 + d] = f2bf(Wkqv[1024 + idx]);        // q rows 32..63 of Wkqv
    }
    for (int idx = t; idx < NH*1024; idx += 256) {
        int h = idx >> 10, rem = idx & 1023;
        int d = rem >> 5, eo = rem & 31;
        kvt[h*1280 + eo*40 + d] = f2bf(kv[(size_t)(b*NH + h)*1056 + rem]);
    }
    {
        int h = t >> 5, d = t & 31;
        ksm[t] = kv[(size_t)(b*NH + h)*1056 + 1024 + d];
        gl[t] = g1[t];
        bl[t] = be1[t];
    }
    __syncthreads();

    const int row = row0 + wid*16 + m;
    f32x4 att[NH][2];
    const f32x4 zacc = {0.f, 0.f, 0.f, 0.f};
    #pragma unroll
    for (int h = 0; h < NH; ++h) {
        const float* xp = x + (size_t)row*C + h*32 + g*8;
        float4 xa = *reinterpret_cast<const float4*>(xp);
        float4 xc = *reinterpret_cast<const float4*>(xp + 4);
        bf16x8 xfrag;
        xfrag[0] = (short)f2bf(xa.x); xfrag[1] = (short)f2bf(xa.y);
        xfrag[2] = (short)f2bf(xa.z); xfrag[3] = (short)f2bf(xa.w);
        xfrag[4] = (short)f2bf(xc.x); xfrag[5] = (short)f2bf(xc.y);
        xfrag[6] = (short)f2bf(xc.z); xfrag[7] = (short)f2bf(xc.w);
        bf16x8 wf0 = *reinterpret_cast<const bf16x8*>(&wq[m*40 + g*8]);
        bf16x8 wf1 = *reinterpret_cast<const bf16x8*>(&wq[(16+m)*40 + g*8]);
        f32x4 q0 = __builtin_amdgcn_mfma_f32_16x16x32_bf16(wf0, xfrag, zacc, 0, 0, 0);
        f32x4 q1 = __builtin_amdgcn_mfma_f32_16x16x32_bf16(wf1, xfrag, zacc, 0, 0, 0);
        #pragma unroll
        for (int r = 0; r < 4; ++r) { q0[r] = phi_elu1(q0[r]); q1[r] = phi_elu1(q1[r]); }
        f32x4 ks0 = *reinterpret_cast<const f32x4*>(&ksm[h*32 + g*4]);
        f32x4 ks1 = *reinterpret_cast<const f32x4*>(&ksm[h*32 + 16 + g*4]);
        float zp = q0[0]*ks0[0] + q0[1]*ks0[1] + q0[2]*ks0[2] + q0[3]*ks0[3]
                 + q1[0]*ks1[0] + q1[1]*ks1[1] + q1[2]*ks1[2] + q1[3]*ks1[3];
        zp += __shfl_xor(zp, 16, 64);
        zp += __shfl_xor(zp, 32, 64);
        const float Z = 1.f / (zp + 1e-6f);
        unsigned short* slot = &qld[wid][h & 1][0];
        *reinterpret_cast<uint2*>(&slot[m*40 + g*4]) =
            make_uint2(pack2bf(q0[0], q0[1]), pack2bf(q0[2], q0[3]));
        *reinterpret_cast<uint2*>(&slot[m*40 + 16 + g*4]) =
            make_uint2(pack2bf(q1[0], q1[1]), pack2bf(q1[2], q1[3]));
        __builtin_amdgcn_wave_barrier();
        bf16x8 qrow = *reinterpret_cast<const bf16x8*>(&slot[m*40 + g*8]);
        __builtin_amdgcn_wave_barrier();
        bf16x8 kf0 = *reinterpret_cast<const bf16x8*>(&kvt[h*1280 + m*40 + g*8]);
        bf16x8 kf1 = *reinterpret_cast<const bf16x8*>(&kvt[h*1280 + (16+m)*40 + g*8]);
        f32x4 a0 = __builtin_amdgcn_mfma_f32_16x16x32_bf16(kf0, qrow, zacc, 0, 0, 0);
        f32x4 a1 = __builtin_amdgcn_mfma_f32_16x16x32_bf16(kf1, qrow, zacc, 0, 0, 0);
        #pragma unroll
        for (int r = 0; r < 4; ++r) { a0[r] *= Z; a1[r] *= Z; }
        att[h][0] = a0;
        att[h][1] = a1;
    }
    float s1 = 0.f, s2 = 0.f;
    #pragma unroll
    for (int h = 0; h < NH; ++h) {
        #pragma unroll
        for (int n = 0; n < 2; ++n) {
            const int c0 = h*32 + n*16 + g*4;
            float4 xr = *reinterpret_cast<const float4*>(x + (size_t)row*C + c0);
            f32x4 v = att[h][n];
            v[0] += xr.x; v[1] += xr.y; v[2] += xr.z; v[3] += xr.w;
            att[h][n] = v;
            s1 += v[0] + v[1] + v[2] + v[3];
            s2 += v[0]*v[0] + v[1]*v[1] + v[2]*v[2] + v[3]*v[3];
        }
    }
    s1 += __shfl_xor(s1, 16, 64); s1 += __shfl_xor(s1, 32, 64);
    s2 += __shfl_xor(s2, 16, 64); s2 += __shfl_xor(s2, 32, 64);
    const float mean = s1 * (1.f/C);
    const float var  = s2 * (1.f/C) - mean*mean;
    const float rs = rsqrtf(var + 1e-5f);
    #pragma unroll
    for (int h = 0; h < NH; ++h) {
        #pragma unroll
        for (int n = 0; n < 2; ++n) {
            const int c0 = h*32 + n*16 + g*4;
            f32x4 gv = *reinterpret_cast<const f32x4*>(&gl[c0]);
            f32x4 bv = *reinterpret_cast<const f32x4*>(&bl[c0]);
            f32x4 v = att[h][n];
            float o0 = (v[0]-mean)*rs*gv[0] + bv[0];
            float o1 = (v[1]-mean)*rs*gv[1] + bv[1];
            float o2 = (v[2]-mean)*rs*gv[2] + bv[2];
            float o3 = (v[3]-mean)*rs*gv[3] + bv[3];
            *reinterpret_cast<uint2*>(xb + (size_t)row*C + c0) =
                make_uint2(pack2bf(o0, o1), pack2bf(o2, o3));
        }
    }
}

// ---------------- K4: MFMA GEMM1  c1 = gelu(xb @ W1^T + b1), bf16 out ----------------
__global__ __launch_bounds__(256) void k4_ffn1_mfma(
        const unsigned short* __restrict__ A, const unsigned short* __restrict__ B,
        const float* __restrict__ b1, unsigned short* __restrict__ c1, int mbase) {
    __shared__ unsigned short As[128*64];
    __shared__ unsigned short Bs[128*64];
    const int t = threadIdx.x;
    const int wid = t >> 6, lane = t & 63;
    const int wr = wid >> 1, wc = wid & 1;
    const int m0 = mbase + blockIdx.x*128;
    const int n0 = blockIdx.y*128;
    f32x4 acc[4][4] = {};
    for (int kt = 0; kt < C/64; ++kt) {
        const int k0 = kt*64;
        #pragma unroll
        for (int i = 0; i < 4; ++i) {
            const int seg = i*256 + t;              // 0..1023
            const int row = seg >> 3, jd = seg & 7;
            const int js = jd ^ (row & 7);          // pre-swizzled global source
            gload_lds16(A + (size_t)(m0+row)*C + k0 + js*8, &As[(i*256 + wid*64)*8]);
            gload_lds16(B + (size_t)(n0+row)*C + k0 + js*8, &Bs[(i*256 + wid*64)*8]);
        }
        __syncthreads();
        #pragma unroll
        for (int kk = 0; kk < 2; ++kk) {
            bf16x8 af[4], bfr[4];
            #pragma unroll
            for (int m = 0; m < 4; ++m) {
                const int row = wr*64 + m*16 + (lane & 15);
                const int j = (kk*4 + (lane >> 4)) ^ (row & 7);
                af[m] = *reinterpret_cast<const bf16x8*>(&As[row*64 + j*8]);
            }
            #pragma unroll
            for (int n = 0; n < 4; ++n) {
                const int row = wc*64 + n*16 + (lane & 15);
                const int j = (kk*4 + (lane >> 4)) ^ (row & 7);
                bfr[n] = *reinterpret_cast<const bf16x8*>(&Bs[row*64 + j*8]);
            }
            #pragma unroll
            for (int m = 0; m < 4; ++m)
                #pragma unroll
                for (int n = 0; n < 4; ++n)
                    acc[m][n] = __builtin_amdgcn_mfma_f32_16x16x32_bf16(af[m], bfr[n], acc[m][n], 0, 0, 0);
        }
        __syncthreads();
    }
    const int r4 = lane >> 4, cc = lane & 15;
    #pragma unroll
    for (int m = 0; m < 4; ++m) {
        #pragma unroll
        for (int r = 0; r < 4; ++r) {
            const int lrow = blockIdx.x*128 + wr*64 + m*16 + r4*4 + r;  // chunk-local
            #pragma unroll
            for (int n = 0; n < 4; ++n) {
                const int gcol = n0 + wc*64 + n*16 + cc;
                float f = acc[m][n][r] + b1[gcol];
                f = 0.5f * f * (1.f + erff(f * 0.70710678118654752f));
                c1[(size_t)lrow*FF + gcol] = f2bf(f);
            }
        }
    }
}

// ---------------- K5: MFMA GEMM2  out = xb + c1 @ W2^T + b2 (fp32, pre-LN) ----------------
__global__ __launch_bounds__(256) void k5_ffn2_mfma(
        const unsigned short* __restrict__ A, const unsigned short* __restrict__ B,
        const float* __restrict__ b2, const unsigned short* __restrict__ xb,
        float* __restrict__ out, int mbase) {
    __shared__ unsigned short As[128*64];
    __shared__ unsigned short Bs[128*64];
    const int t = threadIdx.x;
    const int wid = t >> 6, lane = t & 63;
    const int wr = wid >> 1, wc = wid & 1;
    const int lm0 = blockIdx.x*128;
    const int n0 = blockIdx.y*128;
    f32x4 acc[4][4] = {};
    for (int kt = 0; kt < FF/64; ++kt) {
        const int k0 = kt*64;
        #pragma unroll
        for (int i = 0; i < 4; ++i) {
            const int seg = i*256 + t;
            const int row = seg >> 3, jd = seg & 7;
            const int js = jd ^ (row & 7);
            gload_lds16(A + (size_t)(lm0+row)*FF + k0 + js*8, &As[(i*256 + wid*64)*8]);
            gload_lds16(B + (size_t)(n0+row)*FF + k0 + js*8, &Bs[(i*256 + wid*64)*8]);
        }
        __syncthreads();
        #pragma unroll
        for (int kk = 0; kk < 2; ++kk) {
            bf16x8 af[4], bfr[4];
            #pragma unroll
            for (int m = 0; m < 4; ++m) {
                const int row = wr*64 + m*16 + (lane & 15);
                const int j = (kk*4 + (lane >> 4)) ^ (row & 7);
                af[m] = *reinterpret_cast<const bf16x8*>(&As[row*64 + j*8]);
            }
            #pragma unroll
            for (int n = 0; n < 4; ++n) {
                const int row = wc*64 + n*16 + (lane & 15);
                const int j = (kk*4 + (lane >> 4)) ^ (row & 7);
                bfr[n] = *reinterpret_cast<const bf16x8*>(&Bs[row*64 + j*8]);
            }
            #pragma unroll
            for (int m = 0; m < 4; ++m)
                #pragma unroll
                for (int n = 0; n < 4; ++n)
                    acc[m][n] = __builtin_amdgcn_mfma_f32_16x16x32_bf16(af[m], bfr[n], acc[m][n], 0, 0, 0);
        }
        __syncthreads();
    }
    const int r4 = lane >> 4, cc = lane & 15;
    #pragma unroll
    for (int m = 0; m < 4; ++m) {
        #pragma unroll
        for (int r = 0; r < 4; ++r) {
            const int grow = mbase + blockIdx.x*128 + wr*64 + m*16 + r4*4 + r;
            #pragma unroll
            for (int n = 0; n < 4; ++n) {
                const int gcol = n0 + wc*64 + n*16 + cc;
                float f = acc[m][n][r] + b2[gcol] + bf2f(xb[(size_t)grow*C + gcol]);
                out[(size_t)grow*C + gcol] = f;
            }
        }
    }
}

// ---------------- K6: in-place LN2 over d_out rows ----------------
__global__ __launch_bounds__(256) void k6_ln2(
        float* __restrict__ o, const float* __restrict__ g2,
        const float* __restrict__ be2) {
    const int t = threadIdx.x;
    const int wid = t >> 6, lane = t & 63;
    const int row = blockIdx.x*4 + wid;
    float* p = o + (size_t)row*C + lane*4;
    float4 v = *reinterpret_cast<const float4*>(p);
    float s1 = v.x + v.y + v.z + v.w;
    float s2 = v.x*v.x + v.y*v.y + v.z*v.z + v.w*v.w;
    #pragma unroll
    for (int m = 32; m >= 1; m >>= 1) {
        s1 += __shfl_xor(s1, m, 64);
        s2 += __shfl_xor(s2, m, 64);
    }
    const float mean = s1 * (1.f/C);
    const float var  = s2 * (1.f/C) - mean*mean;
    const float rs = rsqrtf(var + 1e-5f);
    const int cb = lane*4;
    float4 w;
    w.x = (v.x - mean)*rs*g2[cb+0] + be2[cb+0];
    w.y = (v.y - mean)*rs*g2[cb+1] + be2[cb+1];
    w.z = (v.z - mean)*rs*g2[cb+2] + be2[cb+2];
    w.w = (v.w - mean)*rs*g2[cb+3] + be2[cb+3];
    *reinterpret_cast<float4*>(p) = w;
}

extern "C" void kernel_launch(void* const* d_in, const int* in_sizes, int n_in,
                              void* d_out, int out_size, void* d_ws, size_t ws_size,
                              hipStream_t stream) {
    const float* x    = (const float*)d_in[0];
    const float* Wkqv = (const float*)d_in[1];
    const float* W1   = (const float*)d_in[2];
    const float* b1   = (const float*)d_in[3];
    const float* W2   = (const float*)d_in[4];
    const float* b2   = (const float*)d_in[5];
    const float* g1   = (const float*)d_in[6];
    const float* be1  = (const float*)d_in[7];
    const float* g2   = (const float*)d_in[8];
    const float* be2  = (const float*)d_in[9];
    float* out = (float*)d_out;

    // ws layout (bytes):
    //   kv @ 0 | W1b @ 128K | W2b @ 640K | part @ 2M | xb @ 12M | c1 @ 48M  (~111 MB)
    char* wsb = (char*)d_ws;
    float* kv            = (float*)(wsb);
    unsigned short* W1b  = (unsigned short*)(wsb + (131072));
    unsigned short* W2b  = (unsigned short*)(wsb + (655360));
    float* part          = (float*)(wsb + ((size_t)2 << 20));
    unsigned short* xb   = (unsigned short*)(wsb + ((size_t)12 << 20));
    unsigned short* c1   = (unsigned short*)(wsb + ((size_t)48 << 20));

    k0_cvt<<<1024, 256, 0, stream>>>(W1, W2, W1b, W2b);
    k1_kv_partial_mfma<<<dim3(16, NCHUNK), 256, 0, stream>>>(x, Wkqv, part);
    k2_kv_reduce<<<16, 256, 0, stream>>>(part, kv);
    k3_attn_ln1_mfma<<<ROWS/64, 256, 0, stream>>>(x, Wkqv, kv, g1, be1, xb);
    for (int chunk = 0; chunk < 2; ++chunk) {
        const int mbase = chunk * MCHUNK;
        k4_ffn1_mfma<<<dim3(MCHUNK/128, FF/128), 256, 0, stream>>>(xb, W1b, b1, c1, mbase);
        k5_ffn2_mfma<<<dim3(MCHUNK/128, C/128), 256, 0, stream>>>(c1, W2b, b2, xb, out, mbase);
    }
    k6_ln2<<<ROWS/4, 256, 0, stream>>>(out, g2, be2);
}

// Round 6
// 252.398 us; speedup vs baseline: 4.8969x; 1.1093x over previous
//
#include <hip/hip_runtime.h>
#include <hip/hip_bf16.h>

#define BSZ 2
#define C 256
#define NH 8
#define DIM 32
#define LSEQ 30720
#define ROWS (BSZ*LSEQ)
#define FF 1024
#define NCHUNK 120
#define CHS 256
#define MCHUNK (ROWS/2)

typedef __attribute__((ext_vector_type(8))) short bf16x8;
typedef __attribute__((ext_vector_type(4))) float f32x4;

__device__ __forceinline__ float phi_elu1(float v) { return v > 0.f ? v + 1.f : __expf(v); }

// tanh-form gelu: 0.5x(1+tanh(sqrt(2/pi)(x+0.044715x^3))), tanh via expf.
// |err| vs exact erf-gelu <= ~1e-3; NaN-free (exp->inf => t->1, exp->0 => t->-1).
__device__ __forceinline__ float fast_gelu(float x) {
    float inner = 0.7978845608028654f * (x + 0.044715f * x * x * x);
    float e2 = __expf(2.f * inner);
    float th = 1.f - 2.f / (e2 + 1.f);
    return 0.5f * x * (1.f + th);
}

// round-to-nearest-even f32 -> bf16 bits (finite inputs)
__device__ __forceinline__ unsigned short f2bf(float f) {
    unsigned int u = __float_as_uint(f);
    u += 0x7fffu + ((u >> 16) & 1u);
    return (unsigned short)(u >> 16);
}
__device__ __forceinline__ float bf2f(unsigned short u) {
    return __uint_as_float(((unsigned int)u) << 16);
}
__device__ __forceinline__ unsigned int pack2bf(float a, float b) {
    return (unsigned int)f2bf(a) | ((unsigned int)f2bf(b) << 16);
}

// async global->LDS, 16B per lane. LDS dest is wave-uniform base + lane*16.
__device__ __forceinline__ void gload_lds16(const unsigned short* g, unsigned short* l) {
    __builtin_amdgcn_global_load_lds(
        (const __attribute__((address_space(1))) unsigned int*)g,
        (__attribute__((address_space(3))) unsigned int*)l, 16, 0, 0);
}

// ---------------- K0: weights fp32 -> bf16 ----------------
__global__ __launch_bounds__(256) void k0_cvt(
        const float* __restrict__ W1, const float* __restrict__ W2,
        unsigned short* __restrict__ W1b, unsigned short* __restrict__ W2b) {
    const int i = blockIdx.x * 256 + threadIdx.x;   // 262144 total
    W1b[i] = f2bf(W1[i]);
    W2b[i] = f2bf(W2[i]);
}

// ---------------- K1 (MFMA): projection + partial KV(32x32) + Ksum per (b,h,chunk) ----------------
__global__ __launch_bounds__(256) void k1_kv_partial_mfma(
        const float* __restrict__ x, const float* __restrict__ Wkqv,
        float* __restrict__ part) {
    __shared__ __align__(16) unsigned short KsT[32*264];
    __shared__ __align__(16) unsigned short VsT[32*264];
    __shared__ __align__(16) float red[4][32][33];
    __shared__ __align__(16) float ksr[8][32];
    const int t = threadIdx.x;
    const int w = t >> 6, lane = t & 63;
    const int g = lane >> 4, m = lane & 15;
    const int bh = blockIdx.x, chunk = blockIdx.y;
    const int b = bh >> 3, head = bh & 7;
    const size_t rowbase = (size_t)b*LSEQ + (size_t)chunk*CHS;

    bf16x8 wk[2], wv[2];
    #pragma unroll
    for (int half = 0; half < 2; ++half) {
        const float* kp = Wkqv + (half*16 + m)*DIM + g*8;   // K rows 0..31
        const float* vp = kp + 2*DIM*DIM;                   // V rows 64..95
        float4 ka = *reinterpret_cast<const float4*>(kp);
        float4 kb = *reinterpret_cast<const float4*>(kp + 4);
        float4 va = *reinterpret_cast<const float4*>(vp);
        float4 vb = *reinterpret_cast<const float4*>(vp + 4);
        wk[half][0]=(short)f2bf(ka.x); wk[half][1]=(short)f2bf(ka.y);
        wk[half][2]=(short)f2bf(ka.z); wk[half][3]=(short)f2bf(ka.w);
        wk[half][4]=(short)f2bf(kb.x); wk[half][5]=(short)f2bf(kb.y);
        wk[half][6]=(short)f2bf(kb.z); wk[half][7]=(short)f2bf(kb.w);
        wv[half][0]=(short)f2bf(va.x); wv[half][1]=(short)f2bf(va.y);
        wv[half][2]=(short)f2bf(va.z); wv[half][3]=(short)f2bf(va.w);
        wv[half][4]=(short)f2bf(vb.x); wv[half][5]=(short)f2bf(vb.y);
        wv[half][6]=(short)f2bf(vb.z); wv[half][7]=(short)f2bf(vb.w);
    }
    const f32x4 zac = {0.f, 0.f, 0.f, 0.f};
    #pragma unroll
    for (int sg = 0; sg < 4; ++sg) {
        const int sl = w*64 + sg*16 + m;
        const float* xp = x + (rowbase + sl)*C + head*DIM + g*8;
        float4 xa = *reinterpret_cast<const float4*>(xp);
        float4 xc = *reinterpret_cast<const float4*>(xp + 4);
        bf16x8 xf;
        xf[0]=(short)f2bf(xa.x); xf[1]=(short)f2bf(xa.y);
        xf[2]=(short)f2bf(xa.z); xf[3]=(short)f2bf(xa.w);
        xf[4]=(short)f2bf(xc.x); xf[5]=(short)f2bf(xc.y);
        xf[6]=(short)f2bf(xc.z); xf[7]=(short)f2bf(xc.w);
        f32x4 kt0 = __builtin_amdgcn_mfma_f32_16x16x32_bf16(wk[0], xf, zac, 0, 0, 0);
        f32x4 kt1 = __builtin_amdgcn_mfma_f32_16x16x32_bf16(wk[1], xf, zac, 0, 0, 0);
        f32x4 vt0 = __builtin_amdgcn_mfma_f32_16x16x32_bf16(wv[0], xf, zac, 0, 0, 0);
        f32x4 vt1 = __builtin_amdgcn_mfma_f32_16x16x32_bf16(wv[1], xf, zac, 0, 0, 0);
        #pragma unroll
        for (int r = 0; r < 4; ++r) {
            KsT[(4*g+r)*264 + sl]    = f2bf(phi_elu1(kt0[r]));
            KsT[(16+4*g+r)*264 + sl] = f2bf(phi_elu1(kt1[r]));
            VsT[(4*g+r)*264 + sl]    = f2bf(vt0[r]);
            VsT[(16+4*g+r)*264 + sl] = f2bf(vt1[r]);
        }
    }
    __syncthreads();
    f32x4 acc[2][2] = {};
    #pragma unroll
    for (int ss = 0; ss < 2; ++ss) {
        const int s0 = w*64 + ss*32 + g*8;
        bf16x8 aK0 = *reinterpret_cast<const bf16x8*>(&KsT[m*264 + s0]);
        bf16x8 aK1 = *reinterpret_cast<const bf16x8*>(&KsT[(16+m)*264 + s0]);
        bf16x8 bV0 = *reinterpret_cast<const bf16x8*>(&VsT[m*264 + s0]);
        bf16x8 bV1 = *reinterpret_cast<const bf16x8*>(&VsT[(16+m)*264 + s0]);
        acc[0][0] = __builtin_amdgcn_mfma_f32_16x16x32_bf16(aK0, bV0, acc[0][0], 0, 0, 0);
        acc[0][1] = __builtin_amdgcn_mfma_f32_16x16x32_bf16(aK0, bV1, acc[0][1], 0, 0, 0);
        acc[1][0] = __builtin_amdgcn_mfma_f32_16x16x32_bf16(aK1, bV0, acc[1][0], 0, 0, 0);
        acc[1][1] = __builtin_amdgcn_mfma_f32_16x16x32_bf16(aK1, bV1, acc[1][1], 0, 0, 0);
    }
    {
        const int d = t & 31, oct = t >> 5;
        float s = 0.f;
        #pragma unroll
        for (int q = 0; q < 4; ++q) {
            bf16x8 kb = *reinterpret_cast<const bf16x8*>(&KsT[d*264 + oct*32 + q*8]);
            #pragma unroll
            for (int j = 0; j < 8; ++j) s += bf2f((unsigned short)kb[j]);
        }
        ksr[oct][d] = s;
    }
    #pragma unroll
    for (int i = 0; i < 2; ++i)
        #pragma unroll
        for (int j = 0; j < 2; ++j)
            #pragma unroll
            for (int r = 0; r < 4; ++r)
                red[w][i*16 + 4*g + r][j*16 + m] = acc[i][j][r];
    __syncthreads();
    float* pb = part + ((size_t)bh*NCHUNK + chunk)*1056;
    {
        const int d = t >> 3, e0 = (t & 7)*4;
        float4 sum;
        sum.x = red[0][d][e0+0]+red[1][d][e0+0]+red[2][d][e0+0]+red[3][d][e0+0];
        sum.y = red[0][d][e0+1]+red[1][d][e0+1]+red[2][d][e0+1]+red[3][d][e0+1];
        sum.z = red[0][d][e0+2]+red[1][d][e0+2]+red[2][d][e0+2]+red[3][d][e0+2];
        sum.w = red[0][d][e0+3]+red[1][d][e0+3]+red[2][d][e0+3]+red[3][d][e0+3];
        *reinterpret_cast<float4*>(pb + d*32 + e0) = sum;
    }
    if (t < 32) {
        float ks = 0.f;
        #pragma unroll
        for (int o = 0; o < 8; ++o) ks += ksr[o][t];
        pb[1024 + t] = ks;
    }
}

// ---------------- K2: deterministic reduce ----------------
__global__ __launch_bounds__(256) void k2_kv_reduce(
        const float* __restrict__ part, float* __restrict__ kv) {
    const int bh = blockIdx.x, t = threadIdx.x;
    for (int i = t; i < 1056; i += 256) {
        float s = 0.f;
        for (int c2 = 0; c2 < NCHUNK; ++c2)
            s += part[((size_t)bh*NCHUNK + c2)*1056 + i];
        kv[bh*1056 + i] = s;
    }
}

// ---------------- K3 (MFMA): Q-proj + attn, residual + LN1 -> xb ----------------
__global__ __launch_bounds__(256) void k3_attn_ln1_mfma(
        const float* __restrict__ x, const float* __restrict__ Wkqv,
        const float* __restrict__ kv, const float* __restrict__ g1,
        const float* __restrict__ be1, unsigned short* __restrict__ xb) {
    __shared__ __align__(16) unsigned short wq[32*40];
    __shared__ __align__(16) unsigned short kvt[NH*32*40];
    __shared__ __align__(16) float ksm[NH*32];
    __shared__ __align__(16) float gl[C], bl[C];
    __shared__ __align__(16) unsigned short qld[4][2][16*40];
    const int t = threadIdx.x;
    const int wid = t >> 6, lane = t & 63;
    const int g = lane >> 4, m = lane & 15;
    const int row0 = blockIdx.x * 64;
    const int b = row0 / LSEQ;
    for (int idx = t; idx < 1024; idx += 256) {
        int e = idx >> 5, d = idx & 31;
        wq[e*40 + d] = f2bf(Wkqv[1024 + idx]);
    }
    for (int idx = t; idx < NH*1024; idx += 256) {
        int h = idx >> 10, rem = idx & 1023;
        int d = rem >> 5, eo = rem & 31;
        kvt[h*1280 + eo*40 + d] = f2bf(kv[(size_t)(b*NH + h)*1056 + rem]);
    }
    {
        int h = t >> 5, d = t & 31;
        ksm[t] = kv[(size_t)(b*NH + h)*1056 + 1024 + d];
        gl[t] = g1[t];
        bl[t] = be1[t];
    }
    __syncthreads();

    const int row = row0 + wid*16 + m;
    f32x4 att[NH][2];
    const f32x4 zacc = {0.f, 0.f, 0.f, 0.f};
    #pragma unroll
    for (int h = 0; h < NH; ++h) {
        const float* xp = x + (size_t)row*C + h*32 + g*8;
        float4 xa = *reinterpret_cast<const float4*>(xp);
        float4 xc = *reinterpret_cast<const float4*>(xp + 4);
        bf16x8 xfrag;
        xfrag[0] = (short)f2bf(xa.x); xfrag[1] = (short)f2bf(xa.y);
        xfrag[2] = (short)f2bf(xa.z); xfrag[3] = (short)f2bf(xa.w);
        xfrag[4] = (short)f2bf(xc.x); xfrag[5] = (short)f2bf(xc.y);
        xfrag[6] = (short)f2bf(xc.z); xfrag[7] = (short)f2bf(xc.w);
        bf16x8 wf0 = *reinterpret_cast<const bf16x8*>(&wq[m*40 + g*8]);
        bf16x8 wf1 = *reinterpret_cast<const bf16x8*>(&wq[(16+m)*40 + g*8]);
        f32x4 q0 = __builtin_amdgcn_mfma_f32_16x16x32_bf16(wf0, xfrag, zacc, 0, 0, 0);
        f32x4 q1 = __builtin_amdgcn_mfma_f32_16x16x32_bf16(wf1, xfrag, zacc, 0, 0, 0);
        #pragma unroll
        for (int r = 0; r < 4; ++r) { q0[r] = phi_elu1(q0[r]); q1[r] = phi_elu1(q1[r]); }
        f32x4 ks0 = *reinterpret_cast<const f32x4*>(&ksm[h*32 + g*4]);
        f32x4 ks1 = *reinterpret_cast<const f32x4*>(&ksm[h*32 + 16 + g*4]);
        float zp = q0[0]*ks0[0] + q0[1]*ks0[1] + q0[2]*ks0[2] + q0[3]*ks0[3]
                 + q1[0]*ks1[0] + q1[1]*ks1[1] + q1[2]*ks1[2] + q1[3]*ks1[3];
        zp += __shfl_xor(zp, 16, 64);
        zp += __shfl_xor(zp, 32, 64);
        const float Z = 1.f / (zp + 1e-6f);
        unsigned short* slot = &qld[wid][h & 1][0];
        *reinterpret_cast<uint2*>(&slot[m*40 + g*4]) =
            make_uint2(pack2bf(q0[0], q0[1]), pack2bf(q0[2], q0[3]));
        *reinterpret_cast<uint2*>(&slot[m*40 + 16 + g*4]) =
            make_uint2(pack2bf(q1[0], q1[1]), pack2bf(q1[2], q1[3]));
        __builtin_amdgcn_wave_barrier();
        bf16x8 qrow = *reinterpret_cast<const bf16x8*>(&slot[m*40 + g*8]);
        __builtin_amdgcn_wave_barrier();
        bf16x8 kf0 = *reinterpret_cast<const bf16x8*>(&kvt[h*1280 + m*40 + g*8]);
        bf16x8 kf1 = *reinterpret_cast<const bf16x8*>(&kvt[h*1280 + (16+m)*40 + g*8]);
        f32x4 a0 = __builtin_amdgcn_mfma_f32_16x16x32_bf16(kf0, qrow, zacc, 0, 0, 0);
        f32x4 a1 = __builtin_amdgcn_mfma_f32_16x16x32_bf16(kf1, qrow, zacc, 0, 0, 0);
        #pragma unroll
        for (int r = 0; r < 4; ++r) { a0[r] *= Z; a1[r] *= Z; }
        att[h][0] = a0;
        att[h][1] = a1;
    }
    float s1 = 0.f, s2 = 0.f;
    #pragma unroll
    for (int h = 0; h < NH; ++h) {
        #pragma unroll
        for (int n = 0; n < 2; ++n) {
            const int c0 = h*32 + n*16 + g*4;
            float4 xr = *reinterpret_cast<const float4*>(x + (size_t)row*C + c0);
            f32x4 v = att[h][n];
            v[0] += xr.x; v[1] += xr.y; v[2] += xr.z; v[3] += xr.w;
            att[h][n] = v;
            s1 += v[0] + v[1] + v[2] + v[3];
            s2 += v[0]*v[0] + v[1]*v[1] + v[2]*v[2] + v[3]*v[3];
        }
    }
    s1 += __shfl_xor(s1, 16, 64); s1 += __shfl_xor(s1, 32, 64);
    s2 += __shfl_xor(s2, 16, 64); s2 += __shfl_xor(s2, 32, 64);
    const float mean = s1 * (1.f/C);
    const float var  = s2 * (1.f/C) - mean*mean;
    const float rs = rsqrtf(var + 1e-5f);
    #pragma unroll
    for (int h = 0; h < NH; ++h) {
        #pragma unroll
        for (int n = 0; n < 2; ++n) {
            const int c0 = h*32 + n*16 + g*4;
            f32x4 gv = *reinterpret_cast<const f32x4*>(&gl[c0]);
            f32x4 bv = *reinterpret_cast<const f32x4*>(&bl[c0]);
            f32x4 v = att[h][n];
            float o0 = (v[0]-mean)*rs*gv[0] + bv[0];
            float o1 = (v[1]-mean)*rs*gv[1] + bv[1];
            float o2 = (v[2]-mean)*rs*gv[2] + bv[2];
            float o3 = (v[3]-mean)*rs*gv[3] + bv[3];
            *reinterpret_cast<uint2*>(xb + (size_t)row*C + c0) =
                make_uint2(pack2bf(o0, o1), pack2bf(o2, o3));
        }
    }
}

// ---------------- K4: MFMA GEMM1  c1 = gelu(xb @ W1^T + b1), bf16 out ----------------
__global__ __launch_bounds__(256) void k4_ffn1_mfma(
        const unsigned short* __restrict__ A, const unsigned short* __restrict__ B,
        const float* __restrict__ b1, unsigned short* __restrict__ c1, int mbase) {
    __shared__ unsigned short As[128*64];
    __shared__ unsigned short Bs[128*64];
    const int t = threadIdx.x;
    const int wid = t >> 6, lane = t & 63;
    const int wr = wid >> 1, wc = wid & 1;
    const int m0 = mbase + blockIdx.x*128;
    const int n0 = blockIdx.y*128;
    f32x4 acc[4][4] = {};
    for (int kt = 0; kt < C/64; ++kt) {
        const int k0 = kt*64;
        #pragma unroll
        for (int i = 0; i < 4; ++i) {
            const int seg = i*256 + t;
            const int row = seg >> 3, jd = seg & 7;
            const int js = jd ^ (row & 7);
            gload_lds16(A + (size_t)(m0+row)*C + k0 + js*8, &As[(i*256 + wid*64)*8]);
            gload_lds16(B + (size_t)(n0+row)*C + k0 + js*8, &Bs[(i*256 + wid*64)*8]);
        }
        __syncthreads();
        #pragma unroll
        for (int kk = 0; kk < 2; ++kk) {
            bf16x8 af[4], bfr[4];
            #pragma unroll
            for (int m = 0; m < 4; ++m) {
                const int row = wr*64 + m*16 + (lane & 15);
                const int j = (kk*4 + (lane >> 4)) ^ (row & 7);
                af[m] = *reinterpret_cast<const bf16x8*>(&As[row*64 + j*8]);
            }
            #pragma unroll
            for (int n = 0; n < 4; ++n) {
                const int row = wc*64 + n*16 + (lane & 15);
                const int j = (kk*4 + (lane >> 4)) ^ (row & 7);
                bfr[n] = *reinterpret_cast<const bf16x8*>(&Bs[row*64 + j*8]);
            }
            #pragma unroll
            for (int m = 0; m < 4; ++m)
                #pragma unroll
                for (int n = 0; n < 4; ++n)
                    acc[m][n] = __builtin_amdgcn_mfma_f32_16x16x32_bf16(af[m], bfr[n], acc[m][n], 0, 0, 0);
        }
        __syncthreads();
    }
    const int r4 = lane >> 4, cc = lane & 15;
    #pragma unroll
    for (int m = 0; m < 4; ++m) {
        #pragma unroll
        for (int r = 0; r < 4; ++r) {
            const int lrow = blockIdx.x*128 + wr*64 + m*16 + r4*4 + r;
            #pragma unroll
            for (int n = 0; n < 4; ++n) {
                const int gcol = n0 + wc*64 + n*16 + cc;
                float f = acc[m][n][r] + b1[gcol];
                c1[(size_t)lrow*FF + gcol] = f2bf(fast_gelu(f));
            }
        }
    }
}

// ---------------- K5: MFMA GEMM2 + residual + LN2 fused -> final out ----------------
// Tile 64 rows x 256 cols (full width -> LN2 in-block). 4 waves, wave wid owns
// cols wid*64..+64, all 64 rows. BK=64, 16 k-steps. A = c1 chunk rows, B = W2b.
__global__ __launch_bounds__(256) void k5_ffn2_ln(
        const unsigned short* __restrict__ A, const unsigned short* __restrict__ B,
        const float* __restrict__ b2, const unsigned short* __restrict__ xb,
        const float* __restrict__ g2, const float* __restrict__ be2,
        float* __restrict__ out, int mbase) {
    __shared__ __align__(16) unsigned short As[64*64];    // 8 KB
    __shared__ __align__(16) unsigned short Bs[256*64];   // 32 KB
    __shared__ float red1[4][64], red2[4][64];
    __shared__ float mear[64], rsr[64];
    __shared__ float g2l[C], b2l[C], be2l[C];
    const int t = threadIdx.x;
    const int wid = t >> 6, lane = t & 63;
    const int lm0 = blockIdx.x*64;      // chunk-local row base
    g2l[t] = g2[t]; b2l[t] = b2[t]; be2l[t] = be2[t];
    f32x4 acc[4][4] = {};
    for (int kt = 0; kt < FF/64; ++kt) {
        const int k0 = kt*64;
        #pragma unroll
        for (int i = 0; i < 2; ++i) {           // A: 512 segs
            const int seg = i*256 + t;
            const int row = seg >> 3, jd = seg & 7;
            const int js = jd ^ (row & 7);
            gload_lds16(A + (size_t)(lm0+row)*FF + k0 + js*8, &As[(i*256 + wid*64)*8]);
        }
        #pragma unroll
        for (int i = 0; i < 8; ++i) {           // B: 2048 segs (all 256 W2 rows)
            const int seg = i*256 + t;
            const int row = seg >> 3, jd = seg & 7;
            const int js = jd ^ (row & 7);
            gload_lds16(B + (size_t)row*FF + k0 + js*8, &Bs[(i*256 + wid*64)*8]);
        }
        __syncthreads();
        #pragma unroll
        for (int kk = 0; kk < 2; ++kk) {
            bf16x8 af[4], bfr[4];
            #pragma unroll
            for (int m = 0; m < 4; ++m) {
                const int row = m*16 + (lane & 15);
                const int j = (kk*4 + (lane >> 4)) ^ (row & 7);
                af[m] = *reinterpret_cast<const bf16x8*>(&As[row*64 + j*8]);
            }
            #pragma unroll
            for (int n = 0; n < 4; ++n) {
                const int row = wid*64 + n*16 + (lane & 15);
                const int j = (kk*4 + (lane >> 4)) ^ (row & 7);
                bfr[n] = *reinterpret_cast<const bf16x8*>(&Bs[row*64 + j*8]);
            }
            #pragma unroll
            for (int m = 0; m < 4; ++m)
                #pragma unroll
                for (int n = 0; n < 4; ++n)
                    acc[m][n] = __builtin_amdgcn_mfma_f32_16x16x32_bf16(af[m], bfr[n], acc[m][n], 0, 0, 0);
        }
        __syncthreads();
    }
    // ---- epilogue: bias + residual, row sums, LN2, store ----
    const int r4 = lane >> 4, cc = lane & 15;
    float s1[4][4] = {}, s2[4][4] = {};
    #pragma unroll
    for (int m = 0; m < 4; ++m) {
        #pragma unroll
        for (int n = 0; n < 4; ++n) {
            const int gcol = wid*64 + n*16 + cc;
            #pragma unroll
            for (int r = 0; r < 4; ++r) {
                const size_t grow = (size_t)(mbase + lm0 + m*16 + r4*4 + r);
                float v = acc[m][n][r] + b2l[gcol] + bf2f(xb[grow*C + gcol]);
                acc[m][n][r] = v;
                s1[m][r] += v;
                s2[m][r] += v*v;
            }
        }
    }
    #pragma unroll
    for (int m = 0; m < 4; ++m) {
        #pragma unroll
        for (int r = 0; r < 4; ++r) {
            float a = s1[m][r], bb = s2[m][r];
            #pragma unroll
            for (int mk = 8; mk >= 1; mk >>= 1) {
                a  += __shfl_xor(a,  mk, 16);
                bb += __shfl_xor(bb, mk, 16);
            }
            if (cc == 0) {
                red1[wid][m*16 + r4*4 + r] = a;
                red2[wid][m*16 + r4*4 + r] = bb;
            }
        }
    }
    __syncthreads();
    if (t < 64) {
        float a  = red1[0][t]+red1[1][t]+red1[2][t]+red1[3][t];
        float bb = red2[0][t]+red2[1][t]+red2[2][t]+red2[3][t];
        float mean = a * (1.f/C);
        float var  = bb * (1.f/C) - mean*mean;
        mear[t] = mean;
        rsr[t]  = rsqrtf(var + 1e-5f);
    }
    __syncthreads();
    #pragma unroll
    for (int m = 0; m < 4; ++m) {
        #pragma unroll
        for (int r = 0; r < 4; ++r) {
            const int rl = m*16 + r4*4 + r;
            const float mu = mear[rl], rs = rsr[rl];
            const size_t grow = (size_t)(mbase + lm0 + rl);
            #pragma unroll
            for (int n = 0; n < 4; ++n) {
                const int gcol = wid*64 + n*16 + cc;
                out[grow*C + gcol] = (acc[m][n][r] - mu)*rs*g2l[gcol] + be2l[gcol];
            }
        }
    }
}

extern "C" void kernel_launch(void* const* d_in, const int* in_sizes, int n_in,
                              void* d_out, int out_size, void* d_ws, size_t ws_size,
                              hipStream_t stream) {
    const float* x    = (const float*)d_in[0];
    const float* Wkqv = (const float*)d_in[1];
    const float* W1   = (const float*)d_in[2];
    const float* b1   = (const float*)d_in[3];
    const float* W2   = (const float*)d_in[4];
    const float* b2   = (const float*)d_in[5];
    const float* g1   = (const float*)d_in[6];
    const float* be1  = (const float*)d_in[7];
    const float* g2   = (const float*)d_in[8];
    const float* be2  = (const float*)d_in[9];
    float* out = (float*)d_out;

    // ws layout (bytes):
    //   kv @ 0 | W1b @ 128K | W2b @ 640K | part @ 2M | xb @ 12M | c1 @ 48M  (~111 MB)
    char* wsb = (char*)d_ws;
    float* kv            = (float*)(wsb);
    unsigned short* W1b  = (unsigned short*)(wsb + (131072));
    unsigned short* W2b  = (unsigned short*)(wsb + (655360));
    float* part          = (float*)(wsb + ((size_t)2 << 20));
    unsigned short* xb   = (unsigned short*)(wsb + ((size_t)12 << 20));
    unsigned short* c1   = (unsigned short*)(wsb + ((size_t)48 << 20));

    k0_cvt<<<1024, 256, 0, stream>>>(W1, W2, W1b, W2b);
    k1_kv_partial_mfma<<<dim3(16, NCHUNK), 256, 0, stream>>>(x, Wkqv, part);
    k2_kv_reduce<<<16, 256, 0, stream>>>(part, kv);
    k3_attn_ln1_mfma<<<ROWS/64, 256, 0, stream>>>(x, Wkqv, kv, g1, be1, xb);
    for (int chunk = 0; chunk < 2; ++chunk) {
        const int mbase = chunk * MCHUNK;
        k4_ffn1_mfma<<<dim3(MCHUNK/128, FF/128), 256, 0, stream>>>(xb, W1b, b1, c1, mbase);
        k5_ffn2_ln<<<MCHUNK/64, 256, 0, stream>>>(c1, W2b, b2, xb, g2, be2, out, mbase);
    }
}

// Round 7
// 247.516 us; speedup vs baseline: 4.9935x; 1.0197x over previous
//
#include <hip/hip_runtime.h>
#include <hip/hip_bf16.h>

#define BSZ 2
#define C 256
#define NH 8
#define DIM 32
#define LSEQ 30720
#define ROWS (BSZ*LSEQ)
#define FF 1024
#define NCHUNK 120
#define CHS 256
#define MCHUNK (ROWS/2)

typedef __attribute__((ext_vector_type(8))) short bf16x8;
typedef __attribute__((ext_vector_type(4))) float f32x4;

__device__ __forceinline__ float phi_elu1(float v) { return v > 0.f ? v + 1.f : __expf(v); }

// tanh-form gelu: |err| vs exact erf-gelu <= ~1e-3; NaN-free.
__device__ __forceinline__ float fast_gelu(float x) {
    float inner = 0.7978845608028654f * (x + 0.044715f * x * x * x);
    float e2 = __expf(2.f * inner);
    float th = 1.f - 2.f / (e2 + 1.f);
    return 0.5f * x * (1.f + th);
}

// round-to-nearest-even f32 -> bf16 bits (finite inputs)
__device__ __forceinline__ unsigned short f2bf(float f) {
    unsigned int u = __float_as_uint(f);
    u += 0x7fffu + ((u >> 16) & 1u);
    return (unsigned short)(u >> 16);
}
__device__ __forceinline__ float bf2f(unsigned short u) {
    return __uint_as_float(((unsigned int)u) << 16);
}
__device__ __forceinline__ unsigned int pack2bf(float a, float b) {
    return (unsigned int)f2bf(a) | ((unsigned int)f2bf(b) << 16);
}

// async global->LDS, 16B per lane. LDS dest is wave-uniform base + lane*16.
__device__ __forceinline__ void gload_lds16(const unsigned short* g, unsigned short* l) {
    __builtin_amdgcn_global_load_lds(
        (const __attribute__((address_space(1))) unsigned int*)g,
        (__attribute__((address_space(3))) unsigned int*)l, 16, 0, 0);
}

// ---------------- K0: weights fp32 -> bf16 ----------------
__global__ __launch_bounds__(256) void k0_cvt(
        const float* __restrict__ W1, const float* __restrict__ W2,
        unsigned short* __restrict__ W1b, unsigned short* __restrict__ W2b) {
    const int i = blockIdx.x * 256 + threadIdx.x;   // 262144 total
    W1b[i] = f2bf(W1[i]);
    W2b[i] = f2bf(W2[i]);
}

// ---------------- K1 (MFMA): projection + partial KV(32x32) + Ksum per (b,h,chunk) ----------------
__global__ __launch_bounds__(256) void k1_kv_partial_mfma(
        const float* __restrict__ x, const float* __restrict__ Wkqv,
        float* __restrict__ part) {
    __shared__ __align__(16) unsigned short KsT[32*264];
    __shared__ __align__(16) unsigned short VsT[32*264];
    __shared__ __align__(16) float red[4][32][33];
    __shared__ __align__(16) float ksr[8][32];
    const int t = threadIdx.x;
    const int w = t >> 6, lane = t & 63;
    const int g = lane >> 4, m = lane & 15;
    const int bh = blockIdx.x, chunk = blockIdx.y;
    const int b = bh >> 3, head = bh & 7;
    const size_t rowbase = (size_t)b*LSEQ + (size_t)chunk*CHS;

    bf16x8 wk[2], wv[2];
    #pragma unroll
    for (int half = 0; half < 2; ++half) {
        const float* kp = Wkqv + (half*16 + m)*DIM + g*8;   // K rows 0..31
        const float* vp = kp + 2*DIM*DIM;                   // V rows 64..95
        float4 ka = *reinterpret_cast<const float4*>(kp);
        float4 kb = *reinterpret_cast<const float4*>(kp + 4);
        float4 va = *reinterpret_cast<const float4*>(vp);
        float4 vb = *reinterpret_cast<const float4*>(vp + 4);
        wk[half][0]=(short)f2bf(ka.x); wk[half][1]=(short)f2bf(ka.y);
        wk[half][2]=(short)f2bf(ka.z); wk[half][3]=(short)f2bf(ka.w);
        wk[half][4]=(short)f2bf(kb.x); wk[half][5]=(short)f2bf(kb.y);
        wk[half][6]=(short)f2bf(kb.z); wk[half][7]=(short)f2bf(kb.w);
        wv[half][0]=(short)f2bf(va.x); wv[half][1]=(short)f2bf(va.y);
        wv[half][2]=(short)f2bf(va.z); wv[half][3]=(short)f2bf(va.w);
        wv[half][4]=(short)f2bf(vb.x); wv[half][5]=(short)f2bf(vb.y);
        wv[half][6]=(short)f2bf(vb.z); wv[half][7]=(short)f2bf(vb.w);
    }
    const f32x4 zac = {0.f, 0.f, 0.f, 0.f};
    #pragma unroll
    for (int sg = 0; sg < 4; ++sg) {
        const int sl = w*64 + sg*16 + m;
        const float* xp = x + (rowbase + sl)*C + head*DIM + g*8;
        float4 xa = *reinterpret_cast<const float4*>(xp);
        float4 xc = *reinterpret_cast<const float4*>(xp + 4);
        bf16x8 xf;
        xf[0]=(short)f2bf(xa.x); xf[1]=(short)f2bf(xa.y);
        xf[2]=(short)f2bf(xa.z); xf[3]=(short)f2bf(xa.w);
        xf[4]=(short)f2bf(xc.x); xf[5]=(short)f2bf(xc.y);
        xf[6]=(short)f2bf(xc.z); xf[7]=(short)f2bf(xc.w);
        f32x4 kt0 = __builtin_amdgcn_mfma_f32_16x16x32_bf16(wk[0], xf, zac, 0, 0, 0);
        f32x4 kt1 = __builtin_amdgcn_mfma_f32_16x16x32_bf16(wk[1], xf, zac, 0, 0, 0);
        f32x4 vt0 = __builtin_amdgcn_mfma_f32_16x16x32_bf16(wv[0], xf, zac, 0, 0, 0);
        f32x4 vt1 = __builtin_amdgcn_mfma_f32_16x16x32_bf16(wv[1], xf, zac, 0, 0, 0);
        #pragma unroll
        for (int r = 0; r < 4; ++r) {
            KsT[(4*g+r)*264 + sl]    = f2bf(phi_elu1(kt0[r]));
            KsT[(16+4*g+r)*264 + sl] = f2bf(phi_elu1(kt1[r]));
            VsT[(4*g+r)*264 + sl]    = f2bf(vt0[r]);
            VsT[(16+4*g+r)*264 + sl] = f2bf(vt1[r]);
        }
    }
    __syncthreads();
    f32x4 acc[2][2] = {};
    #pragma unroll
    for (int ss = 0; ss < 2; ++ss) {
        const int s0 = w*64 + ss*32 + g*8;
        bf16x8 aK0 = *reinterpret_cast<const bf16x8*>(&KsT[m*264 + s0]);
        bf16x8 aK1 = *reinterpret_cast<const bf16x8*>(&KsT[(16+m)*264 + s0]);
        bf16x8 bV0 = *reinterpret_cast<const bf16x8*>(&VsT[m*264 + s0]);
        bf16x8 bV1 = *reinterpret_cast<const bf16x8*>(&VsT[(16+m)*264 + s0]);
        acc[0][0] = __builtin_amdgcn_mfma_f32_16x16x32_bf16(aK0, bV0, acc[0][0], 0, 0, 0);
        acc[0][1] = __builtin_amdgcn_mfma_f32_16x16x32_bf16(aK0, bV1, acc[0][1], 0, 0, 0);
        acc[1][0] = __builtin_amdgcn_mfma_f32_16x16x32_bf16(aK1, bV0, acc[1][0], 0, 0, 0);
        acc[1][1] = __builtin_amdgcn_mfma_f32_16x16x32_bf16(aK1, bV1, acc[1][1], 0, 0, 0);
    }
    {
        const int d = t & 31, oct = t >> 5;
        float s = 0.f;
        #pragma unroll
        for (int q = 0; q < 4; ++q) {
            bf16x8 kb = *reinterpret_cast<const bf16x8*>(&KsT[d*264 + oct*32 + q*8]);
            #pragma unroll
            for (int j = 0; j < 8; ++j) s += bf2f((unsigned short)kb[j]);
        }
        ksr[oct][d] = s;
    }
    #pragma unroll
    for (int i = 0; i < 2; ++i)
        #pragma unroll
        for (int j = 0; j < 2; ++j)
            #pragma unroll
            for (int r = 0; r < 4; ++r)
                red[w][i*16 + 4*g + r][j*16 + m] = acc[i][j][r];
    __syncthreads();
    float* pb = part + ((size_t)bh*NCHUNK + chunk)*1056;
    {
        const int d = t >> 3, e0 = (t & 7)*4;
        float4 sum;
        sum.x = red[0][d][e0+0]+red[1][d][e0+0]+red[2][d][e0+0]+red[3][d][e0+0];
        sum.y = red[0][d][e0+1]+red[1][d][e0+1]+red[2][d][e0+1]+red[3][d][e0+1];
        sum.z = red[0][d][e0+2]+red[1][d][e0+2]+red[2][d][e0+2]+red[3][d][e0+2];
        sum.w = red[0][d][e0+3]+red[1][d][e0+3]+red[2][d][e0+3]+red[3][d][e0+3];
        *reinterpret_cast<float4*>(pb + d*32 + e0) = sum;
    }
    if (t < 32) {
        float ks = 0.f;
        #pragma unroll
        for (int o = 0; o < 8; ++o) ks += ksr[o][t];
        pb[1024 + t] = ks;
    }
}

// ---------------- K2: deterministic reduce ----------------
__global__ __launch_bounds__(256) void k2_kv_reduce(
        const float* __restrict__ part, float* __restrict__ kv) {
    const int bh = blockIdx.x, t = threadIdx.x;
    for (int i = t; i < 1056; i += 256) {
        float s = 0.f;
        for (int c2 = 0; c2 < NCHUNK; ++c2)
            s += part[((size_t)bh*NCHUNK + c2)*1056 + i];
        kv[bh*1056 + i] = s;
    }
}

// ---------------- K3 (MFMA): Q-proj + attn, residual + LN1 -> xb ----------------
__global__ __launch_bounds__(256) void k3_attn_ln1_mfma(
        const float* __restrict__ x, const float* __restrict__ Wkqv,
        const float* __restrict__ kv, const float* __restrict__ g1,
        const float* __restrict__ be1, unsigned short* __restrict__ xb) {
    __shared__ __align__(16) unsigned short wq[32*40];
    __shared__ __align__(16) unsigned short kvt[NH*32*40];
    __shared__ __align__(16) float ksm[NH*32];
    __shared__ __align__(16) float gl[C], bl[C];
    __shared__ __align__(16) unsigned short qld[4][2][16*40];
    const int t = threadIdx.x;
    const int wid = t >> 6, lane = t & 63;
    const int g = lane >> 4, m = lane & 15;
    const int row0 = blockIdx.x * 64;
    const int b = row0 / LSEQ;
    for (int idx = t; idx < 1024; idx += 256) {
        int e = idx >> 5, d = idx & 31;
        wq[e*40 + d] = f2bf(Wkqv[1024 + idx]);
    }
    for (int idx = t; idx < NH*1024; idx += 256) {
        int h = idx >> 10, rem = idx & 1023;
        int d = rem >> 5, eo = rem & 31;
        kvt[h*1280 + eo*40 + d] = f2bf(kv[(size_t)(b*NH + h)*1056 + rem]);
    }
    {
        int h = t >> 5, d = t & 31;
        ksm[t] = kv[(size_t)(b*NH + h)*1056 + 1024 + d];
        gl[t] = g1[t];
        bl[t] = be1[t];
    }
    __syncthreads();

    const int row = row0 + wid*16 + m;
    f32x4 att[NH][2];
    const f32x4 zacc = {0.f, 0.f, 0.f, 0.f};
    #pragma unroll
    for (int h = 0; h < NH; ++h) {
        const float* xp = x + (size_t)row*C + h*32 + g*8;
        float4 xa = *reinterpret_cast<const float4*>(xp);
        float4 xc = *reinterpret_cast<const float4*>(xp + 4);
        bf16x8 xfrag;
        xfrag[0] = (short)f2bf(xa.x); xfrag[1] = (short)f2bf(xa.y);
        xfrag[2] = (short)f2bf(xa.z); xfrag[3] = (short)f2bf(xa.w);
        xfrag[4] = (short)f2bf(xc.x); xfrag[5] = (short)f2bf(xc.y);
        xfrag[6] = (short)f2bf(xc.z); xfrag[7] = (short)f2bf(xc.w);
        bf16x8 wf0 = *reinterpret_cast<const bf16x8*>(&wq[m*40 + g*8]);
        bf16x8 wf1 = *reinterpret_cast<const bf16x8*>(&wq[(16+m)*40 + g*8]);
        f32x4 q0 = __builtin_amdgcn_mfma_f32_16x16x32_bf16(wf0, xfrag, zacc, 0, 0, 0);
        f32x4 q1 = __builtin_amdgcn_mfma_f32_16x16x32_bf16(wf1, xfrag, zacc, 0, 0, 0);
        #pragma unroll
        for (int r = 0; r < 4; ++r) { q0[r] = phi_elu1(q0[r]); q1[r] = phi_elu1(q1[r]); }
        f32x4 ks0 = *reinterpret_cast<const f32x4*>(&ksm[h*32 + g*4]);
        f32x4 ks1 = *reinterpret_cast<const f32x4*>(&ksm[h*32 + 16 + g*4]);
        float zp = q0[0]*ks0[0] + q0[1]*ks0[1] + q0[2]*ks0[2] + q0[3]*ks0[3]
                 + q1[0]*ks1[0] + q1[1]*ks1[1] + q1[2]*ks1[2] + q1[3]*ks1[3];
        zp += __shfl_xor(zp, 16, 64);
        zp += __shfl_xor(zp, 32, 64);
        const float Z = 1.f / (zp + 1e-6f);
        unsigned short* slot = &qld[wid][h & 1][0];
        *reinterpret_cast<uint2*>(&slot[m*40 + g*4]) =
            make_uint2(pack2bf(q0[0], q0[1]), pack2bf(q0[2], q0[3]));
        *reinterpret_cast<uint2*>(&slot[m*40 + 16 + g*4]) =
            make_uint2(pack2bf(q1[0], q1[1]), pack2bf(q1[2], q1[3]));
        __builtin_amdgcn_wave_barrier();
        bf16x8 qrow = *reinterpret_cast<const bf16x8*>(&slot[m*40 + g*8]);
        __builtin_amdgcn_wave_barrier();
        bf16x8 kf0 = *reinterpret_cast<const bf16x8*>(&kvt[h*1280 + m*40 + g*8]);
        bf16x8 kf1 = *reinterpret_cast<const bf16x8*>(&kvt[h*1280 + (16+m)*40 + g*8]);
        f32x4 a0 = __builtin_amdgcn_mfma_f32_16x16x32_bf16(kf0, qrow, zacc, 0, 0, 0);
        f32x4 a1 = __builtin_amdgcn_mfma_f32_16x16x32_bf16(kf1, qrow, zacc, 0, 0, 0);
        #pragma unroll
        for (int r = 0; r < 4; ++r) { a0[r] *= Z; a1[r] *= Z; }
        att[h][0] = a0;
        att[h][1] = a1;
    }
    float s1 = 0.f, s2 = 0.f;
    #pragma unroll
    for (int h = 0; h < NH; ++h) {
        #pragma unroll
        for (int n = 0; n < 2; ++n) {
            const int c0 = h*32 + n*16 + g*4;
            float4 xr = *reinterpret_cast<const float4*>(x + (size_t)row*C + c0);
            f32x4 v = att[h][n];
            v[0] += xr.x; v[1] += xr.y; v[2] += xr.z; v[3] += xr.w;
            att[h][n] = v;
            s1 += v[0] + v[1] + v[2] + v[3];
            s2 += v[0]*v[0] + v[1]*v[1] + v[2]*v[2] + v[3]*v[3];
        }
    }
    s1 += __shfl_xor(s1, 16, 64); s1 += __shfl_xor(s1, 32, 64);
    s2 += __shfl_xor(s2, 16, 64); s2 += __shfl_xor(s2, 32, 64);
    const float mean = s1 * (1.f/C);
    const float var  = s2 * (1.f/C) - mean*mean;
    const float rs = rsqrtf(var + 1e-5f);
    #pragma unroll
    for (int h = 0; h < NH; ++h) {
        #pragma unroll
        for (int n = 0; n < 2; ++n) {
            const int c0 = h*32 + n*16 + g*4;
            f32x4 gv = *reinterpret_cast<const f32x4*>(&gl[c0]);
            f32x4 bv = *reinterpret_cast<const f32x4*>(&bl[c0]);
            f32x4 v = att[h][n];
            float o0 = (v[0]-mean)*rs*gv[0] + bv[0];
            float o1 = (v[1]-mean)*rs*gv[1] + bv[1];
            float o2 = (v[2]-mean)*rs*gv[2] + bv[2];
            float o3 = (v[3]-mean)*rs*gv[3] + bv[3];
            *reinterpret_cast<uint2*>(xb + (size_t)row*C + c0) =
                make_uint2(pack2bf(o0, o1), pack2bf(o2, o3));
        }
    }
}

// ---------------- K4: MFMA GEMM1, 2-phase double-buffered prefetch ----------------
// Per tile: STAGE(next) -> ds_read+MFMA(cur) -> ONE barrier. Next-tile loads fly
// under compute; barrier's vmcnt drain lands them (T3-minimum recipe).
__global__ __launch_bounds__(256) void k4_ffn1_mfma(
        const unsigned short* __restrict__ A, const unsigned short* __restrict__ B,
        const float* __restrict__ b1, unsigned short* __restrict__ c1, int mbase) {
    __shared__ __align__(16) unsigned short As[2][128*64];   // 2x16KB
    __shared__ __align__(16) unsigned short Bs[2][128*64];   // 2x16KB
    const int t = threadIdx.x;
    const int wid = t >> 6, lane = t & 63;
    const int wr = wid >> 1, wc = wid & 1;
    const int m0 = mbase + blockIdx.x*128;
    const int n0 = blockIdx.y*128;
    f32x4 acc[4][4] = {};

    const int srow = t >> 3, sjd = t & 7;          // this thread's staging seg (per i)
    // prologue: stage tile 0 into buffer 0
    #pragma unroll
    for (int i = 0; i < 4; ++i) {
        const int row = (i*256 + t) >> 3, jd = (i*256 + t) & 7;
        const int js = jd ^ (row & 7);
        gload_lds16(A + (size_t)(m0+row)*C + js*8, &As[0][(i*256 + wid*64)*8]);
        gload_lds16(B + (size_t)(n0+row)*C + js*8, &Bs[0][(i*256 + wid*64)*8]);
    }
    __syncthreads();
    for (int kt = 0; kt < C/64; ++kt) {
        const int cur = kt & 1;
        if (kt < C/64 - 1) {                        // prefetch next tile into other buffer
            const int k0n = (kt+1)*64;
            #pragma unroll
            for (int i = 0; i < 4; ++i) {
                const int row = (i*256 + t) >> 3, jd = (i*256 + t) & 7;
                const int js = jd ^ (row & 7);
                gload_lds16(A + (size_t)(m0+row)*C + k0n + js*8, &As[cur^1][(i*256 + wid*64)*8]);
                gload_lds16(B + (size_t)(n0+row)*C + k0n + js*8, &Bs[cur^1][(i*256 + wid*64)*8]);
            }
        }
        #pragma unroll
        for (int kk = 0; kk < 2; ++kk) {
            bf16x8 af[4], bfr[4];
            #pragma unroll
            for (int m = 0; m < 4; ++m) {
                const int row = wr*64 + m*16 + (lane & 15);
                const int j = (kk*4 + (lane >> 4)) ^ (row & 7);
                af[m] = *reinterpret_cast<const bf16x8*>(&As[cur][row*64 + j*8]);
            }
            #pragma unroll
            for (int n = 0; n < 4; ++n) {
                const int row = wc*64 + n*16 + (lane & 15);
                const int j = (kk*4 + (lane >> 4)) ^ (row & 7);
                bfr[n] = *reinterpret_cast<const bf16x8*>(&Bs[cur][row*64 + j*8]);
            }
            #pragma unroll
            for (int m = 0; m < 4; ++m)
                #pragma unroll
                for (int n = 0; n < 4; ++n)
                    acc[m][n] = __builtin_amdgcn_mfma_f32_16x16x32_bf16(af[m], bfr[n], acc[m][n], 0, 0, 0);
        }
        if (kt < C/64 - 1) __syncthreads();
    }
    (void)srow; (void)sjd;
    const int r4 = lane >> 4, cc = lane & 15;
    #pragma unroll
    for (int m = 0; m < 4; ++m) {
        #pragma unroll
        for (int r = 0; r < 4; ++r) {
            const int lrow = blockIdx.x*128 + wr*64 + m*16 + r4*4 + r;
            #pragma unroll
            for (int n = 0; n < 4; ++n) {
                const int gcol = n0 + wc*64 + n*16 + cc;
                float f = acc[m][n][r] + b1[gcol];
                c1[(size_t)lrow*FF + gcol] = f2bf(fast_gelu(f));
            }
        }
    }
}

// ---------------- K5: MFMA GEMM2 + residual + LN2 fused, 2-phase prefetch ----------------
// 64 rows x 256 cols (full width). LDS exactly 80KB (2 blocks/CU): smem carved
// into As[2]/Bs[2]; LN scratch overlays As buffer 0 (all reads of it fenced by
// the iter-14 barrier; last tile reads buffer 1 only).
__global__ __launch_bounds__(256) void k5_ffn2_ln(
        const unsigned short* __restrict__ A, const unsigned short* __restrict__ B,
        const float* __restrict__ b2, const unsigned short* __restrict__ xb,
        const float* __restrict__ g2, const float* __restrict__ be2,
        float* __restrict__ out, int mbase) {
    __shared__ __align__(16) unsigned short smem[40960];   // 80 KB
    unsigned short* As0 = smem;                 // 4096 ushorts (8KB)
    unsigned short* As1 = smem + 4096;
    unsigned short* Bs0 = smem + 8192;          // 16384 ushorts (32KB)
    unsigned short* Bs1 = smem + 8192 + 16384;
    const int t = threadIdx.x;
    const int wid = t >> 6, lane = t & 63;
    const int lm0 = blockIdx.x*64;              // chunk-local row base
    f32x4 acc[4][4] = {};

    // prologue: stage tile 0 into buffer 0
    #pragma unroll
    for (int i = 0; i < 2; ++i) {
        const int row = (i*256 + t) >> 3, jd = (i*256 + t) & 7;
        const int js = jd ^ (row & 7);
        gload_lds16(A + (size_t)(lm0+row)*FF + js*8, &As0[(i*256 + wid*64)*8]);
    }
    #pragma unroll
    for (int i = 0; i < 8; ++i) {
        const int row = (i*256 + t) >> 3, jd = (i*256 + t) & 7;
        const int js = jd ^ (row & 7);
        gload_lds16(B + (size_t)row*FF + js*8, &Bs0[(i*256 + wid*64)*8]);
    }
    __syncthreads();
    for (int kt = 0; kt < FF/64; ++kt) {
        const int cur = kt & 1;
        unsigned short* Asc = cur ? As1 : As0;
        unsigned short* Bsc = cur ? Bs1 : Bs0;
        if (kt < FF/64 - 1) {
            unsigned short* Asn = cur ? As0 : As1;
            unsigned short* Bsn = cur ? Bs0 : Bs1;
            const int k0n = (kt+1)*64;
            #pragma unroll
            for (int i = 0; i < 2; ++i) {
                const int row = (i*256 + t) >> 3, jd = (i*256 + t) & 7;
                const int js = jd ^ (row & 7);
                gload_lds16(A + (size_t)(lm0+row)*FF + k0n + js*8, &Asn[(i*256 + wid*64)*8]);
            }
            #pragma unroll
            for (int i = 0; i < 8; ++i) {
                const int row = (i*256 + t) >> 3, jd = (i*256 + t) & 7;
                const int js = jd ^ (row & 7);
                gload_lds16(B + (size_t)row*FF + k0n + js*8, &Bsn[(i*256 + wid*64)*8]);
            }
        }
        #pragma unroll
        for (int kk = 0; kk < 2; ++kk) {
            bf16x8 af[4], bfr[4];
            #pragma unroll
            for (int m = 0; m < 4; ++m) {
                const int row = m*16 + (lane & 15);
                const int j = (kk*4 + (lane >> 4)) ^ (row & 7);
                af[m] = *reinterpret_cast<const bf16x8*>(&Asc[row*64 + j*8]);
            }
            #pragma unroll
            for (int n = 0; n < 4; ++n) {
                const int row = wid*64 + n*16 + (lane & 15);
                const int j = (kk*4 + (lane >> 4)) ^ (row & 7);
                bfr[n] = *reinterpret_cast<const bf16x8*>(&Bsc[row*64 + j*8]);
            }
            #pragma unroll
            for (int m = 0; m < 4; ++m)
                #pragma unroll
                for (int n = 0; n < 4; ++n)
                    acc[m][n] = __builtin_amdgcn_mfma_f32_16x16x32_bf16(af[m], bfr[n], acc[m][n], 0, 0, 0);
        }
        if (kt < FF/64 - 1) __syncthreads();
    }
    // ---- epilogue: bias + residual, LN2, store. Scratch overlays As0 (8KB). ----
    float* red1 = (float*)smem;           // [4][64]
    float* red2 = (float*)smem + 256;     // [4][64]
    float* mear = (float*)smem + 512;     // [64]
    float* rsr  = (float*)smem + 576;     // [64]
    const int r4 = lane >> 4, cc = lane & 15;
    float b2v[4], g2v[4], be2v[4];
    #pragma unroll
    for (int n = 0; n < 4; ++n) {
        const int gcol = wid*64 + n*16 + cc;
        b2v[n] = b2[gcol]; g2v[n] = g2[gcol]; be2v[n] = be2[gcol];
    }
    float s1[4][4] = {}, s2[4][4] = {};
    #pragma unroll
    for (int m = 0; m < 4; ++m) {
        #pragma unroll
        for (int n = 0; n < 4; ++n) {
            const int gcol = wid*64 + n*16 + cc;
            #pragma unroll
            for (int r = 0; r < 4; ++r) {
                const size_t grow = (size_t)(mbase + lm0 + m*16 + r4*4 + r);
                float v = acc[m][n][r] + b2v[n] + bf2f(xb[grow*C + gcol]);
                acc[m][n][r] = v;
                s1[m][r] += v;
                s2[m][r] += v*v;
            }
        }
    }
    #pragma unroll
    for (int m = 0; m < 4; ++m) {
        #pragma unroll
        for (int r = 0; r < 4; ++r) {
            float a = s1[m][r], bb = s2[m][r];
            #pragma unroll
            for (int mk = 8; mk >= 1; mk >>= 1) {
                a  += __shfl_xor(a,  mk, 16);
                bb += __shfl_xor(bb, mk, 16);
            }
            if (cc == 0) {
                red1[wid*64 + m*16 + r4*4 + r] = a;
                red2[wid*64 + m*16 + r4*4 + r] = bb;
            }
        }
    }
    __syncthreads();
    if (t < 64) {
        float a  = red1[t]+red1[64+t]+red1[128+t]+red1[192+t];
        float bb = red2[t]+red2[64+t]+red2[128+t]+red2[192+t];
        float mean = a * (1.f/C);
        float var  = bb * (1.f/C) - mean*mean;
        mear[t] = mean;
        rsr[t]  = rsqrtf(var + 1e-5f);
    }
    __syncthreads();
    #pragma unroll
    for (int m = 0; m < 4; ++m) {
        #pragma unroll
        for (int r = 0; r < 4; ++r) {
            const int rl = m*16 + r4*4 + r;
            const float mu = mear[rl], rs = rsr[rl];
            const size_t grow = (size_t)(mbase + lm0 + rl);
            #pragma unroll
            for (int n = 0; n < 4; ++n) {
                const int gcol = wid*64 + n*16 + cc;
                out[grow*C + gcol] = (acc[m][n][r] - mu)*rs*g2v[n] + be2v[n];
            }
        }
    }
}

extern "C" void kernel_launch(void* const* d_in, const int* in_sizes, int n_in,
                              void* d_out, int out_size, void* d_ws, size_t ws_size,
                              hipStream_t stream) {
    const float* x    = (const float*)d_in[0];
    const float* Wkqv = (const float*)d_in[1];
    const float* W1   = (const float*)d_in[2];
    const float* b1   = (const float*)d_in[3];
    const float* W2   = (const float*)d_in[4];
    const float* b2   = (const float*)d_in[5];
    const float* g1   = (const float*)d_in[6];
    const float* be1  = (const float*)d_in[7];
    const float* g2   = (const float*)d_in[8];
    const float* be2  = (const float*)d_in[9];
    float* out = (float*)d_out;

    // ws layout (bytes):
    //   kv @ 0 | W1b @ 128K | W2b @ 640K | part @ 2M | xb @ 12M | c1 @ 48M  (~111 MB)
    char* wsb = (char*)d_ws;
    float* kv            = (float*)(wsb);
    unsigned short* W1b  = (unsigned short*)(wsb + (131072));
    unsigned short* W2b  = (unsigned short*)(wsb + (655360));
    float* part          = (float*)(wsb + ((size_t)2 << 20));
    unsigned short* xb   = (unsigned short*)(wsb + ((size_t)12 << 20));
    unsigned short* c1   = (unsigned short*)(wsb + ((size_t)48 << 20));

    k0_cvt<<<1024, 256, 0, stream>>>(W1, W2, W1b, W2b);
    k1_kv_partial_mfma<<<dim3(16, NCHUNK), 256, 0, stream>>>(x, Wkqv, part);
    k2_kv_reduce<<<16, 256, 0, stream>>>(part, kv);
    k3_attn_ln1_mfma<<<ROWS/64, 256, 0, stream>>>(x, Wkqv, kv, g1, be1, xb);
    for (int chunk = 0; chunk < 2; ++chunk) {
        const int mbase = chunk * MCHUNK;
        k4_ffn1_mfma<<<dim3(MCHUNK/128, FF/128), 256, 0, stream>>>(xb, W1b, b1, c1, mbase);
        k5_ffn2_ln<<<MCHUNK/64, 256, 0, stream>>>(c1, W2b, b2, xb, g2, be2, out, mbase);
    }
}

// Round 9
// 236.642 us; speedup vs baseline: 5.2230x; 1.0460x over previous
//
#include <hip/hip_runtime.h>
#include <hip/hip_bf16.h>

#define BSZ 2
#define C 256
#define NH 8
#define DIM 32
#define LSEQ 30720
#define ROWS (BSZ*LSEQ)
#define FF 1024
#define NCHUNK 120
#define CHS 256
#define MCHUNK (ROWS/2)

typedef __attribute__((ext_vector_type(8))) short bf16x8;
typedef __attribute__((ext_vector_type(4))) float f32x4;

__device__ __forceinline__ float phi_elu1(float v) { return v > 0.f ? v + 1.f : __expf(v); }

// tanh-form gelu in exp2 form (constants pre-folded with log2e).
// v_exp_f32 computes 2^x natively. NaN-free at +-inf.
__device__ __forceinline__ float fast_gelu(float x) {
    float p = x * x * x;
    float q = __builtin_amdgcn_exp2f(fmaf(0.10294557f, p, 2.30211758f * x)); // e^(2*inner)
    float r = __builtin_amdgcn_rcpf(q + 1.f);
    float hx = 0.5f * x;
    return fmaf(hx, fmaf(-2.f, r, 1.f), hx);                    // 0.5x(1+th)
}

// round-to-nearest-even f32 -> bf16 bits (finite inputs)
__device__ __forceinline__ unsigned short f2bf(float f) {
    unsigned int u = __float_as_uint(f);
    u += 0x7fffu + ((u >> 16) & 1u);
    return (unsigned short)(u >> 16);
}
__device__ __forceinline__ float bf2f(unsigned short u) {
    return __uint_as_float(((unsigned int)u) << 16);
}
__device__ __forceinline__ unsigned int pack2bf(float a, float b) {
    return (unsigned int)f2bf(a) | ((unsigned int)f2bf(b) << 16);
}

// async global->LDS, 16B per lane. LDS dest is wave-uniform base + lane*16.
__device__ __forceinline__ void gload_lds16(const unsigned short* g, unsigned short* l) {
    __builtin_amdgcn_global_load_lds(
        (const __attribute__((address_space(1))) unsigned int*)g,
        (__attribute__((address_space(3))) unsigned int*)l, 16, 0, 0);
}

// ---------------- K0: weights fp32 -> bf16 ----------------
__global__ __launch_bounds__(256) void k0_cvt(
        const float* __restrict__ W1, const float* __restrict__ W2,
        unsigned short* __restrict__ W1b, unsigned short* __restrict__ W2b) {
    const int i = blockIdx.x * 256 + threadIdx.x;   // 262144 total
    W1b[i] = f2bf(W1[i]);
    W2b[i] = f2bf(W2[i]);
}

// ---------------- K1 (MFMA): projection + partial KV(32x32) + Ksum per (b,h,chunk) ----------------
__global__ __launch_bounds__(256) void k1_kv_partial_mfma(
        const float* __restrict__ x, const float* __restrict__ Wkqv,
        float* __restrict__ part) {
    __shared__ __align__(16) unsigned short KsT[32*264];
    __shared__ __align__(16) unsigned short VsT[32*264];
    __shared__ __align__(16) float red[4][32][33];
    __shared__ __align__(16) float ksr[8][32];
    const int t = threadIdx.x;
    const int w = t >> 6, lane = t & 63;
    const int g = lane >> 4, m = lane & 15;
    const int bh = blockIdx.x, chunk = blockIdx.y;
    const int b = bh >> 3, head = bh & 7;
    const size_t rowbase = (size_t)b*LSEQ + (size_t)chunk*CHS;

    bf16x8 wk[2], wv[2];
    #pragma unroll
    for (int half = 0; half < 2; ++half) {
        const float* kp = Wkqv + (half*16 + m)*DIM + g*8;   // K rows 0..31
        const float* vp = kp + 2*DIM*DIM;                   // V rows 64..95
        float4 ka = *reinterpret_cast<const float4*>(kp);
        float4 kb = *reinterpret_cast<const float4*>(kp + 4);
        float4 va = *reinterpret_cast<const float4*>(vp);
        float4 vb = *reinterpret_cast<const float4*>(vp + 4);
        wk[half][0]=(short)f2bf(ka.x); wk[half][1]=(short)f2bf(ka.y);
        wk[half][2]=(short)f2bf(ka.z); wk[half][3]=(short)f2bf(ka.w);
        wk[half][4]=(short)f2bf(kb.x); wk[half][5]=(short)f2bf(kb.y);
        wk[half][6]=(short)f2bf(kb.z); wk[half][7]=(short)f2bf(kb.w);
        wv[half][0]=(short)f2bf(va.x); wv[half][1]=(short)f2bf(va.y);
        wv[half][2]=(short)f2bf(va.z); wv[half][3]=(short)f2bf(va.w);
        wv[half][4]=(short)f2bf(vb.x); wv[half][5]=(short)f2bf(vb.y);
        wv[half][6]=(short)f2bf(vb.z); wv[half][7]=(short)f2bf(vb.w);
    }
    const f32x4 zac = {0.f, 0.f, 0.f, 0.f};
    #pragma unroll
    for (int sg = 0; sg < 4; ++sg) {
        const int sl = w*64 + sg*16 + m;
        const float* xp = x + (rowbase + sl)*C + head*DIM + g*8;
        float4 xa = *reinterpret_cast<const float4*>(xp);
        float4 xc = *reinterpret_cast<const float4*>(xp + 4);
        bf16x8 xf;
        xf[0]=(short)f2bf(xa.x); xf[1]=(short)f2bf(xa.y);
        xf[2]=(short)f2bf(xa.z); xf[3]=(short)f2bf(xa.w);
        xf[4]=(short)f2bf(xc.x); xf[5]=(short)f2bf(xc.y);
        xf[6]=(short)f2bf(xc.z); xf[7]=(short)f2bf(xc.w);
        f32x4 kt0 = __builtin_amdgcn_mfma_f32_16x16x32_bf16(wk[0], xf, zac, 0, 0, 0);
        f32x4 kt1 = __builtin_amdgcn_mfma_f32_16x16x32_bf16(wk[1], xf, zac, 0, 0, 0);
        f32x4 vt0 = __builtin_amdgcn_mfma_f32_16x16x32_bf16(wv[0], xf, zac, 0, 0, 0);
        f32x4 vt1 = __builtin_amdgcn_mfma_f32_16x16x32_bf16(wv[1], xf, zac, 0, 0, 0);
        #pragma unroll
        for (int r = 0; r < 4; ++r) {
            KsT[(4*g+r)*264 + sl]    = f2bf(phi_elu1(kt0[r]));
            KsT[(16+4*g+r)*264 + sl] = f2bf(phi_elu1(kt1[r]));
            VsT[(4*g+r)*264 + sl]    = f2bf(vt0[r]);
            VsT[(16+4*g+r)*264 + sl] = f2bf(vt1[r]);
        }
    }
    __syncthreads();
    f32x4 acc[2][2] = {};
    #pragma unroll
    for (int ss = 0; ss < 2; ++ss) {
        const int s0 = w*64 + ss*32 + g*8;
        bf16x8 aK0 = *reinterpret_cast<const bf16x8*>(&KsT[m*264 + s0]);
        bf16x8 aK1 = *reinterpret_cast<const bf16x8*>(&KsT[(16+m)*264 + s0]);
        bf16x8 bV0 = *reinterpret_cast<const bf16x8*>(&VsT[m*264 + s0]);
        bf16x8 bV1 = *reinterpret_cast<const bf16x8*>(&VsT[(16+m)*264 + s0]);
        acc[0][0] = __builtin_amdgcn_mfma_f32_16x16x32_bf16(aK0, bV0, acc[0][0], 0, 0, 0);
        acc[0][1] = __builtin_amdgcn_mfma_f32_16x16x32_bf16(aK0, bV1, acc[0][1], 0, 0, 0);
        acc[1][0] = __builtin_amdgcn_mfma_f32_16x16x32_bf16(aK1, bV0, acc[1][0], 0, 0, 0);
        acc[1][1] = __builtin_amdgcn_mfma_f32_16x16x32_bf16(aK1, bV1, acc[1][1], 0, 0, 0);
    }
    {
        const int d = t & 31, oct = t >> 5;
        float s = 0.f;
        #pragma unroll
        for (int q = 0; q < 4; ++q) {
            bf16x8 kb = *reinterpret_cast<const bf16x8*>(&KsT[d*264 + oct*32 + q*8]);
            #pragma unroll
            for (int j = 0; j < 8; ++j) s += bf2f((unsigned short)kb[j]);
        }
        ksr[oct][d] = s;
    }
    #pragma unroll
    for (int i = 0; i < 2; ++i)
        #pragma unroll
        for (int j = 0; j < 2; ++j)
            #pragma unroll
            for (int r = 0; r < 4; ++r)
                red[w][i*16 + 4*g + r][j*16 + m] = acc[i][j][r];
    __syncthreads();
    float* pb = part + ((size_t)bh*NCHUNK + chunk)*1056;
    {
        const int d = t >> 3, e0 = (t & 7)*4;
        float4 sum;
        sum.x = red[0][d][e0+0]+red[1][d][e0+0]+red[2][d][e0+0]+red[3][d][e0+0];
        sum.y = red[0][d][e0+1]+red[1][d][e0+1]+red[2][d][e0+1]+red[3][d][e0+1];
        sum.z = red[0][d][e0+2]+red[1][d][e0+2]+red[2][d][e0+2]+red[3][d][e0+2];
        sum.w = red[0][d][e0+3]+red[1][d][e0+3]+red[2][d][e0+3]+red[3][d][e0+3];
        *reinterpret_cast<float4*>(pb + d*32 + e0) = sum;
    }
    if (t < 32) {
        float ks = 0.f;
        #pragma unroll
        for (int o = 0; o < 8; ++o) ks += ksr[o][t];
        pb[1024 + t] = ks;
    }
}

// ---------------- K2: deterministic reduce ----------------
__global__ __launch_bounds__(256) void k2_kv_reduce(
        const float* __restrict__ part, float* __restrict__ kv) {
    const int bh = blockIdx.x, t = threadIdx.x;
    for (int i = t; i < 1056; i += 256) {
        float s = 0.f;
        for (int c2 = 0; c2 < NCHUNK; ++c2)
            s += part[((size_t)bh*NCHUNK + c2)*1056 + i];
        kv[bh*1056 + i] = s;
    }
}

// ---------------- K3 (MFMA): Q-proj + attn, residual + LN1 -> xb ----------------
__global__ __launch_bounds__(256) void k3_attn_ln1_mfma(
        const float* __restrict__ x, const float* __restrict__ Wkqv,
        const float* __restrict__ kv, const float* __restrict__ g1,
        const float* __restrict__ be1, unsigned short* __restrict__ xb) {
    __shared__ __align__(16) unsigned short wq[32*40];
    __shared__ __align__(16) unsigned short kvt[NH*32*40];
    __shared__ __align__(16) float ksm[NH*32];
    __shared__ __align__(16) float gl[C], bl[C];
    __shared__ __align__(16) unsigned short qld[4][2][16*40];
    const int t = threadIdx.x;
    const int wid = t >> 6, lane = t & 63;
    const int g = lane >> 4, m = lane & 15;
    const int row0 = blockIdx.x * 64;
    const int b = row0 / LSEQ;
    for (int idx = t; idx < 1024; idx += 256) {
        int e = idx >> 5, d = idx & 31;
        wq[e*40 + d] = f2bf(Wkqv[1024 + idx]);
    }
    for (int idx = t; idx < NH*1024; idx += 256) {
        int h = idx >> 10, rem = idx & 1023;
        int d = rem >> 5, eo = rem & 31;
        kvt[h*1280 + eo*40 + d] = f2bf(kv[(size_t)(b*NH + h)*1056 + rem]);
    }
    {
        int h = t >> 5, d = t & 31;
        ksm[t] = kv[(size_t)(b*NH + h)*1056 + 1024 + d];
        gl[t] = g1[t];
        bl[t] = be1[t];
    }
    __syncthreads();

    const int row = row0 + wid*16 + m;
    f32x4 att[NH][2];
    const f32x4 zacc = {0.f, 0.f, 0.f, 0.f};
    #pragma unroll
    for (int h = 0; h < NH; ++h) {
        const float* xp = x + (size_t)row*C + h*32 + g*8;
        float4 xa = *reinterpret_cast<const float4*>(xp);
        float4 xc = *reinterpret_cast<const float4*>(xp + 4);
        bf16x8 xfrag;
        xfrag[0] = (short)f2bf(xa.x); xfrag[1] = (short)f2bf(xa.y);
        xfrag[2] = (short)f2bf(xa.z); xfrag[3] = (short)f2bf(xa.w);
        xfrag[4] = (short)f2bf(xc.x); xfrag[5] = (short)f2bf(xc.y);
        xfrag[6] = (short)f2bf(xc.z); xfrag[7] = (short)f2bf(xc.w);
        bf16x8 wf0 = *reinterpret_cast<const bf16x8*>(&wq[m*40 + g*8]);
        bf16x8 wf1 = *reinterpret_cast<const bf16x8*>(&wq[(16+m)*40 + g*8]);
        f32x4 q0 = __builtin_amdgcn_mfma_f32_16x16x32_bf16(wf0, xfrag, zacc, 0, 0, 0);
        f32x4 q1 = __builtin_amdgcn_mfma_f32_16x16x32_bf16(wf1, xfrag, zacc, 0, 0, 0);
        #pragma unroll
        for (int r = 0; r < 4; ++r) { q0[r] = phi_elu1(q0[r]); q1[r] = phi_elu1(q1[r]); }
        f32x4 ks0 = *reinterpret_cast<const f32x4*>(&ksm[h*32 + g*4]);
        f32x4 ks1 = *reinterpret_cast<const f32x4*>(&ksm[h*32 + 16 + g*4]);
        float zp = q0[0]*ks0[0] + q0[1]*ks0[1] + q0[2]*ks0[2] + q0[3]*ks0[3]
                 + q1[0]*ks1[0] + q1[1]*ks1[1] + q1[2]*ks1[2] + q1[3]*ks1[3];
        zp += __shfl_xor(zp, 16, 64);
        zp += __shfl_xor(zp, 32, 64);
        const float Z = 1.f / (zp + 1e-6f);
        unsigned short* slot = &qld[wid][h & 1][0];
        *reinterpret_cast<uint2*>(&slot[m*40 + g*4]) =
            make_uint2(pack2bf(q0[0], q0[1]), pack2bf(q0[2], q0[3]));
        *reinterpret_cast<uint2*>(&slot[m*40 + 16 + g*4]) =
            make_uint2(pack2bf(q1[0], q1[1]), pack2bf(q1[2], q1[3]));
        __builtin_amdgcn_wave_barrier();
        bf16x8 qrow = *reinterpret_cast<const bf16x8*>(&slot[m*40 + g*8]);
        __builtin_amdgcn_wave_barrier();
        bf16x8 kf0 = *reinterpret_cast<const bf16x8*>(&kvt[h*1280 + m*40 + g*8]);
        bf16x8 kf1 = *reinterpret_cast<const bf16x8*>(&kvt[h*1280 + (16+m)*40 + g*8]);
        f32x4 a0 = __builtin_amdgcn_mfma_f32_16x16x32_bf16(kf0, qrow, zacc, 0, 0, 0);
        f32x4 a1 = __builtin_amdgcn_mfma_f32_16x16x32_bf16(kf1, qrow, zacc, 0, 0, 0);
        #pragma unroll
        for (int r = 0; r < 4; ++r) { a0[r] *= Z; a1[r] *= Z; }
        att[h][0] = a0;
        att[h][1] = a1;
    }
    float s1 = 0.f, s2 = 0.f;
    #pragma unroll
    for (int h = 0; h < NH; ++h) {
        #pragma unroll
        for (int n = 0; n < 2; ++n) {
            const int c0 = h*32 + n*16 + g*4;
            float4 xr = *reinterpret_cast<const float4*>(x + (size_t)row*C + c0);
            f32x4 v = att[h][n];
            v[0] += xr.x; v[1] += xr.y; v[2] += xr.z; v[3] += xr.w;
            att[h][n] = v;
            s1 += v[0] + v[1] + v[2] + v[3];
            s2 += v[0]*v[0] + v[1]*v[1] + v[2]*v[2] + v[3]*v[3];
        }
    }
    s1 += __shfl_xor(s1, 16, 64); s1 += __shfl_xor(s1, 32, 64);
    s2 += __shfl_xor(s2, 16, 64); s2 += __shfl_xor(s2, 32, 64);
    const float mean = s1 * (1.f/C);
    const float var  = s2 * (1.f/C) - mean*mean;
    const float rs = rsqrtf(var + 1e-5f);
    #pragma unroll
    for (int h = 0; h < NH; ++h) {
        #pragma unroll
        for (int n = 0; n < 2; ++n) {
            const int c0 = h*32 + n*16 + g*4;
            f32x4 gv = *reinterpret_cast<const f32x4*>(&gl[c0]);
            f32x4 bv = *reinterpret_cast<const f32x4*>(&bl[c0]);
            f32x4 v = att[h][n];
            float o0 = (v[0]-mean)*rs*gv[0] + bv[0];
            float o1 = (v[1]-mean)*rs*gv[1] + bv[1];
            float o2 = (v[2]-mean)*rs*gv[2] + bv[2];
            float o3 = (v[3]-mean)*rs*gv[3] + bv[3];
            *reinterpret_cast<uint2*>(xb + (size_t)row*C + c0) =
                make_uint2(pack2bf(o0, o1), pack2bf(o2, o3));
        }
    }
}

// ---------------- K4: MFMA GEMM1 (single-buffer r6 structure — dbuf REGRESSED here:
// K=256 has only 4 tiles, and 64KB LDS halved occupancy; kernel is epilogue/VALU
// bound so occupancy wins) ----------------
__global__ __launch_bounds__(256) void k4_ffn1_mfma(
        const unsigned short* __restrict__ A, const unsigned short* __restrict__ B,
        const float* __restrict__ b1, unsigned short* __restrict__ c1, int mbase) {
    __shared__ unsigned short As[128*64];
    __shared__ unsigned short Bs[128*64];
    const int t = threadIdx.x;
    const int wid = t >> 6, lane = t & 63;
    const int wr = wid >> 1, wc = wid & 1;
    const int m0 = mbase + blockIdx.x*128;
    const int n0 = blockIdx.y*128;
    f32x4 acc[4][4] = {};
    for (int kt = 0; kt < C/64; ++kt) {
        const int k0 = kt*64;
        #pragma unroll
        for (int i = 0; i < 4; ++i) {
            const int seg = i*256 + t;
            const int row = seg >> 3, jd = seg & 7;
            const int js = jd ^ (row & 7);
            gload_lds16(A + (size_t)(m0+row)*C + k0 + js*8, &As[(i*256 + wid*64)*8]);
            gload_lds16(B + (size_t)(n0+row)*C + k0 + js*8, &Bs[(i*256 + wid*64)*8]);
        }
        __syncthreads();
        #pragma unroll
        for (int kk = 0; kk < 2; ++kk) {
            bf16x8 af[4], bfr[4];
            #pragma unroll
            for (int m = 0; m < 4; ++m) {
                const int row = wr*64 + m*16 + (lane & 15);
                const int j = (kk*4 + (lane >> 4)) ^ (row & 7);
                af[m] = *reinterpret_cast<const bf16x8*>(&As[row*64 + j*8]);
            }
            #pragma unroll
            for (int n = 0; n < 4; ++n) {
                const int row = wc*64 + n*16 + (lane & 15);
                const int j = (kk*4 + (lane >> 4)) ^ (row & 7);
                bfr[n] = *reinterpret_cast<const bf16x8*>(&Bs[row*64 + j*8]);
            }
            #pragma unroll
            for (int m = 0; m < 4; ++m)
                #pragma unroll
                for (int n = 0; n < 4; ++n)
                    acc[m][n] = __builtin_amdgcn_mfma_f32_16x16x32_bf16(af[m], bfr[n], acc[m][n], 0, 0, 0);
        }
        __syncthreads();
    }
    const int r4 = lane >> 4, cc = lane & 15;
    #pragma unroll
    for (int m = 0; m < 4; ++m) {
        #pragma unroll
        for (int r = 0; r < 4; ++r) {
            const int lrow = blockIdx.x*128 + wr*64 + m*16 + r4*4 + r;
            #pragma unroll
            for (int n = 0; n < 4; ++n) {
                const int gcol = n0 + wc*64 + n*16 + cc;
                float f = acc[m][n][r] + b1[gcol];
                c1[(size_t)lrow*FF + gcol] = f2bf(fast_gelu(f));
            }
        }
    }
}

// ---------------- K5: MFMA GEMM2 + residual + LN2 fused, 2-phase prefetch ----------------
// 64 rows x 256 cols (full width). LDS exactly 80KB (2 blocks/CU): smem carved
// into As[2]/Bs[2]; LN scratch overlays As buffer 0 (all reads of it fenced by
// the iter-14 barrier; last tile reads buffer 1 only).
__global__ __launch_bounds__(256) void k5_ffn2_ln(
        const unsigned short* __restrict__ A, const unsigned short* __restrict__ B,
        const float* __restrict__ b2, const unsigned short* __restrict__ xb,
        const float* __restrict__ g2, const float* __restrict__ be2,
        float* __restrict__ out, int mbase) {
    __shared__ __align__(16) unsigned short smem[40960];   // 80 KB
    unsigned short* As0 = smem;                 // 4096 ushorts (8KB)
    unsigned short* As1 = smem + 4096;
    unsigned short* Bs0 = smem + 8192;          // 16384 ushorts (32KB)
    unsigned short* Bs1 = smem + 8192 + 16384;
    const int t = threadIdx.x;
    const int wid = t >> 6, lane = t & 63;
    const int lm0 = blockIdx.x*64;              // chunk-local row base
    f32x4 acc[4][4] = {};

    // prologue: stage tile 0 into buffer 0
    #pragma unroll
    for (int i = 0; i < 2; ++i) {
        const int row = (i*256 + t) >> 3, jd = (i*256 + t) & 7;
        const int js = jd ^ (row & 7);
        gload_lds16(A + (size_t)(lm0+row)*FF + js*8, &As0[(i*256 + wid*64)*8]);
    }
    #pragma unroll
    for (int i = 0; i < 8; ++i) {
        const int row = (i*256 + t) >> 3, jd = (i*256 + t) & 7;
        const int js = jd ^ (row & 7);
        gload_lds16(B + (size_t)row*FF + js*8, &Bs0[(i*256 + wid*64)*8]);
    }
    __syncthreads();
    for (int kt = 0; kt < FF/64; ++kt) {
        const int cur = kt & 1;
        unsigned short* Asc = cur ? As1 : As0;
        unsigned short* Bsc = cur ? Bs1 : Bs0;
        if (kt < FF/64 - 1) {
            unsigned short* Asn = cur ? As0 : As1;
            unsigned short* Bsn = cur ? Bs0 : Bs1;
            const int k0n = (kt+1)*64;
            #pragma unroll
            for (int i = 0; i < 2; ++i) {
                const int row = (i*256 + t) >> 3, jd = (i*256 + t) & 7;
                const int js = jd ^ (row & 7);
                gload_lds16(A + (size_t)(lm0+row)*FF + k0n + js*8, &Asn[(i*256 + wid*64)*8]);
            }
            #pragma unroll
            for (int i = 0; i < 8; ++i) {
                const int row = (i*256 + t) >> 3, jd = (i*256 + t) & 7;
                const int js = jd ^ (row & 7);
                gload_lds16(B + (size_t)row*FF + k0n + js*8, &Bsn[(i*256 + wid*64)*8]);
            }
        }
        #pragma unroll
        for (int kk = 0; kk < 2; ++kk) {
            bf16x8 af[4], bfr[4];
            #pragma unroll
            for (int m = 0; m < 4; ++m) {
                const int row = m*16 + (lane & 15);
                const int j = (kk*4 + (lane >> 4)) ^ (row & 7);
                af[m] = *reinterpret_cast<const bf16x8*>(&Asc[row*64 + j*8]);
            }
            #pragma unroll
            for (int n = 0; n < 4; ++n) {
                const int row = wid*64 + n*16 + (lane & 15);
                const int j = (kk*4 + (lane >> 4)) ^ (row & 7);
                bfr[n] = *reinterpret_cast<const bf16x8*>(&Bsc[row*64 + j*8]);
            }
            #pragma unroll
            for (int m = 0; m < 4; ++m)
                #pragma unroll
                for (int n = 0; n < 4; ++n)
                    acc[m][n] = __builtin_amdgcn_mfma_f32_16x16x32_bf16(af[m], bfr[n], acc[m][n], 0, 0, 0);
        }
        if (kt < FF/64 - 1) __syncthreads();
    }
    // ---- epilogue: bias + residual, LN2, store. Scratch overlays As0 (8KB). ----
    float* red1 = (float*)smem;           // [4][64]
    float* red2 = (float*)smem + 256;     // [4][64]
    float* mear = (float*)smem + 512;     // [64]
    float* rsr  = (float*)smem + 576;     // [64]
    const int r4 = lane >> 4, cc = lane & 15;
    float b2v[4], g2v[4], be2v[4];
    #pragma unroll
    for (int n = 0; n < 4; ++n) {
        const int gcol = wid*64 + n*16 + cc;
        b2v[n] = b2[gcol]; g2v[n] = g2[gcol]; be2v[n] = be2[gcol];
    }
    float s1[4][4] = {}, s2[4][4] = {};
    #pragma unroll
    for (int m = 0; m < 4; ++m) {
        #pragma unroll
        for (int n = 0; n < 4; ++n) {
            const int gcol = wid*64 + n*16 + cc;
            #pragma unroll
            for (int r = 0; r < 4; ++r) {
                const size_t grow = (size_t)(mbase + lm0 + m*16 + r4*4 + r);
                float v = acc[m][n][r] + b2v[n] + bf2f(xb[grow*C + gcol]);
                acc[m][n][r] = v;
                s1[m][r] += v;
                s2[m][r] += v*v;
            }
        }
    }
    #pragma unroll
    for (int m = 0; m < 4; ++m) {
        #pragma unroll
        for (int r = 0; r < 4; ++r) {
            float a = s1[m][r], bb = s2[m][r];
            #pragma unroll
            for (int mk = 8; mk >= 1; mk >>= 1) {
                a  += __shfl_xor(a,  mk, 16);
                bb += __shfl_xor(bb, mk, 16);
            }
            if (cc == 0) {
                red1[wid*64 + m*16 + r4*4 + r] = a;
                red2[wid*64 + m*16 + r4*4 + r] = bb;
            }
        }
    }
    __syncthreads();
    if (t < 64) {
        float a  = red1[t]+red1[64+t]+red1[128+t]+red1[192+t];
        float bb = red2[t]+red2[64+t]+red2[128+t]+red2[192+t];
        float mean = a * (1.f/C);
        float var  = bb * (1.f/C) - mean*mean;
        mear[t] = mean;
        rsr[t]  = rsqrtf(var + 1e-5f);
    }
    __syncthreads();
    #pragma unroll
    for (int m = 0; m < 4; ++m) {
        #pragma unroll
        for (int r = 0; r < 4; ++r) {
            const int rl = m*16 + r4*4 + r;
            const float mu = mear[rl], rs = rsr[rl];
            const size_t grow = (size_t)(mbase + lm0 + rl);
            #pragma unroll
            for (int n = 0; n < 4; ++n) {
                const int gcol = wid*64 + n*16 + cc;
                out[grow*C + gcol] = (acc[m][n][r] - mu)*rs*g2v[n] + be2v[n];
            }
        }
    }
}

extern "C" void kernel_launch(void* const* d_in, const int* in_sizes, int n_in,
                              void* d_out, int out_size, void* d_ws, size_t ws_size,
                              hipStream_t stream) {
    const float* x    = (const float*)d_in[0];
    const float* Wkqv = (const float*)d_in[1];
    const float* W1   = (const float*)d_in[2];
    const float* b1   = (const float*)d_in[3];
    const float* W2   = (const float*)d_in[4];
    const float* b2   = (const float*)d_in[5];
    const float* g1   = (const float*)d_in[6];
    const float* be1  = (const float*)d_in[7];
    const float* g2   = (const float*)d_in[8];
    const float* be2  = (const float*)d_in[9];
    float* out = (float*)d_out;

    // ws layout (bytes):
    //   kv @ 0 | W1b @ 128K | W2b @ 640K | part @ 2M | xb @ 12M | c1 @ 48M  (~111 MB)
    char* wsb = (char*)d_ws;
    float* kv            = (float*)(wsb);
    unsigned short* W1b  = (unsigned short*)(wsb + (131072));
    unsigned short* W2b  = (unsigned short*)(wsb + (655360));
    float* part          = (float*)(wsb + ((size_t)2 << 20));
    unsigned short* xb   = (unsigned short*)(wsb + ((size_t)12 << 20));
    unsigned short* c1   = (unsigned short*)(wsb + ((size_t)48 << 20));

    k0_cvt<<<1024, 256, 0, stream>>>(W1, W2, W1b, W2b);
    k1_kv_partial_mfma<<<dim3(16, NCHUNK), 256, 0, stream>>>(x, Wkqv, part);
    k2_kv_reduce<<<16, 256, 0, stream>>>(part, kv);
    k3_attn_ln1_mfma<<<ROWS/64, 256, 0, stream>>>(x, Wkqv, kv, g1, be1, xb);
    for (int chunk = 0; chunk < 2; ++chunk) {
        const int mbase = chunk * MCHUNK;
        k4_ffn1_mfma<<<dim3(MCHUNK/128, FF/128), 256, 0, stream>>>(xb, W1b, b1, c1, mbase);
        k5_ffn2_ln<<<MCHUNK/64, 256, 0, stream>>>(c1, W2b, b2, xb, g2, be2, out, mbase);
    }
}

// Round 10
// 232.767 us; speedup vs baseline: 5.3099x; 1.0166x over previous
//
#include <hip/hip_runtime.h>
#include <hip/hip_bf16.h>

#define BSZ 2
#define C 256
#define NH 8
#define DIM 32
#define LSEQ 30720
#define ROWS (BSZ*LSEQ)
#define FF 1024
#define NCHUNK 120
#define CHS 256
#define MCHUNK (ROWS/2)

typedef __attribute__((ext_vector_type(8))) short bf16x8;
typedef __attribute__((ext_vector_type(4))) float f32x4;

__device__ __forceinline__ float phi_elu1(float v) { return v > 0.f ? v + 1.f : __expf(v); }

// tanh-form gelu in exp2 form (constants pre-folded with log2e).
// v_exp_f32 computes 2^x natively. NaN-free at +-inf.
__device__ __forceinline__ float fast_gelu(float x) {
    float p = x * x * x;
    float q = __builtin_amdgcn_exp2f(fmaf(0.10294557f, p, 2.30211758f * x)); // e^(2*inner)
    float r = __builtin_amdgcn_rcpf(q + 1.f);
    float hx = 0.5f * x;
    return fmaf(hx, fmaf(-2.f, r, 1.f), hx);                    // 0.5x(1+th)
}

// round-to-nearest-even f32 -> bf16 bits (finite inputs)
__device__ __forceinline__ unsigned short f2bf(float f) {
    unsigned int u = __float_as_uint(f);
    u += 0x7fffu + ((u >> 16) & 1u);
    return (unsigned short)(u >> 16);
}
__device__ __forceinline__ float bf2f(unsigned short u) {
    return __uint_as_float(((unsigned int)u) << 16);
}
__device__ __forceinline__ unsigned int pack2bf(float a, float b) {
    return (unsigned int)f2bf(a) | ((unsigned int)f2bf(b) << 16);
}

// async global->LDS, 16B per lane. LDS dest is wave-uniform base + lane*16.
__device__ __forceinline__ void gload_lds16(const unsigned short* g, unsigned short* l) {
    __builtin_amdgcn_global_load_lds(
        (const __attribute__((address_space(1))) unsigned int*)g,
        (__attribute__((address_space(3))) unsigned int*)l, 16, 0, 0);
}

// ---------------- K0: weights fp32 -> bf16 ----------------
__global__ __launch_bounds__(256) void k0_cvt(
        const float* __restrict__ W1, const float* __restrict__ W2,
        unsigned short* __restrict__ W1b, unsigned short* __restrict__ W2b) {
    const int i = blockIdx.x * 256 + threadIdx.x;   // 262144 total
    W1b[i] = f2bf(W1[i]);
    W2b[i] = f2bf(W2[i]);
}

// ---------------- K1 (MFMA): projection + partial KV(32x32) + Ksum per (b,h,chunk) ----------------
// Ksum now accumulated in-register during phase 1 (same bf16-rounded values as
// the LDS store) + 4-step shfl tree — deletes the old 32-read scalar unpack loop.
__global__ __launch_bounds__(256) void k1_kv_partial_mfma(
        const float* __restrict__ x, const float* __restrict__ Wkqv,
        float* __restrict__ part) {
    __shared__ __align__(16) unsigned short KsT[32*264];
    __shared__ __align__(16) unsigned short VsT[32*264];
    __shared__ __align__(16) float red[4][32][33];
    __shared__ __align__(16) float ksr[4][32];
    const int t = threadIdx.x;
    const int w = t >> 6, lane = t & 63;
    const int g = lane >> 4, m = lane & 15;
    const int bh = blockIdx.x, chunk = blockIdx.y;
    const int b = bh >> 3, head = bh & 7;
    const size_t rowbase = (size_t)b*LSEQ + (size_t)chunk*CHS;

    bf16x8 wk[2], wv[2];
    #pragma unroll
    for (int half = 0; half < 2; ++half) {
        const float* kp = Wkqv + (half*16 + m)*DIM + g*8;   // K rows 0..31
        const float* vp = kp + 2*DIM*DIM;                   // V rows 64..95
        float4 ka = *reinterpret_cast<const float4*>(kp);
        float4 kb = *reinterpret_cast<const float4*>(kp + 4);
        float4 va = *reinterpret_cast<const float4*>(vp);
        float4 vb = *reinterpret_cast<const float4*>(vp + 4);
        wk[half][0]=(short)f2bf(ka.x); wk[half][1]=(short)f2bf(ka.y);
        wk[half][2]=(short)f2bf(ka.z); wk[half][3]=(short)f2bf(ka.w);
        wk[half][4]=(short)f2bf(kb.x); wk[half][5]=(short)f2bf(kb.y);
        wk[half][6]=(short)f2bf(kb.z); wk[half][7]=(short)f2bf(kb.w);
        wv[half][0]=(short)f2bf(va.x); wv[half][1]=(short)f2bf(va.y);
        wv[half][2]=(short)f2bf(va.z); wv[half][3]=(short)f2bf(va.w);
        wv[half][4]=(short)f2bf(vb.x); wv[half][5]=(short)f2bf(vb.y);
        wv[half][6]=(short)f2bf(vb.z); wv[half][7]=(short)f2bf(vb.w);
    }
    const f32x4 zac = {0.f, 0.f, 0.f, 0.f};
    f32x4 ks0 = zac, ks1 = zac;   // in-register Ksum partials (d = 4g+r / 16+4g+r)
    #pragma unroll
    for (int sg = 0; sg < 4; ++sg) {
        const int sl = w*64 + sg*16 + m;
        const float* xp = x + (rowbase + sl)*C + head*DIM + g*8;
        float4 xa = *reinterpret_cast<const float4*>(xp);
        float4 xc = *reinterpret_cast<const float4*>(xp + 4);
        bf16x8 xf;
        xf[0]=(short)f2bf(xa.x); xf[1]=(short)f2bf(xa.y);
        xf[2]=(short)f2bf(xa.z); xf[3]=(short)f2bf(xa.w);
        xf[4]=(short)f2bf(xc.x); xf[5]=(short)f2bf(xc.y);
        xf[6]=(short)f2bf(xc.z); xf[7]=(short)f2bf(xc.w);
        f32x4 kt0 = __builtin_amdgcn_mfma_f32_16x16x32_bf16(wk[0], xf, zac, 0, 0, 0);
        f32x4 kt1 = __builtin_amdgcn_mfma_f32_16x16x32_bf16(wk[1], xf, zac, 0, 0, 0);
        f32x4 vt0 = __builtin_amdgcn_mfma_f32_16x16x32_bf16(wv[0], xf, zac, 0, 0, 0);
        f32x4 vt1 = __builtin_amdgcn_mfma_f32_16x16x32_bf16(wv[1], xf, zac, 0, 0, 0);
        #pragma unroll
        for (int r = 0; r < 4; ++r) {
            unsigned short u0 = f2bf(phi_elu1(kt0[r]));
            unsigned short u1 = f2bf(phi_elu1(kt1[r]));
            KsT[(4*g+r)*264 + sl]    = u0;
            KsT[(16+4*g+r)*264 + sl] = u1;
            ks0[r] += bf2f(u0);
            ks1[r] += bf2f(u1);
            VsT[(4*g+r)*264 + sl]    = f2bf(vt0[r]);
            VsT[(16+4*g+r)*264 + sl] = f2bf(vt1[r]);
        }
    }
    // reduce Ksum partials over the 16 m-lanes (stays within each 16-lane group)
    #pragma unroll
    for (int mk = 8; mk >= 1; mk >>= 1) {
        #pragma unroll
        for (int r = 0; r < 4; ++r) {
            ks0[r] += __shfl_xor(ks0[r], mk, 64);
            ks1[r] += __shfl_xor(ks1[r], mk, 64);
        }
    }
    if (m == 0) {
        #pragma unroll
        for (int r = 0; r < 4; ++r) {
            ksr[w][4*g + r]      = ks0[r];
            ksr[w][16 + 4*g + r] = ks1[r];
        }
    }
    __syncthreads();
    f32x4 acc[2][2] = {};
    #pragma unroll
    for (int ss = 0; ss < 2; ++ss) {
        const int s0 = w*64 + ss*32 + g*8;
        bf16x8 aK0 = *reinterpret_cast<const bf16x8*>(&KsT[m*264 + s0]);
        bf16x8 aK1 = *reinterpret_cast<const bf16x8*>(&KsT[(16+m)*264 + s0]);
        bf16x8 bV0 = *reinterpret_cast<const bf16x8*>(&VsT[m*264 + s0]);
        bf16x8 bV1 = *reinterpret_cast<const bf16x8*>(&VsT[(16+m)*264 + s0]);
        acc[0][0] = __builtin_amdgcn_mfma_f32_16x16x32_bf16(aK0, bV0, acc[0][0], 0, 0, 0);
        acc[0][1] = __builtin_amdgcn_mfma_f32_16x16x32_bf16(aK0, bV1, acc[0][1], 0, 0, 0);
        acc[1][0] = __builtin_amdgcn_mfma_f32_16x16x32_bf16(aK1, bV0, acc[1][0], 0, 0, 0);
        acc[1][1] = __builtin_amdgcn_mfma_f32_16x16x32_bf16(aK1, bV1, acc[1][1], 0, 0, 0);
    }
    #pragma unroll
    for (int i = 0; i < 2; ++i)
        #pragma unroll
        for (int j = 0; j < 2; ++j)
            #pragma unroll
            for (int r = 0; r < 4; ++r)
                red[w][i*16 + 4*g + r][j*16 + m] = acc[i][j][r];
    __syncthreads();
    float* pb = part + ((size_t)bh*NCHUNK + chunk)*1056;
    {
        const int d = t >> 3, e0 = (t & 7)*4;
        float4 sum;
        sum.x = red[0][d][e0+0]+red[1][d][e0+0]+red[2][d][e0+0]+red[3][d][e0+0];
        sum.y = red[0][d][e0+1]+red[1][d][e0+1]+red[2][d][e0+1]+red[3][d][e0+1];
        sum.z = red[0][d][e0+2]+red[1][d][e0+2]+red[2][d][e0+2]+red[3][d][e0+2];
        sum.w = red[0][d][e0+3]+red[1][d][e0+3]+red[2][d][e0+3]+red[3][d][e0+3];
        *reinterpret_cast<float4*>(pb + d*32 + e0) = sum;
    }
    if (t < 32) {
        pb[1024 + t] = ksr[0][t] + ksr[1][t] + ksr[2][t] + ksr[3][t];
    }
}

// ---------------- K2: deterministic reduce ----------------
__global__ __launch_bounds__(256) void k2_kv_reduce(
        const float* __restrict__ part, float* __restrict__ kv) {
    const int bh = blockIdx.x, t = threadIdx.x;
    for (int i = t; i < 1056; i += 256) {
        float s = 0.f;
        for (int c2 = 0; c2 < NCHUNK; ++c2)
            s += part[((size_t)bh*NCHUNK + c2)*1056 + i];
        kv[bh*1056 + i] = s;
    }
}

// ---------------- K3 (MFMA): Q-proj + attn, residual + LN1 -> xb ----------------
__global__ __launch_bounds__(256) void k3_attn_ln1_mfma(
        const float* __restrict__ x, const float* __restrict__ Wkqv,
        const float* __restrict__ kv, const float* __restrict__ g1,
        const float* __restrict__ be1, unsigned short* __restrict__ xb) {
    __shared__ __align__(16) unsigned short wq[32*40];
    __shared__ __align__(16) unsigned short kvt[NH*32*40];
    __shared__ __align__(16) float ksm[NH*32];
    __shared__ __align__(16) float gl[C], bl[C];
    __shared__ __align__(16) unsigned short qld[4][2][16*40];
    const int t = threadIdx.x;
    const int wid = t >> 6, lane = t & 63;
    const int g = lane >> 4, m = lane & 15;
    const int row0 = blockIdx.x * 64;
    const int b = row0 / LSEQ;
    for (int idx = t; idx < 1024; idx += 256) {
        int e = idx >> 5, d = idx & 31;
        wq[e*40 + d] = f2bf(Wkqv[1024 + idx]);
    }
    for (int idx = t; idx < NH*1024; idx += 256) {
        int h = idx >> 10, rem = idx & 1023;
        int d = rem >> 5, eo = rem & 31;
        kvt[h*1280 + eo*40 + d] = f2bf(kv[(size_t)(b*NH + h)*1056 + rem]);
    }
    {
        int h = t >> 5, d = t & 31;
        ksm[t] = kv[(size_t)(b*NH + h)*1056 + 1024 + d];
        gl[t] = g1[t];
        bl[t] = be1[t];
    }
    __syncthreads();

    const int row = row0 + wid*16 + m;
    f32x4 att[NH][2];
    const f32x4 zacc = {0.f, 0.f, 0.f, 0.f};
    #pragma unroll
    for (int h = 0; h < NH; ++h) {
        const float* xp = x + (size_t)row*C + h*32 + g*8;
        float4 xa = *reinterpret_cast<const float4*>(xp);
        float4 xc = *reinterpret_cast<const float4*>(xp + 4);
        bf16x8 xfrag;
        xfrag[0] = (short)f2bf(xa.x); xfrag[1] = (short)f2bf(xa.y);
        xfrag[2] = (short)f2bf(xa.z); xfrag[3] = (short)f2bf(xa.w);
        xfrag[4] = (short)f2bf(xc.x); xfrag[5] = (short)f2bf(xc.y);
        xfrag[6] = (short)f2bf(xc.z); xfrag[7] = (short)f2bf(xc.w);
        bf16x8 wf0 = *reinterpret_cast<const bf16x8*>(&wq[m*40 + g*8]);
        bf16x8 wf1 = *reinterpret_cast<const bf16x8*>(&wq[(16+m)*40 + g*8]);
        f32x4 q0 = __builtin_amdgcn_mfma_f32_16x16x32_bf16(wf0, xfrag, zacc, 0, 0, 0);
        f32x4 q1 = __builtin_amdgcn_mfma_f32_16x16x32_bf16(wf1, xfrag, zacc, 0, 0, 0);
        #pragma unroll
        for (int r = 0; r < 4; ++r) { q0[r] = phi_elu1(q0[r]); q1[r] = phi_elu1(q1[r]); }
        f32x4 ks0 = *reinterpret_cast<const f32x4*>(&ksm[h*32 + g*4]);
        f32x4 ks1 = *reinterpret_cast<const f32x4*>(&ksm[h*32 + 16 + g*4]);
        float zp = q0[0]*ks0[0] + q0[1]*ks0[1] + q0[2]*ks0[2] + q0[3]*ks0[3]
                 + q1[0]*ks1[0] + q1[1]*ks1[1] + q1[2]*ks1[2] + q1[3]*ks1[3];
        zp += __shfl_xor(zp, 16, 64);
        zp += __shfl_xor(zp, 32, 64);
        const float Z = 1.f / (zp + 1e-6f);
        unsigned short* slot = &qld[wid][h & 1][0];
        *reinterpret_cast<uint2*>(&slot[m*40 + g*4]) =
            make_uint2(pack2bf(q0[0], q0[1]), pack2bf(q0[2], q0[3]));
        *reinterpret_cast<uint2*>(&slot[m*40 + 16 + g*4]) =
            make_uint2(pack2bf(q1[0], q1[1]), pack2bf(q1[2], q1[3]));
        __builtin_amdgcn_wave_barrier();
        bf16x8 qrow = *reinterpret_cast<const bf16x8*>(&slot[m*40 + g*8]);
        __builtin_amdgcn_wave_barrier();
        bf16x8 kf0 = *reinterpret_cast<const bf16x8*>(&kvt[h*1280 + m*40 + g*8]);
        bf16x8 kf1 = *reinterpret_cast<const bf16x8*>(&kvt[h*1280 + (16+m)*40 + g*8]);
        f32x4 a0 = __builtin_amdgcn_mfma_f32_16x16x32_bf16(kf0, qrow, zacc, 0, 0, 0);
        f32x4 a1 = __builtin_amdgcn_mfma_f32_16x16x32_bf16(kf1, qrow, zacc, 0, 0, 0);
        #pragma unroll
        for (int r = 0; r < 4; ++r) { a0[r] *= Z; a1[r] *= Z; }
        att[h][0] = a0;
        att[h][1] = a1;
    }
    float s1 = 0.f, s2 = 0.f;
    #pragma unroll
    for (int h = 0; h < NH; ++h) {
        #pragma unroll
        for (int n = 0; n < 2; ++n) {
            const int c0 = h*32 + n*16 + g*4;
            float4 xr = *reinterpret_cast<const float4*>(x + (size_t)row*C + c0);
            f32x4 v = att[h][n];
            v[0] += xr.x; v[1] += xr.y; v[2] += xr.z; v[3] += xr.w;
            att[h][n] = v;
            s1 += v[0] + v[1] + v[2] + v[3];
            s2 += v[0]*v[0] + v[1]*v[1] + v[2]*v[2] + v[3]*v[3];
        }
    }
    s1 += __shfl_xor(s1, 16, 64); s1 += __shfl_xor(s1, 32, 64);
    s2 += __shfl_xor(s2, 16, 64); s2 += __shfl_xor(s2, 32, 64);
    const float mean = s1 * (1.f/C);
    const float var  = s2 * (1.f/C) - mean*mean;
    const float rs = rsqrtf(var + 1e-5f);
    #pragma unroll
    for (int h = 0; h < NH; ++h) {
        #pragma unroll
        for (int n = 0; n < 2; ++n) {
            const int c0 = h*32 + n*16 + g*4;
            f32x4 gv = *reinterpret_cast<const f32x4*>(&gl[c0]);
            f32x4 bv = *reinterpret_cast<const f32x4*>(&bl[c0]);
            f32x4 v = att[h][n];
            float o0 = (v[0]-mean)*rs*gv[0] + bv[0];
            float o1 = (v[1]-mean)*rs*gv[1] + bv[1];
            float o2 = (v[2]-mean)*rs*gv[2] + bv[2];
            float o3 = (v[3]-mean)*rs*gv[3] + bv[3];
            *reinterpret_cast<uint2*>(xb + (size_t)row*C + c0) =
                make_uint2(pack2bf(o0, o1), pack2bf(o2, o3));
        }
    }
}

// ---------------- K4: MFMA GEMM1, 128x256 tile, 512 threads (2x4 waves) ----------------
// Same single-buffer 2-barrier loop as r6, re-parameterized: staging/FLOP -25%,
// barriers/FLOP -50%, LDS 48KB -> 3 blocks/CU.
__global__ __launch_bounds__(512) void k4_ffn1_mfma(
        const unsigned short* __restrict__ A, const unsigned short* __restrict__ B,
        const float* __restrict__ b1, unsigned short* __restrict__ c1, int mbase) {
    __shared__ unsigned short As[128*64];   // 16 KB
    __shared__ unsigned short Bs[256*64];   // 32 KB
    const int t = threadIdx.x;
    const int wid = t >> 6, lane = t & 63;
    const int wr = wid >> 2, wc = wid & 3;
    const int m0 = mbase + blockIdx.x*128;
    const int n0 = blockIdx.y*256;
    f32x4 acc[4][4] = {};
    for (int kt = 0; kt < C/64; ++kt) {
        const int k0 = kt*64;
        #pragma unroll
        for (int i = 0; i < 2; ++i) {           // A: 1024 segs
            const int seg = i*512 + t;
            const int row = seg >> 3, jd = seg & 7;
            const int js = jd ^ (row & 7);
            gload_lds16(A + (size_t)(m0+row)*C + k0 + js*8, &As[(i*512 + wid*64)*8]);
        }
        #pragma unroll
        for (int i = 0; i < 4; ++i) {           // B: 2048 segs
            const int seg = i*512 + t;
            const int row = seg >> 3, jd = seg & 7;
            const int js = jd ^ (row & 7);
            gload_lds16(B + (size_t)(n0+row)*C + k0 + js*8, &Bs[(i*512 + wid*64)*8]);
        }
        __syncthreads();
        #pragma unroll
        for (int kk = 0; kk < 2; ++kk) {
            bf16x8 af[4], bfr[4];
            #pragma unroll
            for (int m = 0; m < 4; ++m) {
                const int row = wr*64 + m*16 + (lane & 15);
                const int j = (kk*4 + (lane >> 4)) ^ (row & 7);
                af[m] = *reinterpret_cast<const bf16x8*>(&As[row*64 + j*8]);
            }
            #pragma unroll
            for (int n = 0; n < 4; ++n) {
                const int row = wc*64 + n*16 + (lane & 15);
                const int j = (kk*4 + (lane >> 4)) ^ (row & 7);
                bfr[n] = *reinterpret_cast<const bf16x8*>(&Bs[row*64 + j*8]);
            }
            #pragma unroll
            for (int m = 0; m < 4; ++m)
                #pragma unroll
                for (int n = 0; n < 4; ++n)
                    acc[m][n] = __builtin_amdgcn_mfma_f32_16x16x32_bf16(af[m], bfr[n], acc[m][n], 0, 0, 0);
        }
        __syncthreads();
    }
    const int r4 = lane >> 4, cc = lane & 15;
    #pragma unroll
    for (int m = 0; m < 4; ++m) {
        #pragma unroll
        for (int r = 0; r < 4; ++r) {
            const int lrow = blockIdx.x*128 + wr*64 + m*16 + r4*4 + r;
            #pragma unroll
            for (int n = 0; n < 4; ++n) {
                const int gcol = n0 + wc*64 + n*16 + cc;
                float f = acc[m][n][r] + b1[gcol];
                c1[(size_t)lrow*FF + gcol] = f2bf(fast_gelu(f));
            }
        }
    }
}

// ---------------- K5: MFMA GEMM2 + residual + LN2 fused, 2-phase prefetch ----------------
__global__ __launch_bounds__(256) void k5_ffn2_ln(
        const unsigned short* __restrict__ A, const unsigned short* __restrict__ B,
        const float* __restrict__ b2, const unsigned short* __restrict__ xb,
        const float* __restrict__ g2, const float* __restrict__ be2,
        float* __restrict__ out, int mbase) {
    __shared__ __align__(16) unsigned short smem[40960];   // 80 KB
    unsigned short* As0 = smem;
    unsigned short* As1 = smem + 4096;
    unsigned short* Bs0 = smem + 8192;
    unsigned short* Bs1 = smem + 8192 + 16384;
    const int t = threadIdx.x;
    const int wid = t >> 6, lane = t & 63;
    const int lm0 = blockIdx.x*64;
    f32x4 acc[4][4] = {};

    #pragma unroll
    for (int i = 0; i < 2; ++i) {
        const int row = (i*256 + t) >> 3, jd = (i*256 + t) & 7;
        const int js = jd ^ (row & 7);
        gload_lds16(A + (size_t)(lm0+row)*FF + js*8, &As0[(i*256 + wid*64)*8]);
    }
    #pragma unroll
    for (int i = 0; i < 8; ++i) {
        const int row = (i*256 + t) >> 3, jd = (i*256 + t) & 7;
        const int js = jd ^ (row & 7);
        gload_lds16(B + (size_t)row*FF + js*8, &Bs0[(i*256 + wid*64)*8]);
    }
    __syncthreads();
    for (int kt = 0; kt < FF/64; ++kt) {
        const int cur = kt & 1;
        unsigned short* Asc = cur ? As1 : As0;
        unsigned short* Bsc = cur ? Bs1 : Bs0;
        if (kt < FF/64 - 1) {
            unsigned short* Asn = cur ? As0 : As1;
            unsigned short* Bsn = cur ? Bs0 : Bs1;
            const int k0n = (kt+1)*64;
            #pragma unroll
            for (int i = 0; i < 2; ++i) {
                const int row = (i*256 + t) >> 3, jd = (i*256 + t) & 7;
                const int js = jd ^ (row & 7);
                gload_lds16(A + (size_t)(lm0+row)*FF + k0n + js*8, &Asn[(i*256 + wid*64)*8]);
            }
            #pragma unroll
            for (int i = 0; i < 8; ++i) {
                const int row = (i*256 + t) >> 3, jd = (i*256 + t) & 7;
                const int js = jd ^ (row & 7);
                gload_lds16(B + (size_t)row*FF + k0n + js*8, &Bsn[(i*256 + wid*64)*8]);
            }
        }
        #pragma unroll
        for (int kk = 0; kk < 2; ++kk) {
            bf16x8 af[4], bfr[4];
            #pragma unroll
            for (int m = 0; m < 4; ++m) {
                const int row = m*16 + (lane & 15);
                const int j = (kk*4 + (lane >> 4)) ^ (row & 7);
                af[m] = *reinterpret_cast<const bf16x8*>(&Asc[row*64 + j*8]);
            }
            #pragma unroll
            for (int n = 0; n < 4; ++n) {
                const int row = wid*64 + n*16 + (lane & 15);
                const int j = (kk*4 + (lane >> 4)) ^ (row & 7);
                bfr[n] = *reinterpret_cast<const bf16x8*>(&Bsc[row*64 + j*8]);
            }
            #pragma unroll
            for (int m = 0; m < 4; ++m)
                #pragma unroll
                for (int n = 0; n < 4; ++n)
                    acc[m][n] = __builtin_amdgcn_mfma_f32_16x16x32_bf16(af[m], bfr[n], acc[m][n], 0, 0, 0);
        }
        if (kt < FF/64 - 1) __syncthreads();
    }
    float* red1 = (float*)smem;
    float* red2 = (float*)smem + 256;
    float* mear = (float*)smem + 512;
    float* rsr  = (float*)smem + 576;
    const int r4 = lane >> 4, cc = lane & 15;
    float b2v[4], g2v[4], be2v[4];
    #pragma unroll
    for (int n = 0; n < 4; ++n) {
        const int gcol = wid*64 + n*16 + cc;
        b2v[n] = b2[gcol]; g2v[n] = g2[gcol]; be2v[n] = be2[gcol];
    }
    float s1[4][4] = {}, s2[4][4] = {};
    #pragma unroll
    for (int m = 0; m < 4; ++m) {
        #pragma unroll
        for (int n = 0; n < 4; ++n) {
            const int gcol = wid*64 + n*16 + cc;
            #pragma unroll
            for (int r = 0; r < 4; ++r) {
                const size_t grow = (size_t)(mbase + lm0 + m*16 + r4*4 + r);
                float v = acc[m][n][r] + b2v[n] + bf2f(xb[grow*C + gcol]);
                acc[m][n][r] = v;
                s1[m][r] += v;
                s2[m][r] += v*v;
            }
        }
    }
    #pragma unroll
    for (int m = 0; m < 4; ++m) {
        #pragma unroll
        for (int r = 0; r < 4; ++r) {
            float a = s1[m][r], bb = s2[m][r];
            #pragma unroll
            for (int mk = 8; mk >= 1; mk >>= 1) {
                a  += __shfl_xor(a,  mk, 16);
                bb += __shfl_xor(bb, mk, 16);
            }
            if (cc == 0) {
                red1[wid*64 + m*16 + r4*4 + r] = a;
                red2[wid*64 + m*16 + r4*4 + r] = bb;
            }
        }
    }
    __syncthreads();
    if (t < 64) {
        float a  = red1[t]+red1[64+t]+red1[128+t]+red1[192+t];
        float bb = red2[t]+red2[64+t]+red2[128+t]+red2[192+t];
        float mean = a * (1.f/C);
        float var  = bb * (1.f/C) - mean*mean;
        mear[t] = mean;
        rsr[t]  = rsqrtf(var + 1e-5f);
    }
    __syncthreads();
    #pragma unroll
    for (int m = 0; m < 4; ++m) {
        #pragma unroll
        for (int r = 0; r < 4; ++r) {
            const int rl = m*16 + r4*4 + r;
            const float mu = mear[rl], rs = rsr[rl];
            const size_t grow = (size_t)(mbase + lm0 + rl);
            #pragma unroll
            for (int n = 0; n < 4; ++n) {
                const int gcol = wid*64 + n*16 + cc;
                out[grow*C + gcol] = (acc[m][n][r] - mu)*rs*g2v[n] + be2v[n];
            }
        }
    }
}

extern "C" void kernel_launch(void* const* d_in, const int* in_sizes, int n_in,
                              void* d_out, int out_size, void* d_ws, size_t ws_size,
                              hipStream_t stream) {
    const float* x    = (const float*)d_in[0];
    const float* Wkqv = (const float*)d_in[1];
    const float* W1   = (const float*)d_in[2];
    const float* b1   = (const float*)d_in[3];
    const float* W2   = (const float*)d_in[4];
    const float* b2   = (const float*)d_in[5];
    const float* g1   = (const float*)d_in[6];
    const float* be1  = (const float*)d_in[7];
    const float* g2   = (const float*)d_in[8];
    const float* be2  = (const float*)d_in[9];
    float* out = (float*)d_out;

    // ws layout (bytes):
    //   kv @ 0 | W1b @ 128K | W2b @ 640K | part @ 2M | xb @ 12M | c1 @ 48M  (~111 MB)
    char* wsb = (char*)d_ws;
    float* kv            = (float*)(wsb);
    unsigned short* W1b  = (unsigned short*)(wsb + (131072));
    unsigned short* W2b  = (unsigned short*)(wsb + (655360));
    float* part          = (float*)(wsb + ((size_t)2 << 20));
    unsigned short* xb   = (unsigned short*)(wsb + ((size_t)12 << 20));
    unsigned short* c1   = (unsigned short*)(wsb + ((size_t)48 << 20));

    k0_cvt<<<1024, 256, 0, stream>>>(W1, W2, W1b, W2b);
    k1_kv_partial_mfma<<<dim3(16, NCHUNK), 256, 0, stream>>>(x, Wkqv, part);
    k2_kv_reduce<<<16, 256, 0, stream>>>(part, kv);
    k3_attn_ln1_mfma<<<ROWS/64, 256, 0, stream>>>(x, Wkqv, kv, g1, be1, xb);
    for (int chunk = 0; chunk < 2; ++chunk) {
        const int mbase = chunk * MCHUNK;
        k4_ffn1_mfma<<<dim3(MCHUNK/128, FF/256), 512, 0, stream>>>(xb, W1b, b1, c1, mbase);
        k5_ffn2_ln<<<MCHUNK/64, 256, 0, stream>>>(c1, W2b, b2, xb, g2, be2, out, mbase);
    }
}